// Round 2
// baseline (4382.794 us; speedup 1.0000x reference)
//
#include <hip/hip_runtime.h>
#include <hip/hip_bf16.h>

// AKT_27917287424232 — 3-block distance-decay attention transformer.
// B=8, S=1024, D=512, H=8, dk=64. Inputs fp32, outputs fp32 (out,hq,hs).
// R7: tiled attention rewrite (8 query rows/block, LDS K/V tiles).
// R8: s_t XOR-swizzle, shuffle scan, bounded softmax loops. 4136->3553 us.
// R9: phase1 col-per-lane 4-rows/thread (b128 K + broadcast Q), KS=68 +
// float4 staging, phase5 b128 V + s_t stride 1028 (kills e-read 4-way
// conflict), __expf + range-bounded exp pass, GEMM retile 128x64 (8x4/thr).

typedef __hip_bfloat16 bf16;

constexpr int Bn = 8, Sn = 1024, Dn = 512, Hn = 8, DKn = 64;
constexpr float LN_EPS = 1e-5f;
constexpr int TQ = 8;     // query rows per block
constexpr int TJ = 128;   // K/V tile rows
constexpr int KS = 68;    // LDS row stride for q/k/v tiles (16B aligned)
constexpr int SRS = 1028; // s_t row stride (4-bank offset per row)

__device__ inline float wave_reduce_sum(float v) {
    #pragma unroll
    for (int off = 32; off; off >>= 1) v += __shfl_xor(v, off, 64);
    return v;
}
// Block of exactly 256 threads (4 waves). smem >= 4 floats.
__device__ inline float block_reduce_sum(float v, float* smem) {
    int lane = threadIdx.x & 63, wave = threadIdx.x >> 6;
    v = wave_reduce_sum(v);
    __syncthreads();
    if (lane == 0) smem[wave] = v;
    __syncthreads();
    return smem[0] + smem[1] + smem[2] + smem[3];
}

// s_t column swizzle: logical col j lives at j ^ ((j>>5)&31). Bijective
// within each 32-col group; makes the chunked softmax access conflict-free.
__device__ inline int sswz(int col) { return col ^ ((col >> 5) & 31); }

// ---------------------------------------------------------------------------
// C[M,N] = A[M,K] @ W[K,N] + bias[N]. 128x64 tile, BK=16, 8x4/thread. fp32.
// ---------------------------------------------------------------------------
__global__ __launch_bounds__(256) void gemm_bias(
    const float* __restrict__ A, const float* __restrict__ W,
    const float* __restrict__ bias, float* __restrict__ C, int M, int N,
    int K) {
    __shared__ __align__(16) float As[16][132];
    __shared__ __align__(16) float Bs[16][68];
    const int bm = blockIdx.y * 128, bn = blockIdx.x * 64;
    const int tid = threadIdx.x;
    const int tx = tid & 15, ty = tid >> 4;  // tx: n/4, ty: m/8
    float acc[8][4] = {};
    for (int k0 = 0; k0 < K; k0 += 16) {
        #pragma unroll
        for (int l = 0; l < 8; l++) {
            int idx = tid + l * 256;
            int m = idx >> 4, kk = idx & 15;
            As[kk][m] = A[(size_t)(bm + m) * K + k0 + kk];
        }
        {   // B: 16x64 = 1024 floats = 1 float4/thread
            int kk = tid >> 4, n = (tid & 15) * 4;
            float4 b4 = *reinterpret_cast<const float4*>(
                &W[(size_t)(k0 + kk) * N + bn + n]);
            *reinterpret_cast<float4*>(&Bs[kk][n]) = b4;
        }
        __syncthreads();
        #pragma unroll
        for (int kk = 0; kk < 16; kk++) {
            float4 a0 = *reinterpret_cast<const float4*>(&As[kk][ty * 8]);
            float4 a1 = *reinterpret_cast<const float4*>(&As[kk][ty * 8 + 4]);
            float4 b4 = *reinterpret_cast<const float4*>(&Bs[kk][tx * 4]);
            float am[8] = {a0.x, a0.y, a0.z, a0.w, a1.x, a1.y, a1.z, a1.w};
            float bv4[4] = {b4.x, b4.y, b4.z, b4.w};
            #pragma unroll
            for (int um = 0; um < 8; um++)
                #pragma unroll
                for (int un = 0; un < 4; un++) acc[um][un] += am[um] * bv4[un];
        }
        __syncthreads();
    }
    const float4 bb = *reinterpret_cast<const float4*>(&bias[bn + tx * 4]);
    #pragma unroll
    for (int um = 0; um < 8; um++) {
        int m = bm + ty * 8 + um;
        float4 o = make_float4(acc[um][0] + bb.x, acc[um][1] + bb.y,
                               acc[um][2] + bb.z, acc[um][3] + bb.w);
        *reinterpret_cast<float4*>(&C[(size_t)m * N + bn + tx * 4]) = o;
    }
}

// out[M,512] = [A1 | A2][M,1024] @ W[1024,512] + bias[512], fp32 out.
__global__ __launch_bounds__(256) void gemm_cat(
    const float* __restrict__ A1, const float* __restrict__ A2,
    const float* __restrict__ W, const float* __restrict__ bias,
    float* __restrict__ C, int M, int N) {
    __shared__ __align__(16) float As[16][132];
    __shared__ __align__(16) float Bs[16][68];
    const int bm = blockIdx.y * 128, bn = blockIdx.x * 64;
    const int tid = threadIdx.x;
    const int tx = tid & 15, ty = tid >> 4;
    float acc[8][4] = {};
    const int K = 2 * Dn;
    for (int k0 = 0; k0 < K; k0 += 16) {
        const float* A = (k0 < Dn) ? A1 : A2;
        const int kc = k0 & (Dn - 1);
        #pragma unroll
        for (int l = 0; l < 8; l++) {
            int idx = tid + l * 256;
            int m = idx >> 4, kk = idx & 15;
            As[kk][m] = A[(size_t)(bm + m) * Dn + kc + kk];
        }
        {
            int kk = tid >> 4, n = (tid & 15) * 4;
            float4 b4 = *reinterpret_cast<const float4*>(
                &W[(size_t)(k0 + kk) * N + bn + n]);
            *reinterpret_cast<float4*>(&Bs[kk][n]) = b4;
        }
        __syncthreads();
        #pragma unroll
        for (int kk = 0; kk < 16; kk++) {
            float4 a0 = *reinterpret_cast<const float4*>(&As[kk][ty * 8]);
            float4 a1 = *reinterpret_cast<const float4*>(&As[kk][ty * 8 + 4]);
            float4 b4 = *reinterpret_cast<const float4*>(&Bs[kk][tx * 4]);
            float am[8] = {a0.x, a0.y, a0.z, a0.w, a1.x, a1.y, a1.z, a1.w};
            float bv4[4] = {b4.x, b4.y, b4.z, b4.w};
            #pragma unroll
            for (int um = 0; um < 8; um++)
                #pragma unroll
                for (int un = 0; un < 4; un++) acc[um][un] += am[um] * bv4[un];
        }
        __syncthreads();
    }
    const float4 bb = *reinterpret_cast<const float4*>(&bias[bn + tx * 4]);
    #pragma unroll
    for (int um = 0; um < 8; um++) {
        int m = bm + ty * 8 + um;
        float4 o = make_float4(acc[um][0] + bb.x, acc[um][1] + bb.y,
                               acc[um][2] + bb.z, acc[um][3] + bb.w);
        *reinterpret_cast<float4*>(&C[(size_t)m * N + bn + tx * 4]) = o;
    }
}

// ---------------------------------------------------------------------------
// Tiled distance-decay attention. One block (256 thr) per (b,h, 8-row tile).
// MODE: 0 = j<=i; 1 = j<i; 2 = i-19<=j<i.
// Phase 1: col-per-lane scores (4 rows/thread, b128 K + broadcast Q).
// Phases 2-4: per-row softmax1 / cumsum / decay / softmax2 (32 thr/row,
// shuffle reductions, valid-range-bounded, __expf).
// Phase 5: A.V, 4-wave j-split, b128 V reads, 2x4 reg block.
// s_t columns XOR-swizzled; s_t row stride 1028 (e-reads conflict-free).
// ---------------------------------------------------------------------------
template <int MODE, bool MAXOUT>
__global__ __launch_bounds__(256) void attn_tile(
    const float* __restrict__ QK, const float* __restrict__ V,
    const float* __restrict__ gam, size_t g_off, float* __restrict__ O) {
    __shared__ float q_t[TQ * KS];                      // 2176 B
    __shared__ __align__(16) float kv[TJ * KS];         // 34816 B (K then V)
    __shared__ float s_t[TQ * SRS];                     // 32896 B
    __shared__ __align__(16) float pv[4 * 512];         // 8192 B
    __shared__ float rcoef[TQ];

    const int tid = threadIdx.x;
    const int i0 = blockIdx.x * TQ;
    const int bh = blockIdx.y;
    const int h = bh & (Hn - 1);
    const int b = bh >> 3;

    const float* Kbase = QK + (size_t)b * Sn * Dn + h * DKn;  // Q==K buffer
    const float* Vbase = V + (size_t)b * Sn * Dn + h * DKn;

    const int last_j = (MODE == 0) ? (i0 + TQ - 1) : (i0 + TQ - 2);
    const int jt_hi = (last_j >> 7) + 1;
    const int jt_lo = (MODE == 2) ? (max(0, i0 - 19) >> 7) : 0;

    // ---- stage Q (8 rows x 64) ----
    #pragma unroll
    for (int rep = 0; rep < 2; rep++) {
        int idx = tid + rep * 256;
        int r = idx >> 6, d = idx & 63;
        q_t[r * KS + d] = Kbase[(size_t)(i0 + r) * Dn + d];
    }

    // ---- phase 1: scores (col-per-lane, 4 rows per thread) ----
    const int colg = tid & 127;          // col within K tile
    const int rg4 = (tid >> 7) * 4;      // 0 or 4: first of this group's rows
    for (int jt = jt_lo; jt < jt_hi; jt++) {
        __syncthreads();
        #pragma unroll
        for (int rep = 0; rep < 8; rep++) {
            int f = rep * 1024 + tid * 4;
            int row = f >> 6, d = f & 63;
            const float4 v4 = *reinterpret_cast<const float4*>(
                &Kbase[(size_t)(jt * TJ + row) * Dn + d]);
            *reinterpret_cast<float4*>(&kv[row * KS + d]) = v4;
        }
        __syncthreads();
        float acc[4] = {0.f, 0.f, 0.f, 0.f};
        #pragma unroll
        for (int d = 0; d < DKn; d += 4) {
            const float4 kf = *reinterpret_cast<const float4*>(&kv[colg * KS + d]);
            #pragma unroll
            for (int r = 0; r < 4; r++) {
                const float4 qf =
                    *reinterpret_cast<const float4*>(&q_t[(rg4 + r) * KS + d]);
                acc[r] += qf.x * kf.x + qf.y * kf.y + qf.z * kf.z + qf.w * kf.w;
            }
        }
        const int sj = sswz(jt * TJ + colg);
        #pragma unroll
        for (int r = 0; r < 4; r++) s_t[(rg4 + r) * SRS + sj] = acc[r] * 0.125f;
    }
    __syncthreads();

    // ---- phases 2-4: per-row softmax1 / cumsum / decay / softmax2 ----
    const int sr = tid >> 5, st = tid & 31;  // 8 rows x 32 threads
    const int i = i0 + sr;
    float* srow = &s_t[sr * SRS];
    const int c0 = st * 32;
    // valid-k range within this thread's 32-col chunk (contiguous)
    const int lastv = (MODE == 0) ? i : i - 1;  // last valid j
    int vlo = (MODE == 2) ? min(max((i - 19) - c0, 0), 32) : 0;
    int vhi = min(max(lastv + 1 - c0, 0), 32);
    if (vhi < vlo) vhi = vlo;
    // swizzled slot for logical col c0+k within this row: c0 + (k^st)
    #define SLOT(k) (c0 + ((k) ^ st))

    float lm = -3.4e38f;
    for (int k = vlo; k < vhi; k++) lm = fmaxf(lm, srow[SLOT(k)]);
    #pragma unroll
    for (int off = 16; off; off >>= 1) lm = fmaxf(lm, __shfl_xor(lm, off, 64));
    const float m1 = lm;

    float csum = 0.f;
    for (int k = vlo; k < vhi; k++) csum += __expf(srow[SLOT(k)] - m1);
    // segmented (32-lane) inclusive scan of chunk sums, no LDS / barriers
    float scan = csum;
    #pragma unroll
    for (int off = 1; off < 32; off <<= 1) {
        float o = __shfl_up(scan, off, 32);
        if (st >= off) scan += o;
    }
    const float Z1 = __shfl(scan, 31, 32);
    const float invZ1 = 1.f / fmaxf(Z1, 1e-37f);
    const float g = -fabsf(gam[g_off + h]);
    float run = scan - csum;  // exclusive prefix at chunk start
    for (int k = vlo; k < vhi; k++) {
        float s = srow[SLOT(k)];
        float p = __expf(s - m1);
        run += p;
        float cum = run * invZ1;
        float dist = sqrtf(fmaxf((1.f - cum) * (float)(i - (c0 + k)), 0.f));
        float decay = fminf(fmaxf(__expf(g * dist), 1e-5f), 1e5f);
        srow[SLOT(k)] = s * decay;
    }

    float lm2 = -3.4e38f;
    for (int k = vlo; k < vhi; k++) lm2 = fmaxf(lm2, srow[SLOT(k)]);
    #pragma unroll
    for (int off = 16; off; off >>= 1) lm2 = fmaxf(lm2, __shfl_xor(lm2, off, 64));
    float z2c = 0.f;
    for (int k = vlo; k < vhi; k++) {
        float e = __expf(srow[SLOT(k)] - lm2);
        srow[SLOT(k)] = e;
        z2c += e;
    }
    for (int k = 0; k < vlo; k++) srow[SLOT(k)] = 0.f;
    for (int k = vhi; k < 32; k++) srow[SLOT(k)] = 0.f;
    #pragma unroll
    for (int off = 16; off; off >>= 1) z2c += __shfl_xor(z2c, off, 64);
    if (st == 0)
        rcoef[sr] = (MAXOUT ? fminf(z2c, 5.f) : 1.f) / fmaxf(z2c, 1e-37f);
    #undef SLOT

    // ---- phase 5: A.V (wave w handles 32 j's per tile) ----
    const int w = tid >> 6, lane = tid & 63;
    const int gq = lane >> 4, lt = lane & 15;
    const int ar0 = 2 * gq, ar1 = ar0 + 1;
    float a0[4] = {0.f, 0.f, 0.f, 0.f}, a1[4] = {0.f, 0.f, 0.f, 0.f};
    for (int jt = jt_lo; jt < jt_hi; jt++) {
        __syncthreads();
        #pragma unroll
        for (int rep = 0; rep < 8; rep++) {
            int f = rep * 1024 + tid * 4;
            int row = f >> 6, d = f & 63;
            const float4 v4 = *reinterpret_cast<const float4*>(
                &Vbase[(size_t)(jt * TJ + row) * Dn + d]);
            *reinterpret_cast<float4*>(&kv[row * KS + d]) = v4;
        }
        __syncthreads();
        const int jbase = w * 32;
        #pragma unroll 8
        for (int jj = 0; jj < 32; jj++) {
            int j = jbase + jj;
            const int sgj = sswz(jt * TJ + j);
            float e0 = s_t[ar0 * SRS + sgj];
            float e1 = s_t[ar1 * SRS + sgj];
            const float4 vv =
                *reinterpret_cast<const float4*>(&kv[j * KS + 4 * lt]);
            a0[0] += e0 * vv.x; a0[1] += e0 * vv.y;
            a0[2] += e0 * vv.z; a0[3] += e0 * vv.w;
            a1[0] += e1 * vv.x; a1[1] += e1 * vv.y;
            a1[2] += e1 * vv.z; a1[3] += e1 * vv.w;
        }
    }
    *reinterpret_cast<float4*>(&pv[w * 512 + ar0 * 64 + 4 * lt]) =
        make_float4(a0[0], a0[1], a0[2], a0[3]);
    *reinterpret_cast<float4*>(&pv[w * 512 + ar1 * 64 + 4 * lt]) =
        make_float4(a1[0], a1[1], a1[2], a1[3]);
    __syncthreads();

    // ---- combine + store ----
    #pragma unroll
    for (int rep = 0; rep < 2; rep++) {
        int idx = tid + rep * 256;
        int r = idx >> 6, d = idx & 63;
        float v = (pv[idx] + pv[512 + idx] + pv[1024 + idx] + pv[1536 + idx]) *
                  rcoef[r];
        O[(size_t)(b * Sn + i0 + r) * Dn + h * DKn + d] = v;
    }
}

// ---------------------------------------------------------------------------
// out = LN(x + y) (fp32), one block per row of D=512.
// ---------------------------------------------------------------------------
__global__ __launch_bounds__(256) void add_ln(
    const float* __restrict__ X, const float* __restrict__ Y,
    const float* __restrict__ lnw, const float* __restrict__ lnb, size_t off,
    float* __restrict__ out) {
    __shared__ float red[4];
    const int row = blockIdx.x, tid = threadIdx.x;
    const size_t base = (size_t)row * Dn;
    float v0 = X[base + tid] + Y[base + tid];
    float v1 = X[base + tid + 256] + Y[base + tid + 256];
    const float mu = block_reduce_sum(v0 + v1, red) * (1.f / Dn);
    const float d0 = v0 - mu, d1 = v1 - mu;
    const float var = block_reduce_sum(d0 * d0 + d1 * d1, red) * (1.f / Dn);
    const float rs = rsqrtf(var + LN_EPS);
    out[base + tid] = d0 * rs * lnw[off + tid] + lnb[off + tid];
    out[base + tid + 256] = d1 * rs * lnw[off + tid + 256] + lnb[off + tid + 256];
}

// ---------------------------------------------------------------------------
// catA = LN2(hq + o); catB = LN2(hq + o + ow). All fp32, disjoint buffers.
// ---------------------------------------------------------------------------
__global__ __launch_bounds__(256) void cat_ln(
    const float* __restrict__ hq, const float* __restrict__ o,
    const float* __restrict__ ow, const float* __restrict__ lnw,
    const float* __restrict__ lnb, size_t off, float* __restrict__ catA,
    float* __restrict__ catB) {
    __shared__ float red[4];
    const int row = blockIdx.x, tid = threadIdx.x;
    const size_t base = (size_t)row * Dn;
    const float h0 = hq[base + tid] + o[base + tid];
    const float h1 = hq[base + tid + 256] + o[base + tid + 256];
    const float hw0 = h0 + ow[base + tid];
    const float hw1 = h1 + ow[base + tid + 256];
    const float w0 = lnw[off + tid], w1 = lnw[off + tid + 256];
    const float b0 = lnb[off + tid], b1 = lnb[off + tid + 256];

    float mu = block_reduce_sum(h0 + h1, red) * (1.f / Dn);
    float d0 = h0 - mu, d1 = h1 - mu;
    float var = block_reduce_sum(d0 * d0 + d1 * d1, red) * (1.f / Dn);
    float rs = rsqrtf(var + LN_EPS);
    catA[base + tid] = d0 * rs * w0 + b0;
    catA[base + tid + 256] = d1 * rs * w1 + b1;

    mu = block_reduce_sum(hw0 + hw1, red) * (1.f / Dn);
    d0 = hw0 - mu;
    d1 = hw1 - mu;
    var = block_reduce_sum(d0 * d0 + d1 * d1, red) * (1.f / Dn);
    rs = rsqrtf(var + LN_EPS);
    catB[base + tid] = d0 * rs * w0 + b0;
    catB[base + tid + 256] = d1 * rs * w1 + b1;
}

extern "C" void kernel_launch(void* const* d_in, const int* in_sizes, int n_in,
                              void* d_out, int out_size, void* d_ws,
                              size_t ws_size, hipStream_t stream) {
    const float* q_emb = (const float*)d_in[0];
    const float* s_emb = (const float*)d_in[1];
    const float* Wq = (const float*)d_in[2];
    const float* bq = (const float*)d_in[3];
    const float* Wqw = (const float*)d_in[4];
    const float* bqw = (const float*)d_in[5];
    const float* Wv = (const float*)d_in[6];
    const float* bv = (const float*)d_in[7];
    const float* Wo = (const float*)d_in[8];
    const float* bo = (const float*)d_in[9];
    const float* Wow = (const float*)d_in[10];
    const float* bow = (const float*)d_in[11];
    const float* gammas = (const float*)d_in[12];
    const float* ln_w = (const float*)d_in[13];
    const float* ln_b = (const float*)d_in[14];
    const float* Wc = (const float*)d_in[15];
    const float* bc = (const float*)d_in[16];
    // d_in[17] = lens: unused in the forward pass.

    const size_t BSD = (size_t)Bn * Sn * Dn;
    float* ws = (float*)d_ws;
    float* W0 = ws;
    float* W1 = ws + BSD;
    float* W2 = ws + 2 * BSD;

    float* out_main = (float*)d_out;     // out [B,S,D]
    float* out_hq = out_main + BSD;      // hq
    float* out_hs = out_main + 2 * BSD;  // hs

    const int rows = Bn * Sn;  // 8192
    const dim3 tpb(256);
    const dim3 ggemm(Dn / 64, rows / 128);  // (8, 64)
    const dim3 gattn(Sn / TQ, Bn * Hn);     // (128, 64)
    const dim3 grow(rows);
    const size_t DD = (size_t)Dn * Dn;

    // ---- Block 1: hq = LN0(q_emb + attn0(q_emb)) -> out_hq ----
    gemm_bias<<<ggemm, tpb, 0, stream>>>(q_emb, Wq, bq, W0, rows, Dn, Dn);
    gemm_bias<<<ggemm, tpb, 0, stream>>>(q_emb, Wv, bv, W1, rows, Dn, Dn);
    attn_tile<0, false><<<gattn, tpb, 0, stream>>>(W0, W1, gammas, 0, W2);
    gemm_bias<<<ggemm, tpb, 0, stream>>>(W2, Wo, bo, W0, rows, Dn, Dn);
    add_ln<<<grow, tpb, 0, stream>>>(q_emb, W0, ln_w, ln_b, 0, out_hq);

    // ---- Block 2: hs = LN1(s_emb + attn1(s_emb)) -> out_hs ----
    gemm_bias<<<ggemm, tpb, 0, stream>>>(s_emb, Wq + DD, bq + Dn, W0, rows, Dn, Dn);
    gemm_bias<<<ggemm, tpb, 0, stream>>>(s_emb, Wv + DD, bv + Dn, W1, rows, Dn, Dn);
    attn_tile<0, false><<<gattn, tpb, 0, stream>>>(W0, W1, gammas, Hn, W2);
    gemm_bias<<<ggemm, tpb, 0, stream>>>(W2, Wo + DD, bo + Dn, W0, rows, Dn, Dn);
    add_ln<<<grow, tpb, 0, stream>>>(s_emb, W0, ln_w, ln_b, Dn, out_hs);

    // ---- Block 3: xq=xk=hq, xv=hs ----
    gemm_bias<<<ggemm, tpb, 0, stream>>>(out_hq, Wq + 2 * DD, bq + 2 * Dn, W0, rows, Dn, Dn);
    gemm_bias<<<ggemm, tpb, 0, stream>>>(out_hs, Wv + 2 * DD, bv + 2 * Dn, W1, rows, Dn, Dn);
    attn_tile<1, true><<<gattn, tpb, 0, stream>>>(W0, W1, gammas, 2 * Hn, W2);
    gemm_bias<<<ggemm, tpb, 0, stream>>>(W2, Wo + 2 * DD, bo + 2 * Dn, out_main, rows, Dn, Dn);
    gemm_bias<<<ggemm, tpb, 0, stream>>>(out_hq, Wqw + 2 * DD, bqw + 2 * Dn, W0, rows, Dn, Dn);
    attn_tile<2, false><<<gattn, tpb, 0, stream>>>(W0, W1, gammas, 2 * Hn, W2);
    gemm_bias<<<ggemm, tpb, 0, stream>>>(W2, Wow, bow, W0, rows, Dn, Dn);
    // catA = LN2(hq + o) -> W1 ; catB = LN2(hq + o + ow) -> W2
    cat_ln<<<grow, tpb, 0, stream>>>(out_hq, out_main, W0, ln_w, ln_b, 2 * Dn, W1, W2);
    gemm_cat<<<ggemm, tpb, 0, stream>>>(W1, W2, Wc, bc, out_main, rows, Dn);
}

// Round 3
// 3177.161 us; speedup vs baseline: 1.3795x; 1.3795x over previous
//
#include <hip/hip_runtime.h>
#include <hip/hip_bf16.h>

// AKT_27917287424232 — 3-block distance-decay attention transformer.
// B=8, S=1024, D=512, H=8, dk=64. Inputs fp32, outputs fp32 (out,hq,hs).
// R7: tiled attention rewrite (8 query rows/block, LDS K/V tiles).
// R8: s_t XOR-swizzle, shuffle scan, bounded softmax loops. 4136->3553 us.
// R9 (REGRESSED, reverted): phase1 4-row b128 rewrite + GEMM 128x64 blew
// VGPR 88->136, occupancy 21%->11%. Lesson: stay under the 128-VGPR
// allocation boundary.
// R10: R8 structure + SRS=1028 s_t stride (kills phase-5 e-read 4-way
// conflict), __expf, contiguous-bounded softmax loops + zero-fill.

typedef __hip_bfloat16 bf16;

constexpr int Bn = 8, Sn = 1024, Dn = 512, Hn = 8, DKn = 64;
constexpr float LN_EPS = 1e-5f;
constexpr int TQ = 8;     // query rows per block
constexpr int TJ = 128;   // K/V tile rows
constexpr int KS = 66;    // LDS row stride for q/k/v tiles (2-way max aliasing)
constexpr int SRS = 1028; // s_t row stride (4-bank offset per row)

__device__ inline float wave_reduce_sum(float v) {
    #pragma unroll
    for (int off = 32; off; off >>= 1) v += __shfl_xor(v, off, 64);
    return v;
}
// Block of exactly 256 threads (4 waves). smem >= 4 floats.
__device__ inline float block_reduce_sum(float v, float* smem) {
    int lane = threadIdx.x & 63, wave = threadIdx.x >> 6;
    v = wave_reduce_sum(v);
    __syncthreads();
    if (lane == 0) smem[wave] = v;
    __syncthreads();
    return smem[0] + smem[1] + smem[2] + smem[3];
}

// s_t column swizzle: logical col j lives at j ^ ((j>>5)&31). Bijective
// within each 32-col group; makes the chunked softmax access conflict-free.
__device__ inline int sswz(int col) { return col ^ ((col >> 5) & 31); }

// ---------------------------------------------------------------------------
// C[M,N] = A[M,K] @ W[K,N] + bias[N]. 64x64 tile, BK=16, 4x4/thread. fp32.
// (R1-proven version; 128x64 retile regressed — do not re-grow.)
// ---------------------------------------------------------------------------
__global__ __launch_bounds__(256) void gemm_bias(
    const float* __restrict__ A, const float* __restrict__ W,
    const float* __restrict__ bias, float* __restrict__ C, int M, int N,
    int K) {
    __shared__ __align__(16) float As[16][68];
    __shared__ __align__(16) float Bs[16][68];
    const int bm = blockIdx.y * 64, bn = blockIdx.x * 64;
    const int tid = threadIdx.x;
    const int tx = tid & 15, ty = tid >> 4;
    float acc[4][4] = {};
    for (int k0 = 0; k0 < K; k0 += 16) {
        #pragma unroll
        for (int l = 0; l < 4; l++) {
            int idx = tid + l * 256;
            int m = idx >> 4, kk = idx & 15;
            As[kk][m] = A[(size_t)(bm + m) * K + k0 + kk];
        }
        #pragma unroll
        for (int l = 0; l < 4; l++) {
            int idx = tid + l * 256;
            int kk = idx >> 6, n = idx & 63;
            Bs[kk][n] = W[(size_t)(k0 + kk) * N + bn + n];
        }
        __syncthreads();
        #pragma unroll
        for (int kk = 0; kk < 16; kk++) {
            float4 a4 = *reinterpret_cast<const float4*>(&As[kk][ty * 4]);
            float4 b4 = *reinterpret_cast<const float4*>(&Bs[kk][tx * 4]);
            float a[4] = {a4.x, a4.y, a4.z, a4.w};
            float b[4] = {b4.x, b4.y, b4.z, b4.w};
            #pragma unroll
            for (int um = 0; um < 4; um++)
                #pragma unroll
                for (int un = 0; un < 4; un++) acc[um][un] += a[um] * b[un];
        }
        __syncthreads();
    }
    #pragma unroll
    for (int um = 0; um < 4; um++) {
        int m = bm + ty * 4 + um;
        #pragma unroll
        for (int un = 0; un < 4; un++) {
            int n = bn + tx * 4 + un;
            C[(size_t)m * N + n] = acc[um][un] + bias[n];
        }
    }
}

// out[M,512] = [A1 | A2][M,1024] @ W[1024,512] + bias[512], fp32 out.
__global__ __launch_bounds__(256) void gemm_cat(
    const float* __restrict__ A1, const float* __restrict__ A2,
    const float* __restrict__ W, const float* __restrict__ bias,
    float* __restrict__ C, int M, int N) {
    __shared__ __align__(16) float As[16][68];
    __shared__ __align__(16) float Bs[16][68];
    const int bm = blockIdx.y * 64, bn = blockIdx.x * 64;
    const int tid = threadIdx.x;
    const int tx = tid & 15, ty = tid >> 4;
    float acc[4][4] = {};
    const int K = 2 * Dn;
    for (int k0 = 0; k0 < K; k0 += 16) {
        const float* A = (k0 < Dn) ? A1 : A2;
        const int kc = k0 & (Dn - 1);
        #pragma unroll
        for (int l = 0; l < 4; l++) {
            int idx = tid + l * 256;
            int m = idx >> 4, kk = idx & 15;
            As[kk][m] = A[(size_t)(bm + m) * Dn + kc + kk];
        }
        #pragma unroll
        for (int l = 0; l < 4; l++) {
            int idx = tid + l * 256;
            int kk = idx >> 6, n = idx & 63;
            Bs[kk][n] = W[(size_t)(k0 + kk) * N + bn + n];
        }
        __syncthreads();
        #pragma unroll
        for (int kk = 0; kk < 16; kk++) {
            float4 a4 = *reinterpret_cast<const float4*>(&As[kk][ty * 4]);
            float4 b4 = *reinterpret_cast<const float4*>(&Bs[kk][tx * 4]);
            float a[4] = {a4.x, a4.y, a4.z, a4.w};
            float b[4] = {b4.x, b4.y, b4.z, b4.w};
            #pragma unroll
            for (int um = 0; um < 4; um++)
                #pragma unroll
                for (int un = 0; un < 4; un++) acc[um][un] += a[um] * b[un];
        }
        __syncthreads();
    }
    #pragma unroll
    for (int um = 0; um < 4; um++) {
        int m = bm + ty * 4 + um;
        #pragma unroll
        for (int un = 0; un < 4; un++) {
            int n = bn + tx * 4 + un;
            C[(size_t)m * N + n] = acc[um][un] + bias[n];
        }
    }
}

// ---------------------------------------------------------------------------
// Tiled distance-decay attention. One block (256 thr) per (b,h, 8-row tile).
// MODE: 0 = j<=i; 1 = j<i; 2 = i-19<=j<i.
// Phases: stage Q; per K-tile(128): stage K, compute scores (2x2 reg block);
// per-row softmax1 (32 thr/row, shuffle reductions + shfl_up scan), cumsum,
// decay rescale; softmax2 (+maxout coef); per V-tile: stage V, accumulate A.V
// (4-wave j-split, 2x4 reg block); combine partials, scale by coef, store.
// s_t columns XOR-swizzled; s_t row stride 1028 (e-reads conflict-free).
// ---------------------------------------------------------------------------
template <int MODE, bool MAXOUT>
__global__ __launch_bounds__(256) void attn_tile(
    const float* __restrict__ QK, const float* __restrict__ V,
    const float* __restrict__ gam, size_t g_off, float* __restrict__ O) {
    __shared__ float q_t[TQ * KS];               // 2112 B
    __shared__ float kv[TJ * KS];                // 33792 B (K then V)
    __shared__ float s_t[TQ * SRS];              // 32896 B (scores->s'->e)
    __shared__ __align__(16) float pv[4 * 512];  // 8192 B (A.V partials)
    __shared__ float rcoef[TQ];

    const int tid = threadIdx.x;
    const int i0 = blockIdx.x * TQ;
    const int bh = blockIdx.y;
    const int h = bh & (Hn - 1);
    const int b = bh >> 3;

    const float* Kbase = QK + (size_t)b * Sn * Dn + h * DKn;  // Q==K buffer
    const float* Vbase = V + (size_t)b * Sn * Dn + h * DKn;

    const int last_j = (MODE == 0) ? (i0 + TQ - 1) : (i0 + TQ - 2);
    const int jt_hi = (last_j >> 7) + 1;
    const int jt_lo = (MODE == 2) ? (max(0, i0 - 19) >> 7) : 0;

    // ---- stage Q (8 rows x 64) ----
    #pragma unroll
    for (int rep = 0; rep < 2; rep++) {
        int idx = tid + rep * 256;
        int r = idx >> 6, d = idx & 63;
        q_t[r * KS + d] = Kbase[(size_t)(i0 + r) * Dn + d];
    }

    // ---- phase 1: scores ----
    const int pc = tid & 63;
    const int pr = tid >> 6;  // wave id -> rows 2pr, 2pr+1
    const int r0 = 2 * pr, r1 = r0 + 1;
    for (int jt = jt_lo; jt < jt_hi; jt++) {
        __syncthreads();
        #pragma unroll
        for (int rep = 0; rep < 8; rep++) {
            int f = rep * 1024 + tid * 4;
            int row = f >> 6, d = f & 63;
            const float4 v4 = *reinterpret_cast<const float4*>(
                &Kbase[(size_t)(jt * TJ + row) * Dn + d]);
            float* dst = &kv[row * KS + d];
            *reinterpret_cast<float2*>(dst) = make_float2(v4.x, v4.y);
            *reinterpret_cast<float2*>(dst + 2) = make_float2(v4.z, v4.w);
        }
        __syncthreads();
        float d00 = 0.f, d01 = 0.f, d10 = 0.f, d11 = 0.f;
        #pragma unroll 8
        for (int d = 0; d < DKn; d += 2) {
            float2 qa = *reinterpret_cast<const float2*>(&q_t[r0 * KS + d]);
            float2 qb = *reinterpret_cast<const float2*>(&q_t[r1 * KS + d]);
            float2 ka = *reinterpret_cast<const float2*>(&kv[pc * KS + d]);
            float2 kb = *reinterpret_cast<const float2*>(&kv[(pc + 64) * KS + d]);
            d00 += qa.x * ka.x + qa.y * ka.y;
            d01 += qa.x * kb.x + qa.y * kb.y;
            d10 += qb.x * ka.x + qb.y * ka.y;
            d11 += qb.x * kb.x + qb.y * kb.y;
        }
        const int ja = jt * TJ + pc, jb = ja + 64;
        const int sja = sswz(ja), sjb = sswz(jb);
        s_t[r0 * SRS + sja] = d00 * 0.125f;
        s_t[r0 * SRS + sjb] = d01 * 0.125f;
        s_t[r1 * SRS + sja] = d10 * 0.125f;
        s_t[r1 * SRS + sjb] = d11 * 0.125f;
    }
    __syncthreads();

    // ---- phases 2-4: per-row softmax1 / cumsum / decay / softmax2 ----
    const int sr = tid >> 5, st = tid & 31;  // 8 rows x 32 threads
    const int i = i0 + sr;
    float* srow = &s_t[sr * SRS];
    const int c0 = st * 32;
    // valid-k range within this thread's 32-col chunk (contiguous)
    const int lastv = (MODE == 0) ? i : i - 1;  // last valid j
    int vlo = (MODE == 2) ? min(max((i - 19) - c0, 0), 32) : 0;
    int vhi = min(max(lastv + 1 - c0, 0), 32);
    if (vhi < vlo) vhi = vlo;
    // swizzled slot for logical col c0+k within this row: c0 + (k^st)
    #define SLOT(k) (c0 + ((k) ^ st))

    float lm = -3.4e38f;
    for (int k = vlo; k < vhi; k++) lm = fmaxf(lm, srow[SLOT(k)]);
    #pragma unroll
    for (int off = 16; off; off >>= 1) lm = fmaxf(lm, __shfl_xor(lm, off, 64));
    const float m1 = lm;

    float csum = 0.f;
    for (int k = vlo; k < vhi; k++) csum += __expf(srow[SLOT(k)] - m1);
    // segmented (32-lane) inclusive scan of chunk sums, no LDS / barriers
    float scan = csum;
    #pragma unroll
    for (int off = 1; off < 32; off <<= 1) {
        float o = __shfl_up(scan, off, 32);
        if (st >= off) scan += o;
    }
    const float Z1 = __shfl(scan, 31, 32);
    const float invZ1 = 1.f / fmaxf(Z1, 1e-37f);
    const float g = -fabsf(gam[g_off + h]);
    float run = scan - csum;  // exclusive prefix at chunk start
    for (int k = vlo; k < vhi; k++) {
        float s = srow[SLOT(k)];
        float p = __expf(s - m1);
        run += p;
        float cum = run * invZ1;
        float dist = sqrtf(fmaxf((1.f - cum) * (float)(i - (c0 + k)), 0.f));
        float decay = fminf(fmaxf(__expf(g * dist), 1e-5f), 1e5f);
        srow[SLOT(k)] = s * decay;
    }

    float lm2 = -3.4e38f;
    for (int k = vlo; k < vhi; k++) lm2 = fmaxf(lm2, srow[SLOT(k)]);
    #pragma unroll
    for (int off = 16; off; off >>= 1) lm2 = fmaxf(lm2, __shfl_xor(lm2, off, 64));
    float z2c = 0.f;
    for (int k = vlo; k < vhi; k++) {
        float e = __expf(srow[SLOT(k)] - lm2);
        srow[SLOT(k)] = e;
        z2c += e;
    }
    for (int k = 0; k < vlo; k++) srow[SLOT(k)] = 0.f;
    for (int k = vhi; k < 32; k++) srow[SLOT(k)] = 0.f;
    #pragma unroll
    for (int off = 16; off; off >>= 1) z2c += __shfl_xor(z2c, off, 64);
    if (st == 0)
        rcoef[sr] = (MAXOUT ? fminf(z2c, 5.f) : 1.f) / fmaxf(z2c, 1e-37f);
    #undef SLOT

    // ---- phase 5: A.V (wave w handles 32 j's per tile) ----
    const int w = tid >> 6, lane = tid & 63;
    const int gq = lane >> 4, lt = lane & 15;
    const int ar0 = 2 * gq, ar1 = ar0 + 1;
    float a0[4] = {0.f, 0.f, 0.f, 0.f}, a1[4] = {0.f, 0.f, 0.f, 0.f};
    for (int jt = jt_lo; jt < jt_hi; jt++) {
        __syncthreads();
        #pragma unroll
        for (int rep = 0; rep < 8; rep++) {
            int f = rep * 1024 + tid * 4;
            int row = f >> 6, d = f & 63;
            const float4 v4 = *reinterpret_cast<const float4*>(
                &Vbase[(size_t)(jt * TJ + row) * Dn + d]);
            float* dst = &kv[row * KS + d];
            *reinterpret_cast<float2*>(dst) = make_float2(v4.x, v4.y);
            *reinterpret_cast<float2*>(dst + 2) = make_float2(v4.z, v4.w);
        }
        __syncthreads();
        const int jbase = w * 32;
        #pragma unroll 4
        for (int jj = 0; jj < 32; jj++) {
            int j = jbase + jj;
            const int sgj = sswz(jt * TJ + j);
            float e0 = s_t[ar0 * SRS + sgj];
            float e1 = s_t[ar1 * SRS + sgj];
            float2 va = *reinterpret_cast<const float2*>(&kv[j * KS + 4 * lt]);
            float2 vb = *reinterpret_cast<const float2*>(&kv[j * KS + 4 * lt + 2]);
            a0[0] += e0 * va.x; a0[1] += e0 * va.y;
            a0[2] += e0 * vb.x; a0[3] += e0 * vb.y;
            a1[0] += e1 * va.x; a1[1] += e1 * va.y;
            a1[2] += e1 * vb.x; a1[3] += e1 * vb.y;
        }
    }
    *reinterpret_cast<float4*>(&pv[w * 512 + ar0 * 64 + 4 * lt]) =
        make_float4(a0[0], a0[1], a0[2], a0[3]);
    *reinterpret_cast<float4*>(&pv[w * 512 + ar1 * 64 + 4 * lt]) =
        make_float4(a1[0], a1[1], a1[2], a1[3]);
    __syncthreads();

    // ---- combine + store ----
    #pragma unroll
    for (int rep = 0; rep < 2; rep++) {
        int idx = tid + rep * 256;
        int r = idx >> 6, d = idx & 63;
        float v = (pv[idx] + pv[512 + idx] + pv[1024 + idx] + pv[1536 + idx]) *
                  rcoef[r];
        O[(size_t)(b * Sn + i0 + r) * Dn + h * DKn + d] = v;
    }
}

// ---------------------------------------------------------------------------
// out = LN(x + y) (fp32), one block per row of D=512.
// ---------------------------------------------------------------------------
__global__ __launch_bounds__(256) void add_ln(
    const float* __restrict__ X, const float* __restrict__ Y,
    const float* __restrict__ lnw, const float* __restrict__ lnb, size_t off,
    float* __restrict__ out) {
    __shared__ float red[4];
    const int row = blockIdx.x, tid = threadIdx.x;
    const size_t base = (size_t)row * Dn;
    float v0 = X[base + tid] + Y[base + tid];
    float v1 = X[base + tid + 256] + Y[base + tid + 256];
    const float mu = block_reduce_sum(v0 + v1, red) * (1.f / Dn);
    const float d0 = v0 - mu, d1 = v1 - mu;
    const float var = block_reduce_sum(d0 * d0 + d1 * d1, red) * (1.f / Dn);
    const float rs = rsqrtf(var + LN_EPS);
    out[base + tid] = d0 * rs * lnw[off + tid] + lnb[off + tid];
    out[base + tid + 256] = d1 * rs * lnw[off + tid + 256] + lnb[off + tid + 256];
}

// ---------------------------------------------------------------------------
// catA = LN2(hq + o); catB = LN2(hq + o + ow). All fp32, disjoint buffers.
// ---------------------------------------------------------------------------
__global__ __launch_bounds__(256) void cat_ln(
    const float* __restrict__ hq, const float* __restrict__ o,
    const float* __restrict__ ow, const float* __restrict__ lnw,
    const float* __restrict__ lnb, size_t off, float* __restrict__ catA,
    float* __restrict__ catB) {
    __shared__ float red[4];
    const int row = blockIdx.x, tid = threadIdx.x;
    const size_t base = (size_t)row * Dn;
    const float h0 = hq[base + tid] + o[base + tid];
    const float h1 = hq[base + tid + 256] + o[base + tid + 256];
    const float hw0 = h0 + ow[base + tid];
    const float hw1 = h1 + ow[base + tid + 256];
    const float w0 = lnw[off + tid], w1 = lnw[off + tid + 256];
    const float b0 = lnb[off + tid], b1 = lnb[off + tid + 256];

    float mu = block_reduce_sum(h0 + h1, red) * (1.f / Dn);
    float d0 = h0 - mu, d1 = h1 - mu;
    float var = block_reduce_sum(d0 * d0 + d1 * d1, red) * (1.f / Dn);
    float rs = rsqrtf(var + LN_EPS);
    catA[base + tid] = d0 * rs * w0 + b0;
    catA[base + tid + 256] = d1 * rs * w1 + b1;

    mu = block_reduce_sum(hw0 + hw1, red) * (1.f / Dn);
    d0 = hw0 - mu;
    d1 = hw1 - mu;
    var = block_reduce_sum(d0 * d0 + d1 * d1, red) * (1.f / Dn);
    rs = rsqrtf(var + LN_EPS);
    catB[base + tid] = d0 * rs * w0 + b0;
    catB[base + tid + 256] = d1 * rs * w1 + b1;
}

extern "C" void kernel_launch(void* const* d_in, const int* in_sizes, int n_in,
                              void* d_out, int out_size, void* d_ws,
                              size_t ws_size, hipStream_t stream) {
    const float* q_emb = (const float*)d_in[0];
    const float* s_emb = (const float*)d_in[1];
    const float* Wq = (const float*)d_in[2];
    const float* bq = (const float*)d_in[3];
    const float* Wqw = (const float*)d_in[4];
    const float* bqw = (const float*)d_in[5];
    const float* Wv = (const float*)d_in[6];
    const float* bv = (const float*)d_in[7];
    const float* Wo = (const float*)d_in[8];
    const float* bo = (const float*)d_in[9];
    const float* Wow = (const float*)d_in[10];
    const float* bow = (const float*)d_in[11];
    const float* gammas = (const float*)d_in[12];
    const float* ln_w = (const float*)d_in[13];
    const float* ln_b = (const float*)d_in[14];
    const float* Wc = (const float*)d_in[15];
    const float* bc = (const float*)d_in[16];
    // d_in[17] = lens: unused in the forward pass.

    const size_t BSD = (size_t)Bn * Sn * Dn;
    float* ws = (float*)d_ws;
    float* W0 = ws;
    float* W1 = ws + BSD;
    float* W2 = ws + 2 * BSD;

    float* out_main = (float*)d_out;     // out [B,S,D]
    float* out_hq = out_main + BSD;      // hq
    float* out_hs = out_main + 2 * BSD;  // hs

    const int rows = Bn * Sn;  // 8192
    const dim3 tpb(256);
    const dim3 ggemm(Dn / 64, rows / 64);
    const dim3 gattn(Sn / TQ, Bn * Hn);  // (128, 64)
    const dim3 grow(rows);
    const size_t DD = (size_t)Dn * Dn;

    // ---- Block 1: hq = LN0(q_emb + attn0(q_emb)) -> out_hq ----
    gemm_bias<<<ggemm, tpb, 0, stream>>>(q_emb, Wq, bq, W0, rows, Dn, Dn);
    gemm_bias<<<ggemm, tpb, 0, stream>>>(q_emb, Wv, bv, W1, rows, Dn, Dn);
    attn_tile<0, false><<<gattn, tpb, 0, stream>>>(W0, W1, gammas, 0, W2);
    gemm_bias<<<ggemm, tpb, 0, stream>>>(W2, Wo, bo, W0, rows, Dn, Dn);
    add_ln<<<grow, tpb, 0, stream>>>(q_emb, W0, ln_w, ln_b, 0, out_hq);

    // ---- Block 2: hs = LN1(s_emb + attn1(s_emb)) -> out_hs ----
    gemm_bias<<<ggemm, tpb, 0, stream>>>(s_emb, Wq + DD, bq + Dn, W0, rows, Dn, Dn);
    gemm_bias<<<ggemm, tpb, 0, stream>>>(s_emb, Wv + DD, bv + Dn, W1, rows, Dn, Dn);
    attn_tile<0, false><<<gattn, tpb, 0, stream>>>(W0, W1, gammas, Hn, W2);
    gemm_bias<<<ggemm, tpb, 0, stream>>>(W2, Wo + DD, bo + Dn, W0, rows, Dn, Dn);
    add_ln<<<grow, tpb, 0, stream>>>(s_emb, W0, ln_w, ln_b, Dn, out_hs);

    // ---- Block 3: xq=xk=hq, xv=hs ----
    gemm_bias<<<ggemm, tpb, 0, stream>>>(out_hq, Wq + 2 * DD, bq + 2 * Dn, W0, rows, Dn, Dn);
    gemm_bias<<<ggemm, tpb, 0, stream>>>(out_hs, Wv + 2 * DD, bv + 2 * Dn, W1, rows, Dn, Dn);
    attn_tile<1, true><<<gattn, tpb, 0, stream>>>(W0, W1, gammas, 2 * Hn, W2);
    gemm_bias<<<ggemm, tpb, 0, stream>>>(W2, Wo + 2 * DD, bo + 2 * Dn, out_main, rows, Dn, Dn);
    gemm_bias<<<ggemm, tpb, 0, stream>>>(out_hq, Wqw + 2 * DD, bqw + 2 * Dn, W0, rows, Dn, Dn);
    attn_tile<2, false><<<gattn, tpb, 0, stream>>>(W0, W1, gammas, 2 * Hn, W2);
    gemm_bias<<<ggemm, tpb, 0, stream>>>(W2, Wow, bow, W0, rows, Dn, Dn);
    // catA = LN2(hq + o) -> W1 ; catB = LN2(hq + o + ow) -> W2
    cat_ln<<<grow, tpb, 0, stream>>>(out_hq, out_main, W0, ln_w, ln_b, 2 * Dn, W1, W2);
    gemm_cat<<<ggemm, tpb, 0, stream>>>(W1, W2, Wc, bc, out_main, rows, Dn);
}

// Round 4
// 2984.617 us; speedup vs baseline: 1.4685x; 1.0645x over previous
//
#include <hip/hip_runtime.h>
#include <hip/hip_bf16.h>

// AKT_27917287424232 — 3-block distance-decay attention transformer.
// B=8, S=1024, D=512, H=8, dk=64. Inputs fp32, outputs fp32 (out,hq,hs).
// R7: tiled attention rewrite (8 query rows/block, LDS K/V tiles).
// R8: s_t XOR-swizzle, shuffle scan, bounded softmax loops. 4136->3553 us.
// R9 (REGRESSED, reverted): phase1 4-row b128 rewrite + GEMM 128x64 blew
// VGPR 88->136, occupancy 21%->11%. Lesson: stay under 128 VGPR.
// R10: SRS=1028, __expf, contiguous softmax bounds. 3553->3177 us.
// R11: KS=68 + float4 staging/reads (R2's conflict-free layout) with R1's
// low-register 2x2 phase-1 shape (#pragma unroll 2), float4 phase-5 V read,
// GEMM BK=32 (half the barriers). Watch item: attn VGPR must stay <128.

typedef __hip_bfloat16 bf16;

constexpr int Bn = 8, Sn = 1024, Dn = 512, Hn = 8, DKn = 64;
constexpr float LN_EPS = 1e-5f;
constexpr int TQ = 8;     // query rows per block
constexpr int TJ = 128;   // K/V tile rows
constexpr int KS = 68;    // LDS row stride for q/k/v tiles (16B aligned)
constexpr int SRS = 1028; // s_t row stride (4-bank offset per row)

__device__ inline float wave_reduce_sum(float v) {
    #pragma unroll
    for (int off = 32; off; off >>= 1) v += __shfl_xor(v, off, 64);
    return v;
}
// Block of exactly 256 threads (4 waves). smem >= 4 floats.
__device__ inline float block_reduce_sum(float v, float* smem) {
    int lane = threadIdx.x & 63, wave = threadIdx.x >> 6;
    v = wave_reduce_sum(v);
    __syncthreads();
    if (lane == 0) smem[wave] = v;
    __syncthreads();
    return smem[0] + smem[1] + smem[2] + smem[3];
}

// s_t column swizzle: logical col j lives at j ^ ((j>>5)&31). Bijective
// within each 32-col group; makes the chunked softmax access conflict-free.
__device__ inline int sswz(int col) { return col ^ ((col >> 5) & 31); }

// ---------------------------------------------------------------------------
// C[M,N] = A[M,K] @ W[K,N] + bias[N]. 64x64 tile, BK=32, 4x4/thread. fp32.
// ---------------------------------------------------------------------------
__global__ __launch_bounds__(256) void gemm_bias(
    const float* __restrict__ A, const float* __restrict__ W,
    const float* __restrict__ bias, float* __restrict__ C, int M, int N,
    int K) {
    __shared__ __align__(16) float As[32][68];
    __shared__ __align__(16) float Bs[32][68];
    const int bm = blockIdx.y * 64, bn = blockIdx.x * 64;
    const int tid = threadIdx.x;
    const int tx = tid & 15, ty = tid >> 4;
    float acc[4][4] = {};
    for (int k0 = 0; k0 < K; k0 += 32) {
        #pragma unroll
        for (int l = 0; l < 8; l++) {
            int idx = tid + l * 256;
            int m = idx >> 5, kk = idx & 31;
            As[kk][m] = A[(size_t)(bm + m) * K + k0 + kk];
        }
        #pragma unroll
        for (int l = 0; l < 8; l++) {
            int idx = tid + l * 256;
            int kk = idx >> 6, n = idx & 63;
            Bs[kk][n] = W[(size_t)(k0 + kk) * N + bn + n];
        }
        __syncthreads();
        #pragma unroll
        for (int kk = 0; kk < 32; kk++) {
            float4 a4 = *reinterpret_cast<const float4*>(&As[kk][ty * 4]);
            float4 b4 = *reinterpret_cast<const float4*>(&Bs[kk][tx * 4]);
            float a[4] = {a4.x, a4.y, a4.z, a4.w};
            float b[4] = {b4.x, b4.y, b4.z, b4.w};
            #pragma unroll
            for (int um = 0; um < 4; um++)
                #pragma unroll
                for (int un = 0; un < 4; un++) acc[um][un] += a[um] * b[un];
        }
        __syncthreads();
    }
    #pragma unroll
    for (int um = 0; um < 4; um++) {
        int m = bm + ty * 4 + um;
        #pragma unroll
        for (int un = 0; un < 4; un++) {
            int n = bn + tx * 4 + un;
            C[(size_t)m * N + n] = acc[um][un] + bias[n];
        }
    }
}

// out[M,512] = [A1 | A2][M,1024] @ W[1024,512] + bias[512], fp32 out.
__global__ __launch_bounds__(256) void gemm_cat(
    const float* __restrict__ A1, const float* __restrict__ A2,
    const float* __restrict__ W, const float* __restrict__ bias,
    float* __restrict__ C, int M, int N) {
    __shared__ __align__(16) float As[32][68];
    __shared__ __align__(16) float Bs[32][68];
    const int bm = blockIdx.y * 64, bn = blockIdx.x * 64;
    const int tid = threadIdx.x;
    const int tx = tid & 15, ty = tid >> 4;
    float acc[4][4] = {};
    const int K = 2 * Dn;
    for (int k0 = 0; k0 < K; k0 += 32) {
        const float* A = (k0 < Dn) ? A1 : A2;
        const int kc = k0 & (Dn - 1);
        #pragma unroll
        for (int l = 0; l < 8; l++) {
            int idx = tid + l * 256;
            int m = idx >> 5, kk = idx & 31;
            As[kk][m] = A[(size_t)(bm + m) * Dn + kc + kk];
        }
        #pragma unroll
        for (int l = 0; l < 8; l++) {
            int idx = tid + l * 256;
            int kk = idx >> 6, n = idx & 63;
            Bs[kk][n] = W[(size_t)(k0 + kk) * N + bn + n];
        }
        __syncthreads();
        #pragma unroll
        for (int kk = 0; kk < 32; kk++) {
            float4 a4 = *reinterpret_cast<const float4*>(&As[kk][ty * 4]);
            float4 b4 = *reinterpret_cast<const float4*>(&Bs[kk][tx * 4]);
            float a[4] = {a4.x, a4.y, a4.z, a4.w};
            float b[4] = {b4.x, b4.y, b4.z, b4.w};
            #pragma unroll
            for (int um = 0; um < 4; um++)
                #pragma unroll
                for (int un = 0; un < 4; un++) acc[um][un] += a[um] * b[un];
        }
        __syncthreads();
    }
    #pragma unroll
    for (int um = 0; um < 4; um++) {
        int m = bm + ty * 4 + um;
        #pragma unroll
        for (int un = 0; un < 4; un++) {
            int n = bn + tx * 4 + un;
            C[(size_t)m * N + n] = acc[um][un] + bias[n];
        }
    }
}

// ---------------------------------------------------------------------------
// Tiled distance-decay attention. One block (256 thr) per (b,h, 8-row tile).
// MODE: 0 = j<=i; 1 = j<i; 2 = i-19<=j<i.
// Phases: stage Q; per K-tile(128): stage K (float4), compute scores (2x2 reg
// block, float4 LDS reads, unroll 2); per-row softmax1 (32 thr/row, shuffle
// reductions + shfl_up scan), cumsum, decay rescale; softmax2 (+maxout coef);
// per V-tile: stage V, accumulate A.V (4-wave j-split, float4 V reads);
// combine partials, scale by coef, store.
// s_t columns XOR-swizzled; s_t row stride 1028 (e-reads conflict-free).
// ---------------------------------------------------------------------------
template <int MODE, bool MAXOUT>
__global__ __launch_bounds__(256) void attn_tile(
    const float* __restrict__ QK, const float* __restrict__ V,
    const float* __restrict__ gam, size_t g_off, float* __restrict__ O) {
    __shared__ __align__(16) float q_t[TQ * KS];   // 2176 B
    __shared__ __align__(16) float kv[TJ * KS];    // 34816 B (K then V)
    __shared__ float s_t[TQ * SRS];                // 32896 B (scores->s'->e)
    __shared__ __align__(16) float pv[4 * 512];    // 8192 B (A.V partials)
    __shared__ float rcoef[TQ];

    const int tid = threadIdx.x;
    const int i0 = blockIdx.x * TQ;
    const int bh = blockIdx.y;
    const int h = bh & (Hn - 1);
    const int b = bh >> 3;

    const float* Kbase = QK + (size_t)b * Sn * Dn + h * DKn;  // Q==K buffer
    const float* Vbase = V + (size_t)b * Sn * Dn + h * DKn;

    const int last_j = (MODE == 0) ? (i0 + TQ - 1) : (i0 + TQ - 2);
    const int jt_hi = (last_j >> 7) + 1;
    const int jt_lo = (MODE == 2) ? (max(0, i0 - 19) >> 7) : 0;

    // ---- stage Q (8 rows x 64) ----
    #pragma unroll
    for (int rep = 0; rep < 2; rep++) {
        int idx = tid + rep * 256;
        int r = idx >> 6, d = idx & 63;
        q_t[r * KS + d] = Kbase[(size_t)(i0 + r) * Dn + d];
    }

    // ---- phase 1: scores ----
    const int pc = tid & 63;
    const int pr = tid >> 6;  // wave id -> rows 2pr, 2pr+1
    const int r0 = 2 * pr, r1 = r0 + 1;
    for (int jt = jt_lo; jt < jt_hi; jt++) {
        __syncthreads();
        #pragma unroll
        for (int rep = 0; rep < 8; rep++) {
            int f = rep * 1024 + tid * 4;
            int row = f >> 6, d = f & 63;
            const float4 v4 = *reinterpret_cast<const float4*>(
                &Kbase[(size_t)(jt * TJ + row) * Dn + d]);
            *reinterpret_cast<float4*>(&kv[row * KS + d]) = v4;
        }
        __syncthreads();
        float d00 = 0.f, d01 = 0.f, d10 = 0.f, d11 = 0.f;
        #pragma unroll 2
        for (int d = 0; d < DKn; d += 4) {
            float4 qa = *reinterpret_cast<const float4*>(&q_t[r0 * KS + d]);
            float4 qb = *reinterpret_cast<const float4*>(&q_t[r1 * KS + d]);
            float4 ka = *reinterpret_cast<const float4*>(&kv[pc * KS + d]);
            float4 kb = *reinterpret_cast<const float4*>(&kv[(pc + 64) * KS + d]);
            d00 += qa.x * ka.x + qa.y * ka.y + qa.z * ka.z + qa.w * ka.w;
            d01 += qa.x * kb.x + qa.y * kb.y + qa.z * kb.z + qa.w * kb.w;
            d10 += qb.x * ka.x + qb.y * ka.y + qb.z * ka.z + qb.w * ka.w;
            d11 += qb.x * kb.x + qb.y * kb.y + qb.z * kb.z + qb.w * kb.w;
        }
        const int ja = jt * TJ + pc, jb = ja + 64;
        const int sja = sswz(ja), sjb = sswz(jb);
        s_t[r0 * SRS + sja] = d00 * 0.125f;
        s_t[r0 * SRS + sjb] = d01 * 0.125f;
        s_t[r1 * SRS + sja] = d10 * 0.125f;
        s_t[r1 * SRS + sjb] = d11 * 0.125f;
    }
    __syncthreads();

    // ---- phases 2-4: per-row softmax1 / cumsum / decay / softmax2 ----
    const int sr = tid >> 5, st = tid & 31;  // 8 rows x 32 threads
    const int i = i0 + sr;
    float* srow = &s_t[sr * SRS];
    const int c0 = st * 32;
    // valid-k range within this thread's 32-col chunk (contiguous)
    const int lastv = (MODE == 0) ? i : i - 1;  // last valid j
    int vlo = (MODE == 2) ? min(max((i - 19) - c0, 0), 32) : 0;
    int vhi = min(max(lastv + 1 - c0, 0), 32);
    if (vhi < vlo) vhi = vlo;
    // swizzled slot for logical col c0+k within this row: c0 + (k^st)
    #define SLOT(k) (c0 + ((k) ^ st))

    float lm = -3.4e38f;
    for (int k = vlo; k < vhi; k++) lm = fmaxf(lm, srow[SLOT(k)]);
    #pragma unroll
    for (int off = 16; off; off >>= 1) lm = fmaxf(lm, __shfl_xor(lm, off, 64));
    const float m1 = lm;

    float csum = 0.f;
    for (int k = vlo; k < vhi; k++) csum += __expf(srow[SLOT(k)] - m1);
    // segmented (32-lane) inclusive scan of chunk sums, no LDS / barriers
    float scan = csum;
    #pragma unroll
    for (int off = 1; off < 32; off <<= 1) {
        float o = __shfl_up(scan, off, 32);
        if (st >= off) scan += o;
    }
    const float Z1 = __shfl(scan, 31, 32);
    const float invZ1 = 1.f / fmaxf(Z1, 1e-37f);
    const float g = -fabsf(gam[g_off + h]);
    float run = scan - csum;  // exclusive prefix at chunk start
    for (int k = vlo; k < vhi; k++) {
        float s = srow[SLOT(k)];
        float p = __expf(s - m1);
        run += p;
        float cum = run * invZ1;
        float dist = sqrtf(fmaxf((1.f - cum) * (float)(i - (c0 + k)), 0.f));
        float decay = fminf(fmaxf(__expf(g * dist), 1e-5f), 1e5f);
        srow[SLOT(k)] = s * decay;
    }

    float lm2 = -3.4e38f;
    for (int k = vlo; k < vhi; k++) lm2 = fmaxf(lm2, srow[SLOT(k)]);
    #pragma unroll
    for (int off = 16; off; off >>= 1) lm2 = fmaxf(lm2, __shfl_xor(lm2, off, 64));
    float z2c = 0.f;
    for (int k = vlo; k < vhi; k++) {
        float e = __expf(srow[SLOT(k)] - lm2);
        srow[SLOT(k)] = e;
        z2c += e;
    }
    for (int k = 0; k < vlo; k++) srow[SLOT(k)] = 0.f;
    for (int k = vhi; k < 32; k++) srow[SLOT(k)] = 0.f;
    #pragma unroll
    for (int off = 16; off; off >>= 1) z2c += __shfl_xor(z2c, off, 64);
    if (st == 0)
        rcoef[sr] = (MAXOUT ? fminf(z2c, 5.f) : 1.f) / fmaxf(z2c, 1e-37f);
    #undef SLOT

    // ---- phase 5: A.V (wave w handles 32 j's per tile) ----
    const int w = tid >> 6, lane = tid & 63;
    const int gq = lane >> 4, lt = lane & 15;
    const int ar0 = 2 * gq, ar1 = ar0 + 1;
    float a0[4] = {0.f, 0.f, 0.f, 0.f}, a1[4] = {0.f, 0.f, 0.f, 0.f};
    for (int jt = jt_lo; jt < jt_hi; jt++) {
        __syncthreads();
        #pragma unroll
        for (int rep = 0; rep < 8; rep++) {
            int f = rep * 1024 + tid * 4;
            int row = f >> 6, d = f & 63;
            const float4 v4 = *reinterpret_cast<const float4*>(
                &Vbase[(size_t)(jt * TJ + row) * Dn + d]);
            *reinterpret_cast<float4*>(&kv[row * KS + d]) = v4;
        }
        __syncthreads();
        const int jbase = w * 32;
        #pragma unroll 4
        for (int jj = 0; jj < 32; jj++) {
            int j = jbase + jj;
            const int sgj = sswz(jt * TJ + j);
            float e0 = s_t[ar0 * SRS + sgj];
            float e1 = s_t[ar1 * SRS + sgj];
            const float4 vv =
                *reinterpret_cast<const float4*>(&kv[j * KS + 4 * lt]);
            a0[0] += e0 * vv.x; a0[1] += e0 * vv.y;
            a0[2] += e0 * vv.z; a0[3] += e0 * vv.w;
            a1[0] += e1 * vv.x; a1[1] += e1 * vv.y;
            a1[2] += e1 * vv.z; a1[3] += e1 * vv.w;
        }
    }
    *reinterpret_cast<float4*>(&pv[w * 512 + ar0 * 64 + 4 * lt]) =
        make_float4(a0[0], a0[1], a0[2], a0[3]);
    *reinterpret_cast<float4*>(&pv[w * 512 + ar1 * 64 + 4 * lt]) =
        make_float4(a1[0], a1[1], a1[2], a1[3]);
    __syncthreads();

    // ---- combine + store ----
    #pragma unroll
    for (int rep = 0; rep < 2; rep++) {
        int idx = tid + rep * 256;
        int r = idx >> 6, d = idx & 63;
        float v = (pv[idx] + pv[512 + idx] + pv[1024 + idx] + pv[1536 + idx]) *
                  rcoef[r];
        O[(size_t)(b * Sn + i0 + r) * Dn + h * DKn + d] = v;
    }
}

// ---------------------------------------------------------------------------
// out = LN(x + y) (fp32), one block per row of D=512.
// ---------------------------------------------------------------------------
__global__ __launch_bounds__(256) void add_ln(
    const float* __restrict__ X, const float* __restrict__ Y,
    const float* __restrict__ lnw, const float* __restrict__ lnb, size_t off,
    float* __restrict__ out) {
    __shared__ float red[4];
    const int row = blockIdx.x, tid = threadIdx.x;
    const size_t base = (size_t)row * Dn;
    float v0 = X[base + tid] + Y[base + tid];
    float v1 = X[base + tid + 256] + Y[base + tid + 256];
    const float mu = block_reduce_sum(v0 + v1, red) * (1.f / Dn);
    const float d0 = v0 - mu, d1 = v1 - mu;
    const float var = block_reduce_sum(d0 * d0 + d1 * d1, red) * (1.f / Dn);
    const float rs = rsqrtf(var + LN_EPS);
    out[base + tid] = d0 * rs * lnw[off + tid] + lnb[off + tid];
    out[base + tid + 256] = d1 * rs * lnw[off + tid + 256] + lnb[off + tid + 256];
}

// ---------------------------------------------------------------------------
// catA = LN2(hq + o); catB = LN2(hq + o + ow). All fp32, disjoint buffers.
// ---------------------------------------------------------------------------
__global__ __launch_bounds__(256) void cat_ln(
    const float* __restrict__ hq, const float* __restrict__ o,
    const float* __restrict__ ow, const float* __restrict__ lnw,
    const float* __restrict__ lnb, size_t off, float* __restrict__ catA,
    float* __restrict__ catB) {
    __shared__ float red[4];
    const int row = blockIdx.x, tid = threadIdx.x;
    const size_t base = (size_t)row * Dn;
    const float h0 = hq[base + tid] + o[base + tid];
    const float h1 = hq[base + tid + 256] + o[base + tid + 256];
    const float hw0 = h0 + ow[base + tid];
    const float hw1 = h1 + ow[base + tid + 256];
    const float w0 = lnw[off + tid], w1 = lnw[off + tid + 256];
    const float b0 = lnb[off + tid], b1 = lnb[off + tid + 256];

    float mu = block_reduce_sum(h0 + h1, red) * (1.f / Dn);
    float d0 = h0 - mu, d1 = h1 - mu;
    float var = block_reduce_sum(d0 * d0 + d1 * d1, red) * (1.f / Dn);
    float rs = rsqrtf(var + LN_EPS);
    catA[base + tid] = d0 * rs * w0 + b0;
    catA[base + tid + 256] = d1 * rs * w1 + b1;

    mu = block_reduce_sum(hw0 + hw1, red) * (1.f / Dn);
    d0 = hw0 - mu;
    d1 = hw1 - mu;
    var = block_reduce_sum(d0 * d0 + d1 * d1, red) * (1.f / Dn);
    rs = rsqrtf(var + LN_EPS);
    catB[base + tid] = d0 * rs * w0 + b0;
    catB[base + tid + 256] = d1 * rs * w1 + b1;
}

extern "C" void kernel_launch(void* const* d_in, const int* in_sizes, int n_in,
                              void* d_out, int out_size, void* d_ws,
                              size_t ws_size, hipStream_t stream) {
    const float* q_emb = (const float*)d_in[0];
    const float* s_emb = (const float*)d_in[1];
    const float* Wq = (const float*)d_in[2];
    const float* bq = (const float*)d_in[3];
    const float* Wqw = (const float*)d_in[4];
    const float* bqw = (const float*)d_in[5];
    const float* Wv = (const float*)d_in[6];
    const float* bv = (const float*)d_in[7];
    const float* Wo = (const float*)d_in[8];
    const float* bo = (const float*)d_in[9];
    const float* Wow = (const float*)d_in[10];
    const float* bow = (const float*)d_in[11];
    const float* gammas = (const float*)d_in[12];
    const float* ln_w = (const float*)d_in[13];
    const float* ln_b = (const float*)d_in[14];
    const float* Wc = (const float*)d_in[15];
    const float* bc = (const float*)d_in[16];
    // d_in[17] = lens: unused in the forward pass.

    const size_t BSD = (size_t)Bn * Sn * Dn;
    float* ws = (float*)d_ws;
    float* W0 = ws;
    float* W1 = ws + BSD;
    float* W2 = ws + 2 * BSD;

    float* out_main = (float*)d_out;     // out [B,S,D]
    float* out_hq = out_main + BSD;      // hq
    float* out_hs = out_main + 2 * BSD;  // hs

    const int rows = Bn * Sn;  // 8192
    const dim3 tpb(256);
    const dim3 ggemm(Dn / 64, rows / 64);
    const dim3 gattn(Sn / TQ, Bn * Hn);  // (128, 64)
    const dim3 grow(rows);
    const size_t DD = (size_t)Dn * Dn;

    // ---- Block 1: hq = LN0(q_emb + attn0(q_emb)) -> out_hq ----
    gemm_bias<<<ggemm, tpb, 0, stream>>>(q_emb, Wq, bq, W0, rows, Dn, Dn);
    gemm_bias<<<ggemm, tpb, 0, stream>>>(q_emb, Wv, bv, W1, rows, Dn, Dn);
    attn_tile<0, false><<<gattn, tpb, 0, stream>>>(W0, W1, gammas, 0, W2);
    gemm_bias<<<ggemm, tpb, 0, stream>>>(W2, Wo, bo, W0, rows, Dn, Dn);
    add_ln<<<grow, tpb, 0, stream>>>(q_emb, W0, ln_w, ln_b, 0, out_hq);

    // ---- Block 2: hs = LN1(s_emb + attn1(s_emb)) -> out_hs ----
    gemm_bias<<<ggemm, tpb, 0, stream>>>(s_emb, Wq + DD, bq + Dn, W0, rows, Dn, Dn);
    gemm_bias<<<ggemm, tpb, 0, stream>>>(s_emb, Wv + DD, bv + Dn, W1, rows, Dn, Dn);
    attn_tile<0, false><<<gattn, tpb, 0, stream>>>(W0, W1, gammas, Hn, W2);
    gemm_bias<<<ggemm, tpb, 0, stream>>>(W2, Wo + DD, bo + Dn, W0, rows, Dn, Dn);
    add_ln<<<grow, tpb, 0, stream>>>(s_emb, W0, ln_w, ln_b, Dn, out_hs);

    // ---- Block 3: xq=xk=hq, xv=hs ----
    gemm_bias<<<ggemm, tpb, 0, stream>>>(out_hq, Wq + 2 * DD, bq + 2 * Dn, W0, rows, Dn, Dn);
    gemm_bias<<<ggemm, tpb, 0, stream>>>(out_hs, Wv + 2 * DD, bv + 2 * Dn, W1, rows, Dn, Dn);
    attn_tile<1, true><<<gattn, tpb, 0, stream>>>(W0, W1, gammas, 2 * Hn, W2);
    gemm_bias<<<ggemm, tpb, 0, stream>>>(W2, Wo + 2 * DD, bo + 2 * Dn, out_main, rows, Dn, Dn);
    gemm_bias<<<ggemm, tpb, 0, stream>>>(out_hq, Wqw + 2 * DD, bqw + 2 * Dn, W0, rows, Dn, Dn);
    attn_tile<2, false><<<gattn, tpb, 0, stream>>>(W0, W1, gammas, 2 * Hn, W2);
    gemm_bias<<<ggemm, tpb, 0, stream>>>(W2, Wow, bow, W0, rows, Dn, Dn);
    // catA = LN2(hq + o) -> W1 ; catB = LN2(hq + o + ow) -> W2
    cat_ln<<<grow, tpb, 0, stream>>>(out_hq, out_main, W0, ln_w, ln_b, 2 * Dn, W1, W2);
    gemm_cat<<<ggemm, tpb, 0, stream>>>(W1, W2, Wc, bc, out_main, rows, Dn);
}

// Round 5
// 2458.158 us; speedup vs baseline: 1.7830x; 1.2142x over previous
//
#include <hip/hip_runtime.h>
#include <hip/hip_bf16.h>

// AKT_27917287424232 — 3-block distance-decay attention transformer.
// B=8, S=1024, D=512, H=8, dk=64. Inputs fp32, outputs fp32 (out,hq,hs).
// R7: tiled attention rewrite (8 query rows/block, LDS K/V tiles).
// R8: s_t XOR-swizzle, shuffle scan, bounded softmax loops. 4136->3553 us.
// R9 (REGRESSED, reverted): VGPR 88->136, occupancy halved. Stay <128 VGPR.
// R10: SRS=1028, __expf, contiguous softmax bounds. 3553->3177 us.
// R11: KS=68 float4 layout + low-register phase1, GEMM BK=32. 3177->2985 us.
// R12: split-bf16 MFMA GEMM (hi/lo interleaved along K', K'=2K; exact vs
// fp32 to ~2^-17) — 128x128 tile, 4 waves x (4x4) 16x16x32 bf16 MFMA frags;
// weights pre-packed transposed into ws (+2MB); A converted during staging.
// Attention kernels unchanged.

typedef __hip_bfloat16 bf16;
typedef __attribute__((ext_vector_type(8))) short short8;
typedef __attribute__((ext_vector_type(4))) float f32x4;

constexpr int Bn = 8, Sn = 1024, Dn = 512, Hn = 8, DKn = 64;
constexpr float LN_EPS = 1e-5f;
constexpr int TQ = 8;     // query rows per block
constexpr int TJ = 128;   // K/V tile rows
constexpr int KS = 68;    // LDS row stride for q/k/v tiles (16B aligned)
constexpr int SRS = 1028; // s_t row stride (4-bank offset per row)
constexpr int GKS = 36;   // gemm LDS uint stride (16B-aligned rows)

__device__ inline float wave_reduce_sum(float v) {
    #pragma unroll
    for (int off = 32; off; off >>= 1) v += __shfl_xor(v, off, 64);
    return v;
}
// Block of exactly 256 threads (4 waves). smem >= 4 floats.
__device__ inline float block_reduce_sum(float v, float* smem) {
    int lane = threadIdx.x & 63, wave = threadIdx.x >> 6;
    v = wave_reduce_sum(v);
    __syncthreads();
    if (lane == 0) smem[wave] = v;
    __syncthreads();
    return smem[0] + smem[1] + smem[2] + smem[3];
}

// s_t column swizzle: logical col j lives at j ^ ((j>>5)&31).
__device__ inline int sswz(int col) { return col ^ ((col >> 5) & 31); }

// Split fp32 into (hi,lo) bf16 pair packed in a uint: low 16 bits = hi
// (truncated bf16, = earlier k' element), high 16 bits = lo (RNE bf16 of
// residual). hi+lo represents x to ~2^-17 relative.
__device__ inline unsigned int pack_split(float x) {
    unsigned int bits = __float_as_uint(x);
    unsigned int hi_f = bits & 0xFFFF0000u;
    float lo = x - __uint_as_float(hi_f);
    unsigned int lb = __float_as_uint(lo);
    unsigned int lo_b = (lb + 0x7FFFu + ((lb >> 16) & 1u)) >> 16;
    return (hi_f >> 16) | (lo_b << 16);
}

// ---------------------------------------------------------------------------
// Pack W [K][512] fp32 -> WT [512][K] uints (transposed, hi/lo split).
// ---------------------------------------------------------------------------
__global__ __launch_bounds__(256) void pack_wt(
    const float* __restrict__ W, unsigned int* __restrict__ WT, int K) {
    int idx = blockIdx.x * 256 + threadIdx.x;  // over K*512
    int k = idx >> 9, n = idx & 511;
    WT[(size_t)n * K + k] = pack_split(W[idx]);
}

// ---------------------------------------------------------------------------
// C[M,512] = A[M,K] @ W[K,512] + bias, via split-bf16 MFMA over K'=2K.
// A1/A2: if K==1024, rows come from A1 (k<512) then A2 (k>=512); both have
// row stride 512. WT: packed transposed weights [512][K] uints.
// 128x128 tile, 4 waves (2x2), each 64x64 = 4x4 frags of 16x16x32 bf16.
// ---------------------------------------------------------------------------
__global__ __launch_bounds__(256) void gemm_mfma(
    const float* __restrict__ A1, const float* __restrict__ A2,
    const unsigned int* __restrict__ WT, const float* __restrict__ bias,
    float* __restrict__ C, int M, int N, int K) {
    __shared__ __align__(16) unsigned int Apk[128 * GKS];  // 18432 B
    __shared__ __align__(16) unsigned int Bpk[128 * GKS];  // 18432 B
    const int bm = blockIdx.y * 128, bn = blockIdx.x * 128;
    const int tid = threadIdx.x;
    const int wv = tid >> 6, lane = tid & 63;
    const int wr = (wv >> 1) * 64, wc = (wv & 1) * 64;
    const int fr = lane & 15, fg = lane >> 4;  // frag row(col), k-group

    f32x4 acc[4][4] = {};  // acc[fm][fn]

    const int kq = (tid & 7) * 4;    // uint/k offset within 32-k tile
    const int rbase = tid >> 3;      // 0..31

    for (int k0 = 0; k0 < K; k0 += 32) {
        const float* Ab = (k0 >= 512) ? A2 : A1;  // K==512 -> always A1
        const int kc = k0 & 511;
        // ---- stage A: 128x32 fp32 -> packed uints ----
        #pragma unroll
        for (int rep = 0; rep < 4; rep++) {
            int row = rep * 32 + rbase;
            const float4 a4 = *reinterpret_cast<const float4*>(
                &Ab[(size_t)(bm + row) * 512 + kc + kq]);
            uint4 p;
            p.x = pack_split(a4.x);
            p.y = pack_split(a4.y);
            p.z = pack_split(a4.z);
            p.w = pack_split(a4.w);
            *reinterpret_cast<uint4*>(&Apk[row * GKS + kq]) = p;
        }
        // ---- stage B: WT[n][k] uints, rows bn..bn+127, cols k0..k0+31 ----
        #pragma unroll
        for (int rep = 0; rep < 4; rep++) {
            int n = rep * 32 + rbase;
            const uint4 b4 = *reinterpret_cast<const uint4*>(
                &WT[(size_t)(bn + n) * K + k0 + kq]);
            *reinterpret_cast<uint4*>(&Bpk[n * GKS + kq]) = b4;
        }
        __syncthreads();
        // ---- 2 MFMA k-steps of K'=32 (16 orig k) each ----
        #pragma unroll
        for (int kk = 0; kk < 2; kk++) {
            short8 af[4], bf[4];
            #pragma unroll
            for (int f = 0; f < 4; f++) {
                af[f] = *reinterpret_cast<const short8*>(
                    &Apk[(wr + f * 16 + fr) * GKS + kk * 16 + fg * 4]);
                bf[f] = *reinterpret_cast<const short8*>(
                    &Bpk[(wc + f * 16 + fr) * GKS + kk * 16 + fg * 4]);
            }
            #pragma unroll
            for (int fm = 0; fm < 4; fm++)
                #pragma unroll
                for (int fn = 0; fn < 4; fn++)
                    acc[fm][fn] = __builtin_amdgcn_mfma_f32_16x16x32_bf16(
                        af[fm], bf[fn], acc[fm][fn], 0, 0, 0);
        }
        __syncthreads();
    }
    // ---- epilogue: bias + store (C/D: col=lane&15, row=(lane>>4)*4+r) ----
    #pragma unroll
    for (int fn = 0; fn < 4; fn++) {
        const int col = bn + wc + fn * 16 + fr;
        const float bv = bias[col];
        #pragma unroll
        for (int fm = 0; fm < 4; fm++) {
            const int row0 = bm + wr + fm * 16 + fg * 4;
            #pragma unroll
            for (int r = 0; r < 4; r++)
                C[(size_t)(row0 + r) * N + col] = acc[fm][fn][r] + bv;
        }
    }
}

// ---------------------------------------------------------------------------
// Tiled distance-decay attention (unchanged from R11). One block (256 thr)
// per (b,h, 8-row tile). MODE: 0 = j<=i; 1 = j<i; 2 = i-19<=j<i.
// ---------------------------------------------------------------------------
template <int MODE, bool MAXOUT>
__global__ __launch_bounds__(256) void attn_tile(
    const float* __restrict__ QK, const float* __restrict__ V,
    const float* __restrict__ gam, size_t g_off, float* __restrict__ O) {
    __shared__ __align__(16) float q_t[TQ * KS];   // 2176 B
    __shared__ __align__(16) float kv[TJ * KS];    // 34816 B (K then V)
    __shared__ float s_t[TQ * SRS];                // 32896 B (scores->s'->e)
    __shared__ __align__(16) float pv[4 * 512];    // 8192 B (A.V partials)
    __shared__ float rcoef[TQ];

    const int tid = threadIdx.x;
    const int i0 = blockIdx.x * TQ;
    const int bh = blockIdx.y;
    const int h = bh & (Hn - 1);
    const int b = bh >> 3;

    const float* Kbase = QK + (size_t)b * Sn * Dn + h * DKn;  // Q==K buffer
    const float* Vbase = V + (size_t)b * Sn * Dn + h * DKn;

    const int last_j = (MODE == 0) ? (i0 + TQ - 1) : (i0 + TQ - 2);
    const int jt_hi = (last_j >> 7) + 1;
    const int jt_lo = (MODE == 2) ? (max(0, i0 - 19) >> 7) : 0;

    // ---- stage Q (8 rows x 64) ----
    #pragma unroll
    for (int rep = 0; rep < 2; rep++) {
        int idx = tid + rep * 256;
        int r = idx >> 6, d = idx & 63;
        q_t[r * KS + d] = Kbase[(size_t)(i0 + r) * Dn + d];
    }

    // ---- phase 1: scores ----
    const int pc = tid & 63;
    const int pr = tid >> 6;  // wave id -> rows 2pr, 2pr+1
    const int r0 = 2 * pr, r1 = r0 + 1;
    for (int jt = jt_lo; jt < jt_hi; jt++) {
        __syncthreads();
        #pragma unroll
        for (int rep = 0; rep < 8; rep++) {
            int f = rep * 1024 + tid * 4;
            int row = f >> 6, d = f & 63;
            const float4 v4 = *reinterpret_cast<const float4*>(
                &Kbase[(size_t)(jt * TJ + row) * Dn + d]);
            *reinterpret_cast<float4*>(&kv[row * KS + d]) = v4;
        }
        __syncthreads();
        float d00 = 0.f, d01 = 0.f, d10 = 0.f, d11 = 0.f;
        #pragma unroll 2
        for (int d = 0; d < DKn; d += 4) {
            float4 qa = *reinterpret_cast<const float4*>(&q_t[r0 * KS + d]);
            float4 qb = *reinterpret_cast<const float4*>(&q_t[r1 * KS + d]);
            float4 ka = *reinterpret_cast<const float4*>(&kv[pc * KS + d]);
            float4 kb = *reinterpret_cast<const float4*>(&kv[(pc + 64) * KS + d]);
            d00 += qa.x * ka.x + qa.y * ka.y + qa.z * ka.z + qa.w * ka.w;
            d01 += qa.x * kb.x + qa.y * kb.y + qa.z * kb.z + qa.w * kb.w;
            d10 += qb.x * ka.x + qb.y * ka.y + qb.z * ka.z + qb.w * ka.w;
            d11 += qb.x * kb.x + qb.y * kb.y + qb.z * kb.z + qb.w * kb.w;
        }
        const int ja = jt * TJ + pc, jb = ja + 64;
        const int sja = sswz(ja), sjb = sswz(jb);
        s_t[r0 * SRS + sja] = d00 * 0.125f;
        s_t[r0 * SRS + sjb] = d01 * 0.125f;
        s_t[r1 * SRS + sja] = d10 * 0.125f;
        s_t[r1 * SRS + sjb] = d11 * 0.125f;
    }
    __syncthreads();

    // ---- phases 2-4: per-row softmax1 / cumsum / decay / softmax2 ----
    const int sr = tid >> 5, st = tid & 31;  // 8 rows x 32 threads
    const int i = i0 + sr;
    float* srow = &s_t[sr * SRS];
    const int c0 = st * 32;
    const int lastv = (MODE == 0) ? i : i - 1;  // last valid j
    int vlo = (MODE == 2) ? min(max((i - 19) - c0, 0), 32) : 0;
    int vhi = min(max(lastv + 1 - c0, 0), 32);
    if (vhi < vlo) vhi = vlo;
    #define SLOT(k) (c0 + ((k) ^ st))

    float lm = -3.4e38f;
    for (int k = vlo; k < vhi; k++) lm = fmaxf(lm, srow[SLOT(k)]);
    #pragma unroll
    for (int off = 16; off; off >>= 1) lm = fmaxf(lm, __shfl_xor(lm, off, 64));
    const float m1 = lm;

    float csum = 0.f;
    for (int k = vlo; k < vhi; k++) csum += __expf(srow[SLOT(k)] - m1);
    float scan = csum;
    #pragma unroll
    for (int off = 1; off < 32; off <<= 1) {
        float o = __shfl_up(scan, off, 32);
        if (st >= off) scan += o;
    }
    const float Z1 = __shfl(scan, 31, 32);
    const float invZ1 = 1.f / fmaxf(Z1, 1e-37f);
    const float g = -fabsf(gam[g_off + h]);
    float run = scan - csum;  // exclusive prefix at chunk start
    for (int k = vlo; k < vhi; k++) {
        float s = srow[SLOT(k)];
        float p = __expf(s - m1);
        run += p;
        float cum = run * invZ1;
        float dist = sqrtf(fmaxf((1.f - cum) * (float)(i - (c0 + k)), 0.f));
        float decay = fminf(fmaxf(__expf(g * dist), 1e-5f), 1e5f);
        srow[SLOT(k)] = s * decay;
    }

    float lm2 = -3.4e38f;
    for (int k = vlo; k < vhi; k++) lm2 = fmaxf(lm2, srow[SLOT(k)]);
    #pragma unroll
    for (int off = 16; off; off >>= 1) lm2 = fmaxf(lm2, __shfl_xor(lm2, off, 64));
    float z2c = 0.f;
    for (int k = vlo; k < vhi; k++) {
        float e = __expf(srow[SLOT(k)] - lm2);
        srow[SLOT(k)] = e;
        z2c += e;
    }
    for (int k = 0; k < vlo; k++) srow[SLOT(k)] = 0.f;
    for (int k = vhi; k < 32; k++) srow[SLOT(k)] = 0.f;
    #pragma unroll
    for (int off = 16; off; off >>= 1) z2c += __shfl_xor(z2c, off, 64);
    if (st == 0)
        rcoef[sr] = (MAXOUT ? fminf(z2c, 5.f) : 1.f) / fmaxf(z2c, 1e-37f);
    #undef SLOT

    // ---- phase 5: A.V (wave w handles 32 j's per tile) ----
    const int w = tid >> 6, lane = tid & 63;
    const int gq = lane >> 4, lt = lane & 15;
    const int ar0 = 2 * gq, ar1 = ar0 + 1;
    float a0[4] = {0.f, 0.f, 0.f, 0.f}, a1[4] = {0.f, 0.f, 0.f, 0.f};
    for (int jt = jt_lo; jt < jt_hi; jt++) {
        __syncthreads();
        #pragma unroll
        for (int rep = 0; rep < 8; rep++) {
            int f = rep * 1024 + tid * 4;
            int row = f >> 6, d = f & 63;
            const float4 v4 = *reinterpret_cast<const float4*>(
                &Vbase[(size_t)(jt * TJ + row) * Dn + d]);
            *reinterpret_cast<float4*>(&kv[row * KS + d]) = v4;
        }
        __syncthreads();
        const int jbase = w * 32;
        #pragma unroll 4
        for (int jj = 0; jj < 32; jj++) {
            int j = jbase + jj;
            const int sgj = sswz(jt * TJ + j);
            float e0 = s_t[ar0 * SRS + sgj];
            float e1 = s_t[ar1 * SRS + sgj];
            const float4 vv =
                *reinterpret_cast<const float4*>(&kv[j * KS + 4 * lt]);
            a0[0] += e0 * vv.x; a0[1] += e0 * vv.y;
            a0[2] += e0 * vv.z; a0[3] += e0 * vv.w;
            a1[0] += e1 * vv.x; a1[1] += e1 * vv.y;
            a1[2] += e1 * vv.z; a1[3] += e1 * vv.w;
        }
    }
    *reinterpret_cast<float4*>(&pv[w * 512 + ar0 * 64 + 4 * lt]) =
        make_float4(a0[0], a0[1], a0[2], a0[3]);
    *reinterpret_cast<float4*>(&pv[w * 512 + ar1 * 64 + 4 * lt]) =
        make_float4(a1[0], a1[1], a1[2], a1[3]);
    __syncthreads();

    // ---- combine + store ----
    #pragma unroll
    for (int rep = 0; rep < 2; rep++) {
        int idx = tid + rep * 256;
        int r = idx >> 6, d = idx & 63;
        float v = (pv[idx] + pv[512 + idx] + pv[1024 + idx] + pv[1536 + idx]) *
                  rcoef[r];
        O[(size_t)(b * Sn + i0 + r) * Dn + h * DKn + d] = v;
    }
}

// ---------------------------------------------------------------------------
// out = LN(x + y) (fp32), one block per row of D=512.
// ---------------------------------------------------------------------------
__global__ __launch_bounds__(256) void add_ln(
    const float* __restrict__ X, const float* __restrict__ Y,
    const float* __restrict__ lnw, const float* __restrict__ lnb, size_t off,
    float* __restrict__ out) {
    __shared__ float red[4];
    const int row = blockIdx.x, tid = threadIdx.x;
    const size_t base = (size_t)row * Dn;
    float v0 = X[base + tid] + Y[base + tid];
    float v1 = X[base + tid + 256] + Y[base + tid + 256];
    const float mu = block_reduce_sum(v0 + v1, red) * (1.f / Dn);
    const float d0 = v0 - mu, d1 = v1 - mu;
    const float var = block_reduce_sum(d0 * d0 + d1 * d1, red) * (1.f / Dn);
    const float rs = rsqrtf(var + LN_EPS);
    out[base + tid] = d0 * rs * lnw[off + tid] + lnb[off + tid];
    out[base + tid + 256] = d1 * rs * lnw[off + tid + 256] + lnb[off + tid + 256];
}

// ---------------------------------------------------------------------------
// catA = LN2(hq + o); catB = LN2(hq + o + ow). All fp32, disjoint buffers.
// ---------------------------------------------------------------------------
__global__ __launch_bounds__(256) void cat_ln(
    const float* __restrict__ hq, const float* __restrict__ o,
    const float* __restrict__ ow, const float* __restrict__ lnw,
    const float* __restrict__ lnb, size_t off, float* __restrict__ catA,
    float* __restrict__ catB) {
    __shared__ float red[4];
    const int row = blockIdx.x, tid = threadIdx.x;
    const size_t base = (size_t)row * Dn;
    const float h0 = hq[base + tid] + o[base + tid];
    const float h1 = hq[base + tid + 256] + o[base + tid + 256];
    const float hw0 = h0 + ow[base + tid];
    const float hw1 = h1 + ow[base + tid + 256];
    const float w0 = lnw[off + tid], w1 = lnw[off + tid + 256];
    const float b0 = lnb[off + tid], b1 = lnb[off + tid + 256];

    float mu = block_reduce_sum(h0 + h1, red) * (1.f / Dn);
    float d0 = h0 - mu, d1 = h1 - mu;
    float var = block_reduce_sum(d0 * d0 + d1 * d1, red) * (1.f / Dn);
    float rs = rsqrtf(var + LN_EPS);
    catA[base + tid] = d0 * rs * w0 + b0;
    catA[base + tid + 256] = d1 * rs * w1 + b1;

    mu = block_reduce_sum(hw0 + hw1, red) * (1.f / Dn);
    d0 = hw0 - mu;
    d1 = hw1 - mu;
    var = block_reduce_sum(d0 * d0 + d1 * d1, red) * (1.f / Dn);
    rs = rsqrtf(var + LN_EPS);
    catB[base + tid] = d0 * rs * w0 + b0;
    catB[base + tid + 256] = d1 * rs * w1 + b1;
}

extern "C" void kernel_launch(void* const* d_in, const int* in_sizes, int n_in,
                              void* d_out, int out_size, void* d_ws,
                              size_t ws_size, hipStream_t stream) {
    const float* q_emb = (const float*)d_in[0];
    const float* s_emb = (const float*)d_in[1];
    const float* Wq = (const float*)d_in[2];
    const float* bq = (const float*)d_in[3];
    const float* Wqw = (const float*)d_in[4];
    const float* bqw = (const float*)d_in[5];
    const float* Wv = (const float*)d_in[6];
    const float* bv = (const float*)d_in[7];
    const float* Wo = (const float*)d_in[8];
    const float* bo = (const float*)d_in[9];
    const float* Wow = (const float*)d_in[10];
    const float* bow = (const float*)d_in[11];
    const float* gammas = (const float*)d_in[12];
    const float* ln_w = (const float*)d_in[13];
    const float* ln_b = (const float*)d_in[14];
    const float* Wc = (const float*)d_in[15];
    const float* bc = (const float*)d_in[16];
    // d_in[17] = lens: unused in the forward pass.

    const size_t BSD = (size_t)Bn * Sn * Dn;
    float* ws = (float*)d_ws;
    float* W0 = ws;
    float* W1 = ws + BSD;
    float* W2 = ws + 2 * BSD;
    unsigned int* Wpk = (unsigned int*)(ws + 3 * BSD);  // 2 MB packed weights

    float* out_main = (float*)d_out;     // out [B,S,D]
    float* out_hq = out_main + BSD;      // hq
    float* out_hs = out_main + 2 * BSD;  // hs

    const int rows = Bn * Sn;  // 8192
    const dim3 tpb(256);
    const dim3 ggemm(Dn / 128, rows / 128);  // (4, 64)
    const dim3 gattn(Sn / TQ, Bn * Hn);      // (128, 64)
    const dim3 grow(rows);
    const size_t DD = (size_t)Dn * Dn;
    const int gpack = (Dn * Dn) / 256;       // 1024 blocks per 512x512 W

    #define PK(Wp, Kk) pack_wt<<<(Kk) * 2, tpb, 0, stream>>>((Wp), Wpk, (Kk))
    #define GM(A, Bi, Cc) \
        gemm_mfma<<<ggemm, tpb, 0, stream>>>((A), (A), Wpk, (Bi), (Cc), rows, Dn, Dn)

    // ---- Block 1: hq = LN0(q_emb + attn0(q_emb)) -> out_hq ----
    PK(Wq, Dn);               GM(q_emb, bq, W0);
    PK(Wv, Dn);               GM(q_emb, bv, W1);
    attn_tile<0, false><<<gattn, tpb, 0, stream>>>(W0, W1, gammas, 0, W2);
    PK(Wo, Dn);               GM(W2, bo, W0);
    add_ln<<<grow, tpb, 0, stream>>>(q_emb, W0, ln_w, ln_b, 0, out_hq);

    // ---- Block 2: hs = LN1(s_emb + attn1(s_emb)) -> out_hs ----
    PK(Wq + DD, Dn);          GM(s_emb, bq + Dn, W0);
    PK(Wv + DD, Dn);          GM(s_emb, bv + Dn, W1);
    attn_tile<0, false><<<gattn, tpb, 0, stream>>>(W0, W1, gammas, Hn, W2);
    PK(Wo + DD, Dn);          GM(W2, bo + Dn, W0);
    add_ln<<<grow, tpb, 0, stream>>>(s_emb, W0, ln_w, ln_b, Dn, out_hs);

    // ---- Block 3: xq=xk=hq, xv=hs ----
    PK(Wq + 2 * DD, Dn);      GM(out_hq, bq + 2 * Dn, W0);
    PK(Wv + 2 * DD, Dn);      GM(out_hs, bv + 2 * Dn, W1);
    attn_tile<1, true><<<gattn, tpb, 0, stream>>>(W0, W1, gammas, 2 * Hn, W2);
    PK(Wo + 2 * DD, Dn);      GM(W2, bo + 2 * Dn, out_main);
    PK(Wqw + 2 * DD, Dn);     GM(out_hq, bqw + 2 * Dn, W0);
    attn_tile<2, false><<<gattn, tpb, 0, stream>>>(W0, W1, gammas, 2 * Hn, W2);
    PK(Wow, Dn);              GM(W2, bow, W0);
    // catA = LN2(hq + o) -> W1 ; catB = LN2(hq + o + ow) -> W2
    cat_ln<<<grow, tpb, 0, stream>>>(out_hq, out_main, W0, ln_w, ln_b, 2 * Dn, W1, W2);
    // out = [catA | catB] @ Wc + bc  (K=1024)
    PK(Wc, 2 * Dn);
    gemm_mfma<<<ggemm, tpb, 0, stream>>>(W1, W2, Wpk, bc, out_main, rows, Dn,
                                         2 * Dn);
    #undef PK
    #undef GM
    (void)gpack;
}

// Round 6
// 2000.669 us; speedup vs baseline: 2.1907x; 1.2287x over previous
//
#include <hip/hip_runtime.h>
#include <hip/hip_bf16.h>

// AKT_27917287424232 — 3-block distance-decay attention transformer.
// B=8, S=1024, D=512, H=8, dk=64. Inputs fp32, outputs fp32 (out,hq,hs).
// R8: s_t XOR-swizzle, shuffle scan, bounded softmax loops. 4136->3553 us.
// R9 (REGRESSED, reverted): VGPR 88->136, occupancy halved. Stay <128 VGPR.
// R10: SRS=1028, __expf, contiguous softmax bounds. 3553->3177 us.
// R11: KS=68 float4 layout + low-register phase1, GEMM BK=32. 3177->2985 us.
// R12: split-bf16 MFMA GEMM (exact to ~2^-17). 2985->2458 us.
// R13: split-bf16 MFMA attention. TQ=16, 512 thr (8 waves), 1 block/CU
// (111KB LDS). QK^T: Q/K pre-packed (GEMM epilogue PACK), per-tile 4 MFMA +
// b128 frags per wave. PV: V transpose-packed [bh][d][j] (pack_vt), P packed
// in-place by softmax final pass, 4 MFMA/tile/wave. Softmax unchanged
// (s_u uint LDS + bitcast accessors kill TBAA hazards).

typedef __hip_bfloat16 bf16;
typedef __attribute__((ext_vector_type(8))) short short8;
typedef __attribute__((ext_vector_type(4))) float f32x4;

constexpr int Bn = 8, Sn = 1024, Dn = 512, Hn = 8, DKn = 64;
constexpr float LN_EPS = 1e-5f;
constexpr int TQ = 16;    // query rows per block
constexpr int TJ = 128;   // K/V tile rows (j per tile)
constexpr int SRS = 1028; // s_u row stride (4-bank offset per row)
constexpr int GKS = 36;   // gemm LDS uint stride
constexpr int KQS = 68;   // attn K/Q packed LDS uint stride (16B aligned)
constexpr int VTS = 132;  // attn VT packed LDS uint stride (16B aligned)

__device__ inline float wave_reduce_sum(float v) {
    #pragma unroll
    for (int off = 32; off; off >>= 1) v += __shfl_xor(v, off, 64);
    return v;
}
// Block of exactly 256 threads (4 waves). smem >= 4 floats.
__device__ inline float block_reduce_sum(float v, float* smem) {
    int lane = threadIdx.x & 63, wave = threadIdx.x >> 6;
    v = wave_reduce_sum(v);
    __syncthreads();
    if (lane == 0) smem[wave] = v;
    __syncthreads();
    return smem[0] + smem[1] + smem[2] + smem[3];
}

// s_t column swizzle: logical col j lives at j ^ ((j>>5)&31).
__device__ inline int sswz(int col) { return col ^ ((col >> 5) & 31); }

// Split fp32 into (hi,lo) bf16 pair packed in a uint: low 16 bits = hi
// (truncated bf16 = even k' element), high 16 bits = lo (RNE bf16 of
// residual). hi+lo represents x to ~2^-17 relative.
__device__ inline unsigned int pack_split(float x) {
    unsigned int bits = __float_as_uint(x);
    unsigned int hi_f = bits & 0xFFFF0000u;
    float lo = x - __uint_as_float(hi_f);
    unsigned int lb = __float_as_uint(lo);
    unsigned int lo_b = (lb + 0x7FFFu + ((lb >> 16) & 1u)) >> 16;
    return (hi_f >> 16) | (lo_b << 16);
}

// ---------------------------------------------------------------------------
// Pack W [K][512] fp32 -> WT [512][K] uints (transposed, hi/lo split).
// ---------------------------------------------------------------------------
__global__ __launch_bounds__(256) void pack_wt(
    const float* __restrict__ W, unsigned int* __restrict__ WT, int K) {
    int idx = blockIdx.x * 256 + threadIdx.x;  // over K*512
    int k = idx >> 9, n = idx & 511;
    WT[(size_t)n * K + k] = pack_split(W[idx]);
}

// ---------------------------------------------------------------------------
// Pack V [B,S,D] fp32 -> VT [bh][d][j] uints (per-head transpose + split).
// Grid (16 j-tiles, 64 bh), 256 threads, LDS 64x64 tile.
// ---------------------------------------------------------------------------
__global__ __launch_bounds__(256) void pack_vt(
    const float* __restrict__ V, unsigned int* __restrict__ VT) {
    __shared__ unsigned int tl[64 * 65];
    const int tid = threadIdx.x;
    const int j0 = blockIdx.x * 64;
    const int bh = blockIdx.y;
    const int b = bh >> 3, h = bh & 7;
    #pragma unroll
    for (int rep = 0; rep < 16; rep++) {
        int idx = rep * 256 + tid;
        int jj = idx >> 6, d = idx & 63;
        tl[d * 65 + jj] =
            pack_split(V[(size_t)(b * Sn + j0 + jj) * Dn + h * DKn + d]);
    }
    __syncthreads();
    #pragma unroll
    for (int rep = 0; rep < 16; rep++) {
        int idx = rep * 256 + tid;
        int d = idx >> 6, jj = idx & 63;
        VT[(size_t)(bh * DKn + d) * Sn + j0 + jj] = tl[d * 65 + jj];
    }
}

// ---------------------------------------------------------------------------
// C[M,512] = A[M,K] @ W[K,512] + bias, via split-bf16 MFMA over K'=2K.
// PACK: write pack_split(result) as uint (for attn Q/K consumption).
// 128x128 tile, 4 waves (2x2), each 64x64 = 4x4 frags of 16x16x32 bf16.
// ---------------------------------------------------------------------------
template <bool PACK>
__global__ __launch_bounds__(256) void gemm_mfma(
    const float* __restrict__ A1, const float* __restrict__ A2,
    const unsigned int* __restrict__ WT, const float* __restrict__ bias,
    void* __restrict__ Cout, int M, int N, int K) {
    __shared__ __align__(16) unsigned int Apk[128 * GKS];  // 18432 B
    __shared__ __align__(16) unsigned int Bpk[128 * GKS];  // 18432 B
    const int bm = blockIdx.y * 128, bn = blockIdx.x * 128;
    const int tid = threadIdx.x;
    const int wv = tid >> 6, lane = tid & 63;
    const int wr = (wv >> 1) * 64, wc = (wv & 1) * 64;
    const int fr = lane & 15, fg = lane >> 4;  // frag row(col), k-group

    f32x4 acc[4][4] = {};  // acc[fm][fn]

    const int kq = (tid & 7) * 4;    // uint/k offset within 32-k tile
    const int rbase = tid >> 3;      // 0..31

    for (int k0 = 0; k0 < K; k0 += 32) {
        const float* Ab = (k0 >= 512) ? A2 : A1;  // K==512 -> always A1
        const int kc = k0 & 511;
        #pragma unroll
        for (int rep = 0; rep < 4; rep++) {
            int row = rep * 32 + rbase;
            const float4 a4 = *reinterpret_cast<const float4*>(
                &Ab[(size_t)(bm + row) * 512 + kc + kq]);
            uint4 p;
            p.x = pack_split(a4.x);
            p.y = pack_split(a4.y);
            p.z = pack_split(a4.z);
            p.w = pack_split(a4.w);
            *reinterpret_cast<uint4*>(&Apk[row * GKS + kq]) = p;
        }
        #pragma unroll
        for (int rep = 0; rep < 4; rep++) {
            int n = rep * 32 + rbase;
            const uint4 b4 = *reinterpret_cast<const uint4*>(
                &WT[(size_t)(bn + n) * K + k0 + kq]);
            *reinterpret_cast<uint4*>(&Bpk[n * GKS + kq]) = b4;
        }
        __syncthreads();
        #pragma unroll
        for (int kk = 0; kk < 2; kk++) {
            short8 af[4], bf[4];
            #pragma unroll
            for (int f = 0; f < 4; f++) {
                af[f] = *reinterpret_cast<const short8*>(
                    &Apk[(wr + f * 16 + fr) * GKS + kk * 16 + fg * 4]);
                bf[f] = *reinterpret_cast<const short8*>(
                    &Bpk[(wc + f * 16 + fr) * GKS + kk * 16 + fg * 4]);
            }
            #pragma unroll
            for (int fm = 0; fm < 4; fm++)
                #pragma unroll
                for (int fn = 0; fn < 4; fn++)
                    acc[fm][fn] = __builtin_amdgcn_mfma_f32_16x16x32_bf16(
                        af[fm], bf[fn], acc[fm][fn], 0, 0, 0);
        }
        __syncthreads();
    }
    // epilogue: bias + store (C/D: col=lane&15, row=(lane>>4)*4+r)
    #pragma unroll
    for (int fn = 0; fn < 4; fn++) {
        const int col = bn + wc + fn * 16 + fr;
        const float bv = bias[col];
        #pragma unroll
        for (int fm = 0; fm < 4; fm++) {
            const int row0 = bm + wr + fm * 16 + fg * 4;
            #pragma unroll
            for (int r = 0; r < 4; r++) {
                float v = acc[fm][fn][r] + bv;
                if (PACK)
                    ((unsigned int*)Cout)[(size_t)(row0 + r) * N + col] =
                        pack_split(v);
                else
                    ((float*)Cout)[(size_t)(row0 + r) * N + col] = v;
            }
        }
    }
}

// ---------------------------------------------------------------------------
// MFMA distance-decay attention. One block (512 thr, 8 waves) per
// (b,h, 16-row tile). MODE: 0 = j<=i; 1 = j<i; 2 = i-19<=j<i.
// QKu: packed-split Q/K buffer [b,s,h*64+d] uints. VT: packed-split V
// transposed [bh][d][j] uints. Scores in s_u (fp32 bits), softmax identical
// to R10-12; final pass re-packs e as split-bf16 in place for the PV MFMA.
// ---------------------------------------------------------------------------
template <int MODE, bool MAXOUT>
__global__ __launch_bounds__(512) void attn_tile(
    const unsigned int* __restrict__ QKu, const unsigned int* __restrict__ VT,
    const float* __restrict__ gam, size_t g_off, float* __restrict__ O) {
    __shared__ __align__(16) unsigned int qpk[TQ * KQS];  // 4352 B
    __shared__ __align__(16) unsigned int kvu[TJ * KQS];  // 34816 B (K / VT)
    __shared__ unsigned int s_u[TQ * SRS];                // 65792 B
    __shared__ __align__(16) float pv[8 * 256];           // 8192 B
    __shared__ float rcoef[TQ];

    const int tid = threadIdx.x;
    const int i0 = blockIdx.x * TQ;
    const int bh = blockIdx.y;
    const int h = bh & (Hn - 1);
    const int b = bh >> 3;
    const int w = tid >> 6, lane = tid & 63;
    const int fr = lane & 15, fg = lane >> 4;

    const unsigned int* Kb = QKu + (size_t)b * Sn * Dn + h * DKn;
    const unsigned int* Vb = VT + (size_t)bh * DKn * Sn;

    const int last_j = (MODE == 0) ? (i0 + TQ - 1) : (i0 + TQ - 2);
    const int jt_hi = (last_j >> 7) + 1;
    const int jt_lo = (MODE == 2) ? (max(0, i0 - 19) >> 7) : 0;

    // ---- stage Q (16 rows x 64 packed uints) ----
    #pragma unroll
    for (int rep = 0; rep < 2; rep++) {
        int idx = rep * 512 + tid;
        int r = idx >> 6, du = idx & 63;
        qpk[r * KQS + du] = Kb[(size_t)(i0 + r) * Dn + du];
    }

    // ---- phase 1: QK^T via MFMA (wave w owns j-group w*16..w*16+15) ----
    for (int jt = jt_lo; jt < jt_hi; jt++) {
        __syncthreads();
        #pragma unroll
        for (int rep = 0; rep < 4; rep++) {
            int idx = rep * 2048 + tid * 4;
            int row = idx >> 6, du = idx & 63;
            const uint4 v4 = *reinterpret_cast<const uint4*>(
                &Kb[(size_t)(jt * TJ + row) * Dn + du]);
            *reinterpret_cast<uint4*>(&kvu[row * KQS + du]) = v4;
        }
        __syncthreads();
        f32x4 acc = {0.f, 0.f, 0.f, 0.f};
        #pragma unroll
        for (int kk = 0; kk < 4; kk++) {
            short8 af = *reinterpret_cast<const short8*>(
                &qpk[fr * KQS + kk * 16 + fg * 4]);
            short8 bf = *reinterpret_cast<const short8*>(
                &kvu[(w * 16 + fr) * KQS + kk * 16 + fg * 4]);
            acc = __builtin_amdgcn_mfma_f32_16x16x32_bf16(af, bf, acc, 0, 0, 0);
        }
        const int sj = sswz(jt * TJ + w * 16 + fr);
        #pragma unroll
        for (int r = 0; r < 4; r++)
            s_u[(fg * 4 + r) * SRS + sj] = __float_as_uint(acc[r] * 0.125f);
    }
    __syncthreads();

    // ---- phases 2-4: per-row softmax1 / cumsum / decay / softmax2 ----
    const int sr = tid >> 5, st = tid & 31;  // 16 rows x 32 threads
    const int i = i0 + sr;
    unsigned int* srow = &s_u[sr * SRS];
    const int c0 = st * 32;
    const int lastv = (MODE == 0) ? i : i - 1;  // last valid j
    int vlo = (MODE == 2) ? min(max((i - 19) - c0, 0), 32) : 0;
    int vhi = min(max(lastv + 1 - c0, 0), 32);
    if (vhi < vlo) vhi = vlo;
    #define SLOT(k) (c0 + ((k) ^ st))

    float lm = -3.4e38f;
    for (int k = vlo; k < vhi; k++)
        lm = fmaxf(lm, __uint_as_float(srow[SLOT(k)]));
    #pragma unroll
    for (int off = 16; off; off >>= 1) lm = fmaxf(lm, __shfl_xor(lm, off, 64));
    const float m1 = lm;

    float csum = 0.f;
    for (int k = vlo; k < vhi; k++)
        csum += __expf(__uint_as_float(srow[SLOT(k)]) - m1);
    float scan = csum;
    #pragma unroll
    for (int off = 1; off < 32; off <<= 1) {
        float o = __shfl_up(scan, off, 32);
        if (st >= off) scan += o;
    }
    const float Z1 = __shfl(scan, 31, 32);
    const float invZ1 = 1.f / fmaxf(Z1, 1e-37f);
    const float g = -fabsf(gam[g_off + h]);
    float run = scan - csum;  // exclusive prefix at chunk start
    for (int k = vlo; k < vhi; k++) {
        float s = __uint_as_float(srow[SLOT(k)]);
        float p = __expf(s - m1);
        run += p;
        float cum = run * invZ1;
        float dist = sqrtf(fmaxf((1.f - cum) * (float)(i - (c0 + k)), 0.f));
        float decay = fminf(fmaxf(__expf(g * dist), 1e-5f), 1e5f);
        srow[SLOT(k)] = __float_as_uint(s * decay);
    }

    float lm2 = -3.4e38f;
    for (int k = vlo; k < vhi; k++)
        lm2 = fmaxf(lm2, __uint_as_float(srow[SLOT(k)]));
    #pragma unroll
    for (int off = 16; off; off >>= 1) lm2 = fmaxf(lm2, __shfl_xor(lm2, off, 64));
    float z2c = 0.f;
    // final pass: e -> split-bf16 packed IN PLACE (same slot as read)
    for (int k = vlo; k < vhi; k++) {
        float e = __expf(__uint_as_float(srow[SLOT(k)]) - lm2);
        srow[SLOT(k)] = pack_split(e);
        z2c += e;
    }
    for (int k = 0; k < vlo; k++) srow[SLOT(k)] = 0u;
    for (int k = vhi; k < 32; k++) srow[SLOT(k)] = 0u;
    #pragma unroll
    for (int off = 16; off; off >>= 1) z2c += __shfl_xor(z2c, off, 64);
    if (st == 0)
        rcoef[sr] = (MAXOUT ? fminf(z2c, 5.f) : 1.f) / fmaxf(z2c, 1e-37f);
    #undef SLOT

    // ---- phase 5: PV via MFMA (wave w: d-group w&3, j-half w>>2) ----
    const int dg = w & 3, jh = w >> 2;
    f32x4 accp = {0.f, 0.f, 0.f, 0.f};
    for (int jt = jt_lo; jt < jt_hi; jt++) {
        __syncthreads();
        #pragma unroll
        for (int rep = 0; rep < 4; rep++) {
            int idx = rep * 2048 + tid * 4;
            int d = idx >> 7, jj = idx & 127;
            const uint4 v4 = *reinterpret_cast<const uint4*>(
                &Vb[(size_t)d * Sn + jt * TJ + jj]);
            *reinterpret_cast<uint4*>(&kvu[d * VTS + jj]) = v4;
        }
        __syncthreads();
        #pragma unroll
        for (int kk = 0; kk < 4; kk++) {
            const int jb = jt * TJ + jh * 64 + kk * 16 + fg * 4;
            uint4 au;
            au.x = s_u[fr * SRS + sswz(jb)];
            au.y = s_u[fr * SRS + sswz(jb + 1)];
            au.z = s_u[fr * SRS + sswz(jb + 2)];
            au.w = s_u[fr * SRS + sswz(jb + 3)];
            short8 af = *reinterpret_cast<const short8*>(&au);
            short8 bf = *reinterpret_cast<const short8*>(
                &kvu[(dg * 16 + fr) * VTS + jh * 64 + kk * 16 + fg * 4]);
            accp = __builtin_amdgcn_mfma_f32_16x16x32_bf16(af, bf, accp, 0, 0, 0);
        }
    }
    #pragma unroll
    for (int r = 0; r < 4; r++) pv[w * 256 + (fg * 4 + r) * 16 + fr] = accp[r];
    __syncthreads();

    // ---- combine j-halves + store ----
    #pragma unroll
    for (int rep = 0; rep < 2; rep++) {
        int idx = rep * 512 + tid;
        int r = idx >> 6, d = idx & 63;
        float v = (pv[(d >> 4) * 256 + r * 16 + (d & 15)] +
                   pv[((d >> 4) + 4) * 256 + r * 16 + (d & 15)]) *
                  rcoef[r];
        O[(size_t)(b * Sn + i0 + r) * Dn + h * DKn + d] = v;
    }
}

// ---------------------------------------------------------------------------
// out = LN(x + y) (fp32), one block per row of D=512.
// ---------------------------------------------------------------------------
__global__ __launch_bounds__(256) void add_ln(
    const float* __restrict__ X, const float* __restrict__ Y,
    const float* __restrict__ lnw, const float* __restrict__ lnb, size_t off,
    float* __restrict__ out) {
    __shared__ float red[4];
    const int row = blockIdx.x, tid = threadIdx.x;
    const size_t base = (size_t)row * Dn;
    float v0 = X[base + tid] + Y[base + tid];
    float v1 = X[base + tid + 256] + Y[base + tid + 256];
    const float mu = block_reduce_sum(v0 + v1, red) * (1.f / Dn);
    const float d0 = v0 - mu, d1 = v1 - mu;
    const float var = block_reduce_sum(d0 * d0 + d1 * d1, red) * (1.f / Dn);
    const float rs = rsqrtf(var + LN_EPS);
    out[base + tid] = d0 * rs * lnw[off + tid] + lnb[off + tid];
    out[base + tid + 256] = d1 * rs * lnw[off + tid + 256] + lnb[off + tid + 256];
}

// ---------------------------------------------------------------------------
// catA = LN2(hq + o); catB = LN2(hq + o + ow). All fp32, disjoint buffers.
// ---------------------------------------------------------------------------
__global__ __launch_bounds__(256) void cat_ln(
    const float* __restrict__ hq, const float* __restrict__ o,
    const float* __restrict__ ow, const float* __restrict__ lnw,
    const float* __restrict__ lnb, size_t off, float* __restrict__ catA,
    float* __restrict__ catB) {
    __shared__ float red[4];
    const int row = blockIdx.x, tid = threadIdx.x;
    const size_t base = (size_t)row * Dn;
    const float h0 = hq[base + tid] + o[base + tid];
    const float h1 = hq[base + tid + 256] + o[base + tid + 256];
    const float hw0 = h0 + ow[base + tid];
    const float hw1 = h1 + ow[base + tid + 256];
    const float w0 = lnw[off + tid], w1 = lnw[off + tid + 256];
    const float b0 = lnb[off + tid], b1 = lnb[off + tid + 256];

    float mu = block_reduce_sum(h0 + h1, red) * (1.f / Dn);
    float d0 = h0 - mu, d1 = h1 - mu;
    float var = block_reduce_sum(d0 * d0 + d1 * d1, red) * (1.f / Dn);
    float rs = rsqrtf(var + LN_EPS);
    catA[base + tid] = d0 * rs * w0 + b0;
    catA[base + tid + 256] = d1 * rs * w1 + b1;

    mu = block_reduce_sum(hw0 + hw1, red) * (1.f / Dn);
    d0 = hw0 - mu;
    d1 = hw1 - mu;
    var = block_reduce_sum(d0 * d0 + d1 * d1, red) * (1.f / Dn);
    rs = rsqrtf(var + LN_EPS);
    catB[base + tid] = d0 * rs * w0 + b0;
    catB[base + tid + 256] = d1 * rs * w1 + b1;
}

extern "C" void kernel_launch(void* const* d_in, const int* in_sizes, int n_in,
                              void* d_out, int out_size, void* d_ws,
                              size_t ws_size, hipStream_t stream) {
    const float* q_emb = (const float*)d_in[0];
    const float* s_emb = (const float*)d_in[1];
    const float* Wq = (const float*)d_in[2];
    const float* bq = (const float*)d_in[3];
    const float* Wqw = (const float*)d_in[4];
    const float* bqw = (const float*)d_in[5];
    const float* Wv = (const float*)d_in[6];
    const float* bv = (const float*)d_in[7];
    const float* Wo = (const float*)d_in[8];
    const float* bo = (const float*)d_in[9];
    const float* Wow = (const float*)d_in[10];
    const float* bow = (const float*)d_in[11];
    const float* gammas = (const float*)d_in[12];
    const float* ln_w = (const float*)d_in[13];
    const float* ln_b = (const float*)d_in[14];
    const float* Wc = (const float*)d_in[15];
    const float* bc = (const float*)d_in[16];
    // d_in[17] = lens: unused in the forward pass.

    const size_t BSD = (size_t)Bn * Sn * Dn;
    float* ws = (float*)d_ws;
    float* W0 = ws;
    float* W1 = ws + BSD;
    float* W2 = ws + 2 * BSD;
    unsigned int* VTp = (unsigned int*)(ws + 3 * BSD);   // 16 MB packed V^T
    unsigned int* Wpk = (unsigned int*)(ws + 4 * BSD);   // 2 MB packed weights
    unsigned int* W0u = (unsigned int*)W0;

    float* out_main = (float*)d_out;     // out [B,S,D]
    float* out_hq = out_main + BSD;      // hq
    float* out_hs = out_main + 2 * BSD;  // hs

    const int rows = Bn * Sn;  // 8192
    const dim3 tpb(256), tpA(512);
    const dim3 ggemm(Dn / 128, rows / 128);  // (4, 64)
    const dim3 gattn(Sn / TQ, Bn * Hn);      // (64, 64)
    const dim3 gvt(Sn / 64, Bn * Hn);        // (16, 64)
    const dim3 grow(rows);
    const size_t DD = (size_t)Dn * Dn;

    #define PK(Wp, Kk) pack_wt<<<(Kk) * 2, tpb, 0, stream>>>((Wp), Wpk, (Kk))
    #define GM(A, Bi, Cc) \
        gemm_mfma<false><<<ggemm, tpb, 0, stream>>>((A), (A), Wpk, (Bi), (Cc), rows, Dn, Dn)
    #define GMP(A, Bi, Cc) \
        gemm_mfma<true><<<ggemm, tpb, 0, stream>>>((A), (A), Wpk, (Bi), (Cc), rows, Dn, Dn)

    // ---- Block 1: hq = LN0(q_emb + attn0(q_emb)) -> out_hq ----
    PK(Wq, Dn);               GMP(q_emb, bq, W0u);
    PK(Wv, Dn);               GM(q_emb, bv, W1);
    pack_vt<<<gvt, tpb, 0, stream>>>(W1, VTp);
    attn_tile<0, false><<<gattn, tpA, 0, stream>>>(W0u, VTp, gammas, 0, W2);
    PK(Wo, Dn);               GM(W2, bo, W0);
    add_ln<<<grow, tpb, 0, stream>>>(q_emb, W0, ln_w, ln_b, 0, out_hq);

    // ---- Block 2: hs = LN1(s_emb + attn1(s_emb)) -> out_hs ----
    PK(Wq + DD, Dn);          GMP(s_emb, bq + Dn, W0u);
    PK(Wv + DD, Dn);          GM(s_emb, bv + Dn, W1);
    pack_vt<<<gvt, tpb, 0, stream>>>(W1, VTp);
    attn_tile<0, false><<<gattn, tpA, 0, stream>>>(W0u, VTp, gammas, Hn, W2);
    PK(Wo + DD, Dn);          GM(W2, bo + Dn, W0);
    add_ln<<<grow, tpb, 0, stream>>>(s_emb, W0, ln_w, ln_b, Dn, out_hs);

    // ---- Block 3: xq=xk=hq, xv=hs ----
    PK(Wq + 2 * DD, Dn);      GMP(out_hq, bq + 2 * Dn, W0u);
    PK(Wv + 2 * DD, Dn);      GM(out_hs, bv + 2 * Dn, W1);
    pack_vt<<<gvt, tpb, 0, stream>>>(W1, VTp);
    attn_tile<1, true><<<gattn, tpA, 0, stream>>>(W0u, VTp, gammas, 2 * Hn, W2);
    PK(Wo + 2 * DD, Dn);      GM(W2, bo + 2 * Dn, out_main);
    PK(Wqw + 2 * DD, Dn);     GMP(out_hq, bqw + 2 * Dn, W0u);
    attn_tile<2, false><<<gattn, tpA, 0, stream>>>(W0u, VTp, gammas, 2 * Hn, W2);
    PK(Wow, Dn);              GM(W2, bow, W0);
    // catA = LN2(hq + o) -> W1 ; catB = LN2(hq + o + ow) -> W2
    cat_ln<<<grow, tpb, 0, stream>>>(out_hq, out_main, W0, ln_w, ln_b, 2 * Dn, W1, W2);
    // out = [catA | catB] @ Wc + bc  (K=1024)
    PK(Wc, 2 * Dn);
    gemm_mfma<false><<<ggemm, tpb, 0, stream>>>(W1, W2, Wpk, bc, out_main,
                                                rows, Dn, 2 * Dn);
    #undef PK
    #undef GM
    #undef GMP
}

// Round 7
// 1484.752 us; speedup vs baseline: 2.9519x; 1.3475x over previous
//
#include <hip/hip_runtime.h>
#include <hip/hip_bf16.h>

// AKT_27917287424232 — 3-block distance-decay attention transformer.
// B=8, S=1024, D=512, H=8, dk=64. Inputs fp32, outputs fp32 (out,hq,hs).
// R10: SRS=1028, __expf, contiguous softmax bounds. 3553->3177 us.
// R11: KS=68 float4 layout + low-register phase1, GEMM BK=32. 3177->2985 us.
// R12: split-bf16 MFMA GEMM (exact to ~2^-17). 2985->2458 us.
// R13: split-bf16 MFMA attention (TQ=16, 8 waves, LDS-staged K/V). ->2001 us.
// R14: direct global->register K/V/Q fragments (L2-resident; per-lane uint4
// IS the MFMA B-frag), kvu/qpk LDS deleted -> 74KB LDS -> 2 blocks/CU,
// zero barriers inside j-tile loops (3 per block total). Softmax/PV gather/
// GEMM unchanged.

typedef __hip_bfloat16 bf16;
typedef __attribute__((ext_vector_type(8))) short short8;
typedef __attribute__((ext_vector_type(4))) float f32x4;

constexpr int Bn = 8, Sn = 1024, Dn = 512, Hn = 8, DKn = 64;
constexpr float LN_EPS = 1e-5f;
constexpr int TQ = 16;    // query rows per block
constexpr int TJ = 128;   // K/V tile rows (j per tile)
constexpr int SRS = 1028; // s_u row stride (4-bank offset per row)
constexpr int GKS = 36;   // gemm LDS uint stride

__device__ inline float wave_reduce_sum(float v) {
    #pragma unroll
    for (int off = 32; off; off >>= 1) v += __shfl_xor(v, off, 64);
    return v;
}
// Block of exactly 256 threads (4 waves). smem >= 4 floats.
__device__ inline float block_reduce_sum(float v, float* smem) {
    int lane = threadIdx.x & 63, wave = threadIdx.x >> 6;
    v = wave_reduce_sum(v);
    __syncthreads();
    if (lane == 0) smem[wave] = v;
    __syncthreads();
    return smem[0] + smem[1] + smem[2] + smem[3];
}

// s_u column swizzle: logical col j lives at j ^ ((j>>5)&31).
__device__ inline int sswz(int col) { return col ^ ((col >> 5) & 31); }

// Split fp32 into (hi,lo) bf16 pair packed in a uint: low 16 bits = hi
// (truncated bf16 = even k' element), high 16 bits = lo (RNE bf16 of
// residual). hi+lo represents x to ~2^-17 relative.
__device__ inline unsigned int pack_split(float x) {
    unsigned int bits = __float_as_uint(x);
    unsigned int hi_f = bits & 0xFFFF0000u;
    float lo = x - __uint_as_float(hi_f);
    unsigned int lb = __float_as_uint(lo);
    unsigned int lo_b = (lb + 0x7FFFu + ((lb >> 16) & 1u)) >> 16;
    return (hi_f >> 16) | (lo_b << 16);
}

// ---------------------------------------------------------------------------
// Pack W [K][512] fp32 -> WT [512][K] uints (transposed, hi/lo split).
// ---------------------------------------------------------------------------
__global__ __launch_bounds__(256) void pack_wt(
    const float* __restrict__ W, unsigned int* __restrict__ WT, int K) {
    int idx = blockIdx.x * 256 + threadIdx.x;  // over K*512
    int k = idx >> 9, n = idx & 511;
    WT[(size_t)n * K + k] = pack_split(W[idx]);
}

// ---------------------------------------------------------------------------
// Pack V [B,S,D] fp32 -> VT [bh][d][j] uints (per-head transpose + split).
// Grid (16 j-tiles, 64 bh), 256 threads, LDS 64x64 tile.
// ---------------------------------------------------------------------------
__global__ __launch_bounds__(256) void pack_vt(
    const float* __restrict__ V, unsigned int* __restrict__ VT) {
    __shared__ unsigned int tl[64 * 65];
    const int tid = threadIdx.x;
    const int j0 = blockIdx.x * 64;
    const int bh = blockIdx.y;
    const int b = bh >> 3, h = bh & 7;
    #pragma unroll
    for (int rep = 0; rep < 16; rep++) {
        int idx = rep * 256 + tid;
        int jj = idx >> 6, d = idx & 63;
        tl[d * 65 + jj] =
            pack_split(V[(size_t)(b * Sn + j0 + jj) * Dn + h * DKn + d]);
    }
    __syncthreads();
    #pragma unroll
    for (int rep = 0; rep < 16; rep++) {
        int idx = rep * 256 + tid;
        int d = idx >> 6, jj = idx & 63;
        VT[(size_t)(bh * DKn + d) * Sn + j0 + jj] = tl[d * 65 + jj];
    }
}

// ---------------------------------------------------------------------------
// C[M,512] = A[M,K] @ W[K,512] + bias, via split-bf16 MFMA over K'=2K.
// PACK: write pack_split(result) as uint (for attn Q/K consumption).
// 128x128 tile, 4 waves (2x2), each 64x64 = 4x4 frags of 16x16x32 bf16.
// ---------------------------------------------------------------------------
template <bool PACK>
__global__ __launch_bounds__(256) void gemm_mfma(
    const float* __restrict__ A1, const float* __restrict__ A2,
    const unsigned int* __restrict__ WT, const float* __restrict__ bias,
    void* __restrict__ Cout, int M, int N, int K) {
    __shared__ __align__(16) unsigned int Apk[128 * GKS];  // 18432 B
    __shared__ __align__(16) unsigned int Bpk[128 * GKS];  // 18432 B
    const int bm = blockIdx.y * 128, bn = blockIdx.x * 128;
    const int tid = threadIdx.x;
    const int wv = tid >> 6, lane = tid & 63;
    const int wr = (wv >> 1) * 64, wc = (wv & 1) * 64;
    const int fr = lane & 15, fg = lane >> 4;  // frag row(col), k-group

    f32x4 acc[4][4] = {};  // acc[fm][fn]

    const int kq = (tid & 7) * 4;    // uint/k offset within 32-k tile
    const int rbase = tid >> 3;      // 0..31

    for (int k0 = 0; k0 < K; k0 += 32) {
        const float* Ab = (k0 >= 512) ? A2 : A1;  // K==512 -> always A1
        const int kc = k0 & 511;
        #pragma unroll
        for (int rep = 0; rep < 4; rep++) {
            int row = rep * 32 + rbase;
            const float4 a4 = *reinterpret_cast<const float4*>(
                &Ab[(size_t)(bm + row) * 512 + kc + kq]);
            uint4 p;
            p.x = pack_split(a4.x);
            p.y = pack_split(a4.y);
            p.z = pack_split(a4.z);
            p.w = pack_split(a4.w);
            *reinterpret_cast<uint4*>(&Apk[row * GKS + kq]) = p;
        }
        #pragma unroll
        for (int rep = 0; rep < 4; rep++) {
            int n = rep * 32 + rbase;
            const uint4 b4 = *reinterpret_cast<const uint4*>(
                &WT[(size_t)(bn + n) * K + k0 + kq]);
            *reinterpret_cast<uint4*>(&Bpk[n * GKS + kq]) = b4;
        }
        __syncthreads();
        #pragma unroll
        for (int kk = 0; kk < 2; kk++) {
            short8 af[4], bf[4];
            #pragma unroll
            for (int f = 0; f < 4; f++) {
                af[f] = *reinterpret_cast<const short8*>(
                    &Apk[(wr + f * 16 + fr) * GKS + kk * 16 + fg * 4]);
                bf[f] = *reinterpret_cast<const short8*>(
                    &Bpk[(wc + f * 16 + fr) * GKS + kk * 16 + fg * 4]);
            }
            #pragma unroll
            for (int fm = 0; fm < 4; fm++)
                #pragma unroll
                for (int fn = 0; fn < 4; fn++)
                    acc[fm][fn] = __builtin_amdgcn_mfma_f32_16x16x32_bf16(
                        af[fm], bf[fn], acc[fm][fn], 0, 0, 0);
        }
        __syncthreads();
    }
    // epilogue: bias + store (C/D: col=lane&15, row=(lane>>4)*4+r)
    #pragma unroll
    for (int fn = 0; fn < 4; fn++) {
        const int col = bn + wc + fn * 16 + fr;
        const float bv = bias[col];
        #pragma unroll
        for (int fm = 0; fm < 4; fm++) {
            const int row0 = bm + wr + fm * 16 + fg * 4;
            #pragma unroll
            for (int r = 0; r < 4; r++) {
                float v = acc[fm][fn][r] + bv;
                if (PACK)
                    ((unsigned int*)Cout)[(size_t)(row0 + r) * N + col] =
                        pack_split(v);
                else
                    ((float*)Cout)[(size_t)(row0 + r) * N + col] = v;
            }
        }
    }
}

// ---------------------------------------------------------------------------
// MFMA distance-decay attention, direct-load variant. One block (512 thr,
// 8 waves) per (b,h, 16-row tile). MODE: 0 = j<=i; 1 = j<i; 2 = i-19<=j<i.
// QKu: packed-split Q/K [b,s,h*64+d] uints. VT: packed-split V^T [bh][d][j].
// K/V/Q MFMA fragments are loaded per-lane uint4 straight from global
// (L2-resident, 16MB each) — no LDS staging, no in-loop barriers.
// ---------------------------------------------------------------------------
template <int MODE, bool MAXOUT>
__global__ __launch_bounds__(512, 4) void attn_tile(
    const unsigned int* __restrict__ QKu, const unsigned int* __restrict__ VT,
    const float* __restrict__ gam, size_t g_off, float* __restrict__ O) {
    __shared__ unsigned int s_u[TQ * SRS];       // 65792 B
    __shared__ __align__(16) float pv[8 * 256];  // 8192 B
    __shared__ float rcoef[TQ];

    const int tid = threadIdx.x;
    const int i0 = blockIdx.x * TQ;
    const int bh = blockIdx.y;
    const int h = bh & (Hn - 1);
    const int b = bh >> 3;
    const int w = tid >> 6, lane = tid & 63;
    const int fr = lane & 15, fg = lane >> 4;

    const unsigned int* Kb = QKu + (size_t)b * Sn * Dn + h * DKn;
    const unsigned int* Vb = VT + (size_t)bh * DKn * Sn;

    const int last_j = (MODE == 0) ? (i0 + TQ - 1) : (i0 + TQ - 2);
    const int jt_hi = (last_j >> 7) + 1;
    const int jt_lo = (MODE == 2) ? (max(0, i0 - 19) >> 7) : 0;

    // ---- Q fragments in registers (each wave holds all 16 q-rows) ----
    uint4 qf[4];
    #pragma unroll
    for (int kk = 0; kk < 4; kk++)
        qf[kk] = *reinterpret_cast<const uint4*>(
            &Kb[(size_t)(i0 + fr) * Dn + kk * 16 + fg * 4]);

    // ---- phase 1: QK^T via MFMA (wave w owns j-group w*16..w*16+15) ----
    for (int jt = jt_lo; jt < jt_hi; jt++) {
        f32x4 acc = {0.f, 0.f, 0.f, 0.f};
        #pragma unroll
        for (int kk = 0; kk < 4; kk++) {
            const uint4 kf = *reinterpret_cast<const uint4*>(
                &Kb[(size_t)(jt * TJ + w * 16 + fr) * Dn + kk * 16 + fg * 4]);
            acc = __builtin_amdgcn_mfma_f32_16x16x32_bf16(
                *reinterpret_cast<const short8*>(&qf[kk]),
                *reinterpret_cast<const short8*>(&kf), acc, 0, 0, 0);
        }
        const int sj = sswz(jt * TJ + w * 16 + fr);
        #pragma unroll
        for (int r = 0; r < 4; r++)
            s_u[(fg * 4 + r) * SRS + sj] = __float_as_uint(acc[r] * 0.125f);
    }
    __syncthreads();

    // ---- phases 2-4: per-row softmax1 / cumsum / decay / softmax2 ----
    const int sr = tid >> 5, st = tid & 31;  // 16 rows x 32 threads
    const int i = i0 + sr;
    unsigned int* srow = &s_u[sr * SRS];
    const int c0 = st * 32;
    const int lastv = (MODE == 0) ? i : i - 1;  // last valid j
    int vlo = (MODE == 2) ? min(max((i - 19) - c0, 0), 32) : 0;
    int vhi = min(max(lastv + 1 - c0, 0), 32);
    if (vhi < vlo) vhi = vlo;
    #define SLOT(k) (c0 + ((k) ^ st))

    float lm = -3.4e38f;
    for (int k = vlo; k < vhi; k++)
        lm = fmaxf(lm, __uint_as_float(srow[SLOT(k)]));
    #pragma unroll
    for (int off = 16; off; off >>= 1) lm = fmaxf(lm, __shfl_xor(lm, off, 64));
    const float m1 = lm;

    float csum = 0.f;
    for (int k = vlo; k < vhi; k++)
        csum += __expf(__uint_as_float(srow[SLOT(k)]) - m1);
    float scan = csum;
    #pragma unroll
    for (int off = 1; off < 32; off <<= 1) {
        float o = __shfl_up(scan, off, 32);
        if (st >= off) scan += o;
    }
    const float Z1 = __shfl(scan, 31, 32);
    const float invZ1 = 1.f / fmaxf(Z1, 1e-37f);
    const float g = -fabsf(gam[g_off + h]);
    float run = scan - csum;  // exclusive prefix at chunk start
    for (int k = vlo; k < vhi; k++) {
        float s = __uint_as_float(srow[SLOT(k)]);
        float p = __expf(s - m1);
        run += p;
        float cum = run * invZ1;
        float dist = sqrtf(fmaxf((1.f - cum) * (float)(i - (c0 + k)), 0.f));
        float decay = fminf(fmaxf(__expf(g * dist), 1e-5f), 1e5f);
        srow[SLOT(k)] = __float_as_uint(s * decay);
    }

    float lm2 = -3.4e38f;
    for (int k = vlo; k < vhi; k++)
        lm2 = fmaxf(lm2, __uint_as_float(srow[SLOT(k)]));
    #pragma unroll
    for (int off = 16; off; off >>= 1) lm2 = fmaxf(lm2, __shfl_xor(lm2, off, 64));
    float z2c = 0.f;
    // final pass: e -> split-bf16 packed IN PLACE (same slot as read)
    for (int k = vlo; k < vhi; k++) {
        float e = __expf(__uint_as_float(srow[SLOT(k)]) - lm2);
        srow[SLOT(k)] = pack_split(e);
        z2c += e;
    }
    for (int k = 0; k < vlo; k++) srow[SLOT(k)] = 0u;
    for (int k = vhi; k < 32; k++) srow[SLOT(k)] = 0u;
    #pragma unroll
    for (int off = 16; off; off >>= 1) z2c += __shfl_xor(z2c, off, 64);
    if (st == 0)
        rcoef[sr] = (MAXOUT ? fminf(z2c, 5.f) : 1.f) / fmaxf(z2c, 1e-37f);
    #undef SLOT
    __syncthreads();

    // ---- phase 5: PV via MFMA (wave w: d-group w&3, j-half w>>2) ----
    const int dg = w & 3, jh = w >> 2;
    f32x4 accp = {0.f, 0.f, 0.f, 0.f};
    for (int jt = jt_lo; jt < jt_hi; jt++) {
        #pragma unroll
        for (int kk = 0; kk < 4; kk++) {
            const uint4 vf = *reinterpret_cast<const uint4*>(
                &Vb[(size_t)(dg * 16 + fr) * Sn + jt * TJ + jh * 64 + kk * 16 +
                    fg * 4]);
            const int jb = jt * TJ + jh * 64 + kk * 16 + fg * 4;
            uint4 au;
            au.x = s_u[fr * SRS + sswz(jb)];
            au.y = s_u[fr * SRS + sswz(jb + 1)];
            au.z = s_u[fr * SRS + sswz(jb + 2)];
            au.w = s_u[fr * SRS + sswz(jb + 3)];
            accp = __builtin_amdgcn_mfma_f32_16x16x32_bf16(
                *reinterpret_cast<const short8*>(&au),
                *reinterpret_cast<const short8*>(&vf), accp, 0, 0, 0);
        }
    }
    #pragma unroll
    for (int r = 0; r < 4; r++) pv[w * 256 + (fg * 4 + r) * 16 + fr] = accp[r];
    __syncthreads();

    // ---- combine j-halves + store ----
    #pragma unroll
    for (int rep = 0; rep < 2; rep++) {
        int idx = rep * 512 + tid;
        int r = idx >> 6, d = idx & 63;
        float v = (pv[(d >> 4) * 256 + r * 16 + (d & 15)] +
                   pv[((d >> 4) + 4) * 256 + r * 16 + (d & 15)]) *
                  rcoef[r];
        O[(size_t)(b * Sn + i0 + r) * Dn + h * DKn + d] = v;
    }
}

// ---------------------------------------------------------------------------
// out = LN(x + y) (fp32), one block per row of D=512.
// ---------------------------------------------------------------------------
__global__ __launch_bounds__(256) void add_ln(
    const float* __restrict__ X, const float* __restrict__ Y,
    const float* __restrict__ lnw, const float* __restrict__ lnb, size_t off,
    float* __restrict__ out) {
    __shared__ float red[4];
    const int row = blockIdx.x, tid = threadIdx.x;
    const size_t base = (size_t)row * Dn;
    float v0 = X[base + tid] + Y[base + tid];
    float v1 = X[base + tid + 256] + Y[base + tid + 256];
    const float mu = block_reduce_sum(v0 + v1, red) * (1.f / Dn);
    const float d0 = v0 - mu, d1 = v1 - mu;
    const float var = block_reduce_sum(d0 * d0 + d1 * d1, red) * (1.f / Dn);
    const float rs = rsqrtf(var + LN_EPS);
    out[base + tid] = d0 * rs * lnw[off + tid] + lnb[off + tid];
    out[base + tid + 256] = d1 * rs * lnw[off + tid + 256] + lnb[off + tid + 256];
}

// ---------------------------------------------------------------------------
// catA = LN2(hq + o); catB = LN2(hq + o + ow). All fp32, disjoint buffers.
// ---------------------------------------------------------------------------
__global__ __launch_bounds__(256) void cat_ln(
    const float* __restrict__ hq, const float* __restrict__ o,
    const float* __restrict__ ow, const float* __restrict__ lnw,
    const float* __restrict__ lnb, size_t off, float* __restrict__ catA,
    float* __restrict__ catB) {
    __shared__ float red[4];
    const int row = blockIdx.x, tid = threadIdx.x;
    const size_t base = (size_t)row * Dn;
    const float h0 = hq[base + tid] + o[base + tid];
    const float h1 = hq[base + tid + 256] + o[base + tid + 256];
    const float hw0 = h0 + ow[base + tid];
    const float hw1 = h1 + ow[base + tid + 256];
    const float w0 = lnw[off + tid], w1 = lnw[off + tid + 256];
    const float b0 = lnb[off + tid], b1 = lnb[off + tid + 256];

    float mu = block_reduce_sum(h0 + h1, red) * (1.f / Dn);
    float d0 = h0 - mu, d1 = h1 - mu;
    float var = block_reduce_sum(d0 * d0 + d1 * d1, red) * (1.f / Dn);
    float rs = rsqrtf(var + LN_EPS);
    catA[base + tid] = d0 * rs * w0 + b0;
    catA[base + tid + 256] = d1 * rs * w1 + b1;

    mu = block_reduce_sum(hw0 + hw1, red) * (1.f / Dn);
    d0 = hw0 - mu;
    d1 = hw1 - mu;
    var = block_reduce_sum(d0 * d0 + d1 * d1, red) * (1.f / Dn);
    rs = rsqrtf(var + LN_EPS);
    catB[base + tid] = d0 * rs * w0 + b0;
    catB[base + tid + 256] = d1 * rs * w1 + b1;
}

extern "C" void kernel_launch(void* const* d_in, const int* in_sizes, int n_in,
                              void* d_out, int out_size, void* d_ws,
                              size_t ws_size, hipStream_t stream) {
    const float* q_emb = (const float*)d_in[0];
    const float* s_emb = (const float*)d_in[1];
    const float* Wq = (const float*)d_in[2];
    const float* bq = (const float*)d_in[3];
    const float* Wqw = (const float*)d_in[4];
    const float* bqw = (const float*)d_in[5];
    const float* Wv = (const float*)d_in[6];
    const float* bv = (const float*)d_in[7];
    const float* Wo = (const float*)d_in[8];
    const float* bo = (const float*)d_in[9];
    const float* Wow = (const float*)d_in[10];
    const float* bow = (const float*)d_in[11];
    const float* gammas = (const float*)d_in[12];
    const float* ln_w = (const float*)d_in[13];
    const float* ln_b = (const float*)d_in[14];
    const float* Wc = (const float*)d_in[15];
    const float* bc = (const float*)d_in[16];
    // d_in[17] = lens: unused in the forward pass.

    const size_t BSD = (size_t)Bn * Sn * Dn;
    float* ws = (float*)d_ws;
    float* W0 = ws;
    float* W1 = ws + BSD;
    float* W2 = ws + 2 * BSD;
    unsigned int* VTp = (unsigned int*)(ws + 3 * BSD);   // 16 MB packed V^T
    unsigned int* Wpk = (unsigned int*)(ws + 4 * BSD);   // 2 MB packed weights
    unsigned int* W0u = (unsigned int*)W0;

    float* out_main = (float*)d_out;     // out [B,S,D]
    float* out_hq = out_main + BSD;      // hq
    float* out_hs = out_main + 2 * BSD;  // hs

    const int rows = Bn * Sn;  // 8192
    const dim3 tpb(256), tpA(512);
    const dim3 ggemm(Dn / 128, rows / 128);  // (4, 64)
    const dim3 gattn(Sn / TQ, Bn * Hn);      // (64, 64)
    const dim3 gvt(Sn / 64, Bn * Hn);        // (16, 64)
    const dim3 grow(rows);
    const size_t DD = (size_t)Dn * Dn;

    #define PK(Wp, Kk) pack_wt<<<(Kk) * 2, tpb, 0, stream>>>((Wp), Wpk, (Kk))
    #define GM(A, Bi, Cc) \
        gemm_mfma<false><<<ggemm, tpb, 0, stream>>>((A), (A), Wpk, (Bi), (Cc), rows, Dn, Dn)
    #define GMP(A, Bi, Cc) \
        gemm_mfma<true><<<ggemm, tpb, 0, stream>>>((A), (A), Wpk, (Bi), (Cc), rows, Dn, Dn)

    // ---- Block 1: hq = LN0(q_emb + attn0(q_emb)) -> out_hq ----
    PK(Wq, Dn);               GMP(q_emb, bq, W0u);
    PK(Wv, Dn);               GM(q_emb, bv, W1);
    pack_vt<<<gvt, tpb, 0, stream>>>(W1, VTp);
    attn_tile<0, false><<<gattn, tpA, 0, stream>>>(W0u, VTp, gammas, 0, W2);
    PK(Wo, Dn);               GM(W2, bo, W0);
    add_ln<<<grow, tpb, 0, stream>>>(q_emb, W0, ln_w, ln_b, 0, out_hq);

    // ---- Block 2: hs = LN1(s_emb + attn1(s_emb)) -> out_hs ----
    PK(Wq + DD, Dn);          GMP(s_emb, bq + Dn, W0u);
    PK(Wv + DD, Dn);          GM(s_emb, bv + Dn, W1);
    pack_vt<<<gvt, tpb, 0, stream>>>(W1, VTp);
    attn_tile<0, false><<<gattn, tpA, 0, stream>>>(W0u, VTp, gammas, Hn, W2);
    PK(Wo + DD, Dn);          GM(W2, bo + Dn, W0);
    add_ln<<<grow, tpb, 0, stream>>>(s_emb, W0, ln_w, ln_b, Dn, out_hs);

    // ---- Block 3: xq=xk=hq, xv=hs ----
    PK(Wq + 2 * DD, Dn);      GMP(out_hq, bq + 2 * Dn, W0u);
    PK(Wv + 2 * DD, Dn);      GM(out_hs, bv + 2 * Dn, W1);
    pack_vt<<<gvt, tpb, 0, stream>>>(W1, VTp);
    attn_tile<1, true><<<gattn, tpA, 0, stream>>>(W0u, VTp, gammas, 2 * Hn, W2);
    PK(Wo + 2 * DD, Dn);      GM(W2, bo + 2 * Dn, out_main);
    PK(Wqw + 2 * DD, Dn);     GMP(out_hq, bqw + 2 * Dn, W0u);
    attn_tile<2, false><<<gattn, tpA, 0, stream>>>(W0u, VTp, gammas, 2 * Hn, W2);
    PK(Wow, Dn);              GM(W2, bow, W0);
    // catA = LN2(hq + o) -> W1 ; catB = LN2(hq + o + ow) -> W2
    cat_ln<<<grow, tpb, 0, stream>>>(out_hq, out_main, W0, ln_w, ln_b, 2 * Dn, W1, W2);
    // out = [catA | catB] @ Wc + bc  (K=1024)
    PK(Wc, 2 * Dn);
    gemm_mfma<false><<<ggemm, tpb, 0, stream>>>(W1, W2, Wpk, bc, out_main,
                                                rows, Dn, 2 * Dn);
    #undef PK
    #undef GM
    #undef GMP
}

// Round 8
// 1354.300 us; speedup vs baseline: 3.2362x; 1.0963x over previous
//
#include <hip/hip_runtime.h>
#include <hip/hip_bf16.h>

// AKT_27917287424232 — 3-block distance-decay attention transformer.
// B=8, S=1024, D=512, H=8, dk=64. Inputs fp32, outputs fp32 (out,hq,hs).
// R11: KS=68 float4 layout + low-register phase1, GEMM BK=32. 3177->2985 us.
// R12: split-bf16 MFMA GEMM (exact to ~2^-17). 2985->2458 us.
// R13: split-bf16 MFMA attention (TQ=16, 8 waves, LDS-staged K/V). ->2001 us.
// R14: direct global->register K/V/Q frags, no in-loop barriers. ->1485 us.
// R15: register-resident softmax (sv[32] static unroll, 1 uint2 load pass +
// 1 uint2 store pass replace 5 scalar passes; lm2 fused into decay loop) +
// pair-preserving swizzle sswz2(j)=j^((j>>4)&30) -> uint2 LDS everywhere
// (PV gather 16 scalar -> 4 uint2 per tile). VGPR watch: must stay <128.

typedef __hip_bfloat16 bf16;
typedef __attribute__((ext_vector_type(8))) short short8;
typedef __attribute__((ext_vector_type(4))) float f32x4;

constexpr int Bn = 8, Sn = 1024, Dn = 512, Hn = 8, DKn = 64;
constexpr float LN_EPS = 1e-5f;
constexpr int TQ = 16;    // query rows per block
constexpr int TJ = 128;   // K/V tile rows (j per tile)
constexpr int SRS = 1028; // s_u row stride (4-bank offset per row)
constexpr int GKS = 36;   // gemm LDS uint stride

__device__ inline float wave_reduce_sum(float v) {
    #pragma unroll
    for (int off = 32; off; off >>= 1) v += __shfl_xor(v, off, 64);
    return v;
}
// Block of exactly 256 threads (4 waves). smem >= 4 floats.
__device__ inline float block_reduce_sum(float v, float* smem) {
    int lane = threadIdx.x & 63, wave = threadIdx.x >> 6;
    v = wave_reduce_sum(v);
    __syncthreads();
    if (lane == 0) smem[wave] = v;
    __syncthreads();
    return smem[0] + smem[1] + smem[2] + smem[3];
}

// Pair-preserving column swizzle: XOR low-5 bits with an EVEN value derived
// from the 32-group index. Bijective within each 32-col group; (even,odd)
// pairs stay adjacent -> uint2 LDS access; banks stay at the wave64 floor.
__device__ inline int sswz2(int col) { return col ^ ((col >> 4) & 30); }

// Split fp32 into (hi,lo) bf16 pair packed in a uint: low 16 bits = hi
// (truncated bf16 = even k' element), high 16 bits = lo (RNE bf16 of
// residual). hi+lo represents x to ~2^-17 relative.
__device__ inline unsigned int pack_split(float x) {
    unsigned int bits = __float_as_uint(x);
    unsigned int hi_f = bits & 0xFFFF0000u;
    float lo = x - __uint_as_float(hi_f);
    unsigned int lb = __float_as_uint(lo);
    unsigned int lo_b = (lb + 0x7FFFu + ((lb >> 16) & 1u)) >> 16;
    return (hi_f >> 16) | (lo_b << 16);
}

// ---------------------------------------------------------------------------
// Pack W [K][512] fp32 -> WT [512][K] uints (transposed, hi/lo split).
// ---------------------------------------------------------------------------
__global__ __launch_bounds__(256) void pack_wt(
    const float* __restrict__ W, unsigned int* __restrict__ WT, int K) {
    int idx = blockIdx.x * 256 + threadIdx.x;  // over K*512
    int k = idx >> 9, n = idx & 511;
    WT[(size_t)n * K + k] = pack_split(W[idx]);
}

// ---------------------------------------------------------------------------
// Pack V [B,S,D] fp32 -> VT [bh][d][j] uints (per-head transpose + split).
// Grid (16 j-tiles, 64 bh), 256 threads, LDS 64x64 tile.
// ---------------------------------------------------------------------------
__global__ __launch_bounds__(256) void pack_vt(
    const float* __restrict__ V, unsigned int* __restrict__ VT) {
    __shared__ unsigned int tl[64 * 65];
    const int tid = threadIdx.x;
    const int j0 = blockIdx.x * 64;
    const int bh = blockIdx.y;
    const int b = bh >> 3, h = bh & 7;
    #pragma unroll
    for (int rep = 0; rep < 16; rep++) {
        int idx = rep * 256 + tid;
        int jj = idx >> 6, d = idx & 63;
        tl[d * 65 + jj] =
            pack_split(V[(size_t)(b * Sn + j0 + jj) * Dn + h * DKn + d]);
    }
    __syncthreads();
    #pragma unroll
    for (int rep = 0; rep < 16; rep++) {
        int idx = rep * 256 + tid;
        int d = idx >> 6, jj = idx & 63;
        VT[(size_t)(bh * DKn + d) * Sn + j0 + jj] = tl[d * 65 + jj];
    }
}

// ---------------------------------------------------------------------------
// C[M,512] = A[M,K] @ W[K,512] + bias, via split-bf16 MFMA over K'=2K.
// PACK: write pack_split(result) as uint (for attn Q/K consumption).
// 128x128 tile, 4 waves (2x2), each 64x64 = 4x4 frags of 16x16x32 bf16.
// ---------------------------------------------------------------------------
template <bool PACK>
__global__ __launch_bounds__(256) void gemm_mfma(
    const float* __restrict__ A1, const float* __restrict__ A2,
    const unsigned int* __restrict__ WT, const float* __restrict__ bias,
    void* __restrict__ Cout, int M, int N, int K) {
    __shared__ __align__(16) unsigned int Apk[128 * GKS];  // 18432 B
    __shared__ __align__(16) unsigned int Bpk[128 * GKS];  // 18432 B
    const int bm = blockIdx.y * 128, bn = blockIdx.x * 128;
    const int tid = threadIdx.x;
    const int wv = tid >> 6, lane = tid & 63;
    const int wr = (wv >> 1) * 64, wc = (wv & 1) * 64;
    const int fr = lane & 15, fg = lane >> 4;  // frag row(col), k-group

    f32x4 acc[4][4] = {};  // acc[fm][fn]

    const int kq = (tid & 7) * 4;    // uint/k offset within 32-k tile
    const int rbase = tid >> 3;      // 0..31

    for (int k0 = 0; k0 < K; k0 += 32) {
        const float* Ab = (k0 >= 512) ? A2 : A1;  // K==512 -> always A1
        const int kc = k0 & 511;
        #pragma unroll
        for (int rep = 0; rep < 4; rep++) {
            int row = rep * 32 + rbase;
            const float4 a4 = *reinterpret_cast<const float4*>(
                &Ab[(size_t)(bm + row) * 512 + kc + kq]);
            uint4 p;
            p.x = pack_split(a4.x);
            p.y = pack_split(a4.y);
            p.z = pack_split(a4.z);
            p.w = pack_split(a4.w);
            *reinterpret_cast<uint4*>(&Apk[row * GKS + kq]) = p;
        }
        #pragma unroll
        for (int rep = 0; rep < 4; rep++) {
            int n = rep * 32 + rbase;
            const uint4 b4 = *reinterpret_cast<const uint4*>(
                &WT[(size_t)(bn + n) * K + k0 + kq]);
            *reinterpret_cast<uint4*>(&Bpk[n * GKS + kq]) = b4;
        }
        __syncthreads();
        #pragma unroll
        for (int kk = 0; kk < 2; kk++) {
            short8 af[4], bf[4];
            #pragma unroll
            for (int f = 0; f < 4; f++) {
                af[f] = *reinterpret_cast<const short8*>(
                    &Apk[(wr + f * 16 + fr) * GKS + kk * 16 + fg * 4]);
                bf[f] = *reinterpret_cast<const short8*>(
                    &Bpk[(wc + f * 16 + fr) * GKS + kk * 16 + fg * 4]);
            }
            #pragma unroll
            for (int fm = 0; fm < 4; fm++)
                #pragma unroll
                for (int fn = 0; fn < 4; fn++)
                    acc[fm][fn] = __builtin_amdgcn_mfma_f32_16x16x32_bf16(
                        af[fm], bf[fn], acc[fm][fn], 0, 0, 0);
        }
        __syncthreads();
    }
    // epilogue: bias + store (C/D: col=lane&15, row=(lane>>4)*4+r)
    #pragma unroll
    for (int fn = 0; fn < 4; fn++) {
        const int col = bn + wc + fn * 16 + fr;
        const float bv = bias[col];
        #pragma unroll
        for (int fm = 0; fm < 4; fm++) {
            const int row0 = bm + wr + fm * 16 + fg * 4;
            #pragma unroll
            for (int r = 0; r < 4; r++) {
                float v = acc[fm][fn][r] + bv;
                if (PACK)
                    ((unsigned int*)Cout)[(size_t)(row0 + r) * N + col] =
                        pack_split(v);
                else
                    ((float*)Cout)[(size_t)(row0 + r) * N + col] = v;
            }
        }
    }
}

// ---------------------------------------------------------------------------
// MFMA distance-decay attention, direct-load + register-softmax variant.
// One block (512 thr, 8 waves) per (b,h, 16-row tile).
// MODE: 0 = j<=i; 1 = j<i; 2 = i-19<=j<i.
// QKu: packed-split Q/K [b,s,h*64+d] uints. VT: packed-split V^T [bh][d][j].
// ---------------------------------------------------------------------------
template <int MODE, bool MAXOUT>
__global__ __launch_bounds__(512, 4) void attn_tile(
    const unsigned int* __restrict__ QKu, const unsigned int* __restrict__ VT,
    const float* __restrict__ gam, size_t g_off, float* __restrict__ O) {
    __shared__ __align__(16) unsigned int s_u[TQ * SRS];  // 65792 B
    __shared__ __align__(16) float pv[8 * 256];           // 8192 B
    __shared__ float rcoef[TQ];

    const int tid = threadIdx.x;
    const int i0 = blockIdx.x * TQ;
    const int bh = blockIdx.y;
    const int h = bh & (Hn - 1);
    const int b = bh >> 3;
    const int w = tid >> 6, lane = tid & 63;
    const int fr = lane & 15, fg = lane >> 4;

    const unsigned int* Kb = QKu + (size_t)b * Sn * Dn + h * DKn;
    const unsigned int* Vb = VT + (size_t)bh * DKn * Sn;

    const int last_j = (MODE == 0) ? (i0 + TQ - 1) : (i0 + TQ - 2);
    const int jt_hi = (last_j >> 7) + 1;
    const int jt_lo = (MODE == 2) ? (max(0, i0 - 19) >> 7) : 0;

    // ---- Q fragments in registers (each wave holds all 16 q-rows) ----
    uint4 qf[4];
    #pragma unroll
    for (int kk = 0; kk < 4; kk++)
        qf[kk] = *reinterpret_cast<const uint4*>(
            &Kb[(size_t)(i0 + fr) * Dn + kk * 16 + fg * 4]);

    // ---- phase 1: QK^T via MFMA (wave w owns j-group w*16..w*16+15) ----
    for (int jt = jt_lo; jt < jt_hi; jt++) {
        f32x4 acc = {0.f, 0.f, 0.f, 0.f};
        #pragma unroll
        for (int kk = 0; kk < 4; kk++) {
            const uint4 kf = *reinterpret_cast<const uint4*>(
                &Kb[(size_t)(jt * TJ + w * 16 + fr) * Dn + kk * 16 + fg * 4]);
            acc = __builtin_amdgcn_mfma_f32_16x16x32_bf16(
                *reinterpret_cast<const short8*>(&qf[kk]),
                *reinterpret_cast<const short8*>(&kf), acc, 0, 0, 0);
        }
        const int sj = sswz2(jt * TJ + w * 16 + fr);
        #pragma unroll
        for (int r = 0; r < 4; r++)
            s_u[(fg * 4 + r) * SRS + sj] = __float_as_uint(acc[r] * 0.125f);
    }
    __syncthreads();

    // ---- phases 2-4: register-resident softmax (1 load + 1 store pass) ----
    const int sr = tid >> 5, st = tid & 31;  // 16 rows x 32 threads
    const int i = i0 + sr;
    unsigned int* srow = &s_u[sr * SRS];
    const int c0 = st * 32;
    const int ex = (st << 1) & 31;  // even XOR for this thread's 32-col chunk
    const int lastv = (MODE == 0) ? i : i - 1;  // last valid j
    int vlo = (MODE == 2) ? min(max((i - 19) - c0, 0), 32) : 0;
    int vhi = min(max(lastv + 1 - c0, 0), 32);
    if (vhi < vlo) vhi = vlo;

    float sv[32];
    #pragma unroll
    for (int k = 0; k < 32; k += 2) {
        const uint2 u =
            *reinterpret_cast<const uint2*>(&srow[c0 + (k ^ ex)]);
        sv[k] = __uint_as_float(u.x);
        sv[k + 1] = __uint_as_float(u.y);
    }

    float lm = -3.4e38f;
    #pragma unroll
    for (int k = 0; k < 32; k++)
        lm = (k >= vlo && k < vhi) ? fmaxf(lm, sv[k]) : lm;
    #pragma unroll
    for (int off = 16; off; off >>= 1) lm = fmaxf(lm, __shfl_xor(lm, off, 64));
    const float m1 = lm;

    float csum = 0.f;
    #pragma unroll
    for (int k = 0; k < 32; k++) {
        float p = __expf(sv[k] - m1);
        csum += (k >= vlo && k < vhi) ? p : 0.f;
    }
    float scan = csum;
    #pragma unroll
    for (int off = 1; off < 32; off <<= 1) {
        float o = __shfl_up(scan, off, 32);
        if (st >= off) scan += o;
    }
    const float Z1 = __shfl(scan, 31, 32);
    const float invZ1 = 1.f / fmaxf(Z1, 1e-37f);
    const float g = -fabsf(gam[g_off + h]);
    float run = scan - csum;  // exclusive prefix at chunk start
    float lm2 = -3.4e38f;
    #pragma unroll
    for (int k = 0; k < 32; k++) {
        const bool val = (k >= vlo && k < vhi);
        float p = __expf(sv[k] - m1);
        run += val ? p : 0.f;
        float cum = run * invZ1;
        float dist = sqrtf(fmaxf((1.f - cum) * (float)(i - (c0 + k)), 0.f));
        float decay = fminf(fmaxf(__expf(g * dist), 1e-5f), 1e5f);
        float s2 = sv[k] * decay;
        sv[k] = s2;
        lm2 = val ? fmaxf(lm2, s2) : lm2;
    }
    #pragma unroll
    for (int off = 16; off; off >>= 1) lm2 = fmaxf(lm2, __shfl_xor(lm2, off, 64));

    float z2c = 0.f;
    #pragma unroll
    for (int k = 0; k < 32; k += 2) {
        const bool v0 = (k >= vlo && k < vhi);
        const bool v1 = (k + 1 >= vlo && k + 1 < vhi);
        float e0 = __expf(sv[k] - lm2);
        float e1 = __expf(sv[k + 1] - lm2);
        z2c += (v0 ? e0 : 0.f) + (v1 ? e1 : 0.f);
        uint2 u;
        u.x = v0 ? pack_split(e0) : 0u;
        u.y = v1 ? pack_split(e1) : 0u;
        *reinterpret_cast<uint2*>(&srow[c0 + (k ^ ex)]) = u;
    }
    #pragma unroll
    for (int off = 16; off; off >>= 1) z2c += __shfl_xor(z2c, off, 64);
    if (st == 0)
        rcoef[sr] = (MAXOUT ? fminf(z2c, 5.f) : 1.f) / fmaxf(z2c, 1e-37f);
    __syncthreads();

    // ---- phase 5: PV via MFMA (wave w: d-group w&3, j-half w>>2) ----
    const int dg = w & 3, jh = w >> 2;
    f32x4 accp = {0.f, 0.f, 0.f, 0.f};
    for (int jt = jt_lo; jt < jt_hi; jt++) {
        #pragma unroll
        for (int kk = 0; kk < 4; kk++) {
            const uint4 vf = *reinterpret_cast<const uint4*>(
                &Vb[(size_t)(dg * 16 + fr) * Sn + jt * TJ + jh * 64 + kk * 16 +
                    fg * 4]);
            const int jb = jt * TJ + jh * 64 + kk * 16 + fg * 4;
            const int eb = (jb >> 4) & 30;  // same for jb..jb+3
            const uint2 ua = *reinterpret_cast<const uint2*>(
                &s_u[fr * SRS + (jb ^ eb)]);
            const uint2 ub = *reinterpret_cast<const uint2*>(
                &s_u[fr * SRS + ((jb + 2) ^ eb)]);
            uint4 au;
            au.x = ua.x; au.y = ua.y; au.z = ub.x; au.w = ub.y;
            accp = __builtin_amdgcn_mfma_f32_16x16x32_bf16(
                *reinterpret_cast<const short8*>(&au),
                *reinterpret_cast<const short8*>(&vf), accp, 0, 0, 0);
        }
    }
    #pragma unroll
    for (int r = 0; r < 4; r++) pv[w * 256 + (fg * 4 + r) * 16 + fr] = accp[r];
    __syncthreads();

    // ---- combine j-halves + store ----
    #pragma unroll
    for (int rep = 0; rep < 2; rep++) {
        int idx = rep * 512 + tid;
        int r = idx >> 6, d = idx & 63;
        float v = (pv[(d >> 4) * 256 + r * 16 + (d & 15)] +
                   pv[((d >> 4) + 4) * 256 + r * 16 + (d & 15)]) *
                  rcoef[r];
        O[(size_t)(b * Sn + i0 + r) * Dn + h * DKn + d] = v;
    }
}

// ---------------------------------------------------------------------------
// out = LN(x + y) (fp32), one block per row of D=512.
// ---------------------------------------------------------------------------
__global__ __launch_bounds__(256) void add_ln(
    const float* __restrict__ X, const float* __restrict__ Y,
    const float* __restrict__ lnw, const float* __restrict__ lnb, size_t off,
    float* __restrict__ out) {
    __shared__ float red[4];
    const int row = blockIdx.x, tid = threadIdx.x;
    const size_t base = (size_t)row * Dn;
    float v0 = X[base + tid] + Y[base + tid];
    float v1 = X[base + tid + 256] + Y[base + tid + 256];
    const float mu = block_reduce_sum(v0 + v1, red) * (1.f / Dn);
    const float d0 = v0 - mu, d1 = v1 - mu;
    const float var = block_reduce_sum(d0 * d0 + d1 * d1, red) * (1.f / Dn);
    const float rs = rsqrtf(var + LN_EPS);
    out[base + tid] = d0 * rs * lnw[off + tid] + lnb[off + tid];
    out[base + tid + 256] = d1 * rs * lnw[off + tid + 256] + lnb[off + tid + 256];
}

// ---------------------------------------------------------------------------
// catA = LN2(hq + o); catB = LN2(hq + o + ow). All fp32, disjoint buffers.
// ---------------------------------------------------------------------------
__global__ __launch_bounds__(256) void cat_ln(
    const float* __restrict__ hq, const float* __restrict__ o,
    const float* __restrict__ ow, const float* __restrict__ lnw,
    const float* __restrict__ lnb, size_t off, float* __restrict__ catA,
    float* __restrict__ catB) {
    __shared__ float red[4];
    const int row = blockIdx.x, tid = threadIdx.x;
    const size_t base = (size_t)row * Dn;
    const float h0 = hq[base + tid] + o[base + tid];
    const float h1 = hq[base + tid + 256] + o[base + tid + 256];
    const float hw0 = h0 + ow[base + tid];
    const float hw1 = h1 + ow[base + tid + 256];
    const float w0 = lnw[off + tid], w1 = lnw[off + tid + 256];
    const float b0 = lnb[off + tid], b1 = lnb[off + tid + 256];

    float mu = block_reduce_sum(h0 + h1, red) * (1.f / Dn);
    float d0 = h0 - mu, d1 = h1 - mu;
    float var = block_reduce_sum(d0 * d0 + d1 * d1, red) * (1.f / Dn);
    float rs = rsqrtf(var + LN_EPS);
    catA[base + tid] = d0 * rs * w0 + b0;
    catA[base + tid + 256] = d1 * rs * w1 + b1;

    mu = block_reduce_sum(hw0 + hw1, red) * (1.f / Dn);
    d0 = hw0 - mu;
    d1 = hw1 - mu;
    var = block_reduce_sum(d0 * d0 + d1 * d1, red) * (1.f / Dn);
    rs = rsqrtf(var + LN_EPS);
    catB[base + tid] = d0 * rs * w0 + b0;
    catB[base + tid + 256] = d1 * rs * w1 + b1;
}

extern "C" void kernel_launch(void* const* d_in, const int* in_sizes, int n_in,
                              void* d_out, int out_size, void* d_ws,
                              size_t ws_size, hipStream_t stream) {
    const float* q_emb = (const float*)d_in[0];
    const float* s_emb = (const float*)d_in[1];
    const float* Wq = (const float*)d_in[2];
    const float* bq = (const float*)d_in[3];
    const float* Wqw = (const float*)d_in[4];
    const float* bqw = (const float*)d_in[5];
    const float* Wv = (const float*)d_in[6];
    const float* bv = (const float*)d_in[7];
    const float* Wo = (const float*)d_in[8];
    const float* bo = (const float*)d_in[9];
    const float* Wow = (const float*)d_in[10];
    const float* bow = (const float*)d_in[11];
    const float* gammas = (const float*)d_in[12];
    const float* ln_w = (const float*)d_in[13];
    const float* ln_b = (const float*)d_in[14];
    const float* Wc = (const float*)d_in[15];
    const float* bc = (const float*)d_in[16];
    // d_in[17] = lens: unused in the forward pass.

    const size_t BSD = (size_t)Bn * Sn * Dn;
    float* ws = (float*)d_ws;
    float* W0 = ws;
    float* W1 = ws + BSD;
    float* W2 = ws + 2 * BSD;
    unsigned int* VTp = (unsigned int*)(ws + 3 * BSD);   // 16 MB packed V^T
    unsigned int* Wpk = (unsigned int*)(ws + 4 * BSD);   // 2 MB packed weights
    unsigned int* W0u = (unsigned int*)W0;

    float* out_main = (float*)d_out;     // out [B,S,D]
    float* out_hq = out_main + BSD;      // hq
    float* out_hs = out_main + 2 * BSD;  // hs

    const int rows = Bn * Sn;  // 8192
    const dim3 tpb(256), tpA(512);
    const dim3 ggemm(Dn / 128, rows / 128);  // (4, 64)
    const dim3 gattn(Sn / TQ, Bn * Hn);      // (64, 64)
    const dim3 gvt(Sn / 64, Bn * Hn);        // (16, 64)
    const dim3 grow(rows);
    const size_t DD = (size_t)Dn * Dn;

    #define PK(Wp, Kk) pack_wt<<<(Kk) * 2, tpb, 0, stream>>>((Wp), Wpk, (Kk))
    #define GM(A, Bi, Cc) \
        gemm_mfma<false><<<ggemm, tpb, 0, stream>>>((A), (A), Wpk, (Bi), (Cc), rows, Dn, Dn)
    #define GMP(A, Bi, Cc) \
        gemm_mfma<true><<<ggemm, tpb, 0, stream>>>((A), (A), Wpk, (Bi), (Cc), rows, Dn, Dn)

    // ---- Block 1: hq = LN0(q_emb + attn0(q_emb)) -> out_hq ----
    PK(Wq, Dn);               GMP(q_emb, bq, W0u);
    PK(Wv, Dn);               GM(q_emb, bv, W1);
    pack_vt<<<gvt, tpb, 0, stream>>>(W1, VTp);
    attn_tile<0, false><<<gattn, tpA, 0, stream>>>(W0u, VTp, gammas, 0, W2);
    PK(Wo, Dn);               GM(W2, bo, W0);
    add_ln<<<grow, tpb, 0, stream>>>(q_emb, W0, ln_w, ln_b, 0, out_hq);

    // ---- Block 2: hs = LN1(s_emb + attn1(s_emb)) -> out_hs ----
    PK(Wq + DD, Dn);          GMP(s_emb, bq + Dn, W0u);
    PK(Wv + DD, Dn);          GM(s_emb, bv + Dn, W1);
    pack_vt<<<gvt, tpb, 0, stream>>>(W1, VTp);
    attn_tile<0, false><<<gattn, tpA, 0, stream>>>(W0u, VTp, gammas, Hn, W2);
    PK(Wo + DD, Dn);          GM(W2, bo + Dn, W0);
    add_ln<<<grow, tpb, 0, stream>>>(s_emb, W0, ln_w, ln_b, Dn, out_hs);

    // ---- Block 3: xq=xk=hq, xv=hs ----
    PK(Wq + 2 * DD, Dn);      GMP(out_hq, bq + 2 * Dn, W0u);
    PK(Wv + 2 * DD, Dn);      GM(out_hs, bv + 2 * Dn, W1);
    pack_vt<<<gvt, tpb, 0, stream>>>(W1, VTp);
    attn_tile<1, true><<<gattn, tpA, 0, stream>>>(W0u, VTp, gammas, 2 * Hn, W2);
    PK(Wo + 2 * DD, Dn);      GM(W2, bo + 2 * Dn, out_main);
    PK(Wqw + 2 * DD, Dn);     GMP(out_hq, bqw + 2 * Dn, W0u);
    attn_tile<2, false><<<gattn, tpA, 0, stream>>>(W0u, VTp, gammas, 2 * Hn, W2);
    PK(Wow, Dn);              GM(W2, bow, W0);
    // catA = LN2(hq + o) -> W1 ; catB = LN2(hq + o + ow) -> W2
    cat_ln<<<grow, tpb, 0, stream>>>(out_hq, out_main, W0, ln_w, ln_b, 2 * Dn, W1, W2);
    // out = [catA | catB] @ Wc + bc  (K=1024)
    PK(Wc, 2 * Dn);
    gemm_mfma<false><<<ggemm, tpb, 0, stream>>>(W1, W2, Wpk, bc, out_main,
                                                rows, Dn, 2 * Dn);
    #undef PK
    #undef GM
    #undef GMP
}

// Round 9
// 1174.571 us; speedup vs baseline: 3.7314x; 1.1530x over previous
//
#include <hip/hip_runtime.h>
#include <hip/hip_bf16.h>

// AKT_27917287424232 — 3-block distance-decay attention transformer.
// B=8, S=1024, D=512, H=8, dk=64. Inputs fp32, outputs fp32 (out,hq,hs).
// R12: split-bf16 MFMA GEMM (exact to ~2^-17). 2985->2458 us.
// R13: split-bf16 MFMA attention (TQ=16, 8 waves, LDS-staged K/V). ->2001 us.
// R14: direct global->register K/V/Q frags, no in-loop barriers. ->1485 us.
// R15: register-resident softmax + pair-preserving swizzle sswz2. ->1354 us.
// R16: XCD-locality block remap. attn FETCH was 131MB/dispatch = 8x the
// 32MB working set: blocks sharing a head's K/VT were round-robined across
// all 8 XCDs. Remap flat IDs so same-bh blocks are ≡ (mod 8) -> same XCD
// L2 (4MB/XCD working set). Same for GEMM A-panels (4 N-blocks/panel).

typedef __hip_bfloat16 bf16;
typedef __attribute__((ext_vector_type(8))) short short8;
typedef __attribute__((ext_vector_type(4))) float f32x4;

constexpr int Bn = 8, Sn = 1024, Dn = 512, Hn = 8, DKn = 64;
constexpr float LN_EPS = 1e-5f;
constexpr int TQ = 16;    // query rows per block
constexpr int TJ = 128;   // K/V tile rows (j per tile)
constexpr int SRS = 1028; // s_u row stride (4-bank offset per row)
constexpr int GKS = 36;   // gemm LDS uint stride

__device__ inline float wave_reduce_sum(float v) {
    #pragma unroll
    for (int off = 32; off; off >>= 1) v += __shfl_xor(v, off, 64);
    return v;
}
// Block of exactly 256 threads (4 waves). smem >= 4 floats.
__device__ inline float block_reduce_sum(float v, float* smem) {
    int lane = threadIdx.x & 63, wave = threadIdx.x >> 6;
    v = wave_reduce_sum(v);
    __syncthreads();
    if (lane == 0) smem[wave] = v;
    __syncthreads();
    return smem[0] + smem[1] + smem[2] + smem[3];
}

// Pair-preserving column swizzle: XOR low-5 bits with an EVEN value derived
// from the 32-group index. Bijective within each 32-col group; (even,odd)
// pairs stay adjacent -> uint2 LDS access; banks stay at the wave64 floor.
__device__ inline int sswz2(int col) { return col ^ ((col >> 4) & 30); }

// Split fp32 into (hi,lo) bf16 pair packed in a uint: low 16 bits = hi
// (truncated bf16 = even k' element), high 16 bits = lo (RNE bf16 of
// residual). hi+lo represents x to ~2^-17 relative.
__device__ inline unsigned int pack_split(float x) {
    unsigned int bits = __float_as_uint(x);
    unsigned int hi_f = bits & 0xFFFF0000u;
    float lo = x - __uint_as_float(hi_f);
    unsigned int lb = __float_as_uint(lo);
    unsigned int lo_b = (lb + 0x7FFFu + ((lb >> 16) & 1u)) >> 16;
    return (hi_f >> 16) | (lo_b << 16);
}

// ---------------------------------------------------------------------------
// Pack W [K][512] fp32 -> WT [512][K] uints (transposed, hi/lo split).
// ---------------------------------------------------------------------------
__global__ __launch_bounds__(256) void pack_wt(
    const float* __restrict__ W, unsigned int* __restrict__ WT, int K) {
    int idx = blockIdx.x * 256 + threadIdx.x;  // over K*512
    int k = idx >> 9, n = idx & 511;
    WT[(size_t)n * K + k] = pack_split(W[idx]);
}

// ---------------------------------------------------------------------------
// Pack V [B,S,D] fp32 -> VT [bh][d][j] uints (per-head transpose + split).
// Grid (16 j-tiles, 64 bh), 256 threads, LDS 64x64 tile.
// ---------------------------------------------------------------------------
__global__ __launch_bounds__(256) void pack_vt(
    const float* __restrict__ V, unsigned int* __restrict__ VT) {
    __shared__ unsigned int tl[64 * 65];
    const int tid = threadIdx.x;
    const int j0 = blockIdx.x * 64;
    const int bh = blockIdx.y;
    const int b = bh >> 3, h = bh & 7;
    #pragma unroll
    for (int rep = 0; rep < 16; rep++) {
        int idx = rep * 256 + tid;
        int jj = idx >> 6, d = idx & 63;
        tl[d * 65 + jj] =
            pack_split(V[(size_t)(b * Sn + j0 + jj) * Dn + h * DKn + d]);
    }
    __syncthreads();
    #pragma unroll
    for (int rep = 0; rep < 16; rep++) {
        int idx = rep * 256 + tid;
        int d = idx >> 6, jj = idx & 63;
        VT[(size_t)(bh * DKn + d) * Sn + j0 + jj] = tl[d * 65 + jj];
    }
}

// ---------------------------------------------------------------------------
// C[M,512] = A[M,K] @ W[K,512] + bias, via split-bf16 MFMA over K'=2K.
// PACK: write pack_split(result) as uint (for attn Q/K consumption).
// 128x128 tile, 4 waves (2x2), each 64x64 = 4x4 frags of 16x16x32 bf16.
// XCD remap: same-A-panel blocks (shared bm) land on one XCD.
// ---------------------------------------------------------------------------
template <bool PACK>
__global__ __launch_bounds__(256) void gemm_mfma(
    const float* __restrict__ A1, const float* __restrict__ A2,
    const unsigned int* __restrict__ WT, const float* __restrict__ bias,
    void* __restrict__ Cout, int M, int N, int K) {
    __shared__ __align__(16) unsigned int Apk[128 * GKS];  // 18432 B
    __shared__ __align__(16) unsigned int Bpk[128 * GKS];  // 18432 B
    const int flat = blockIdx.y * 4 + blockIdx.x;  // grid (4, 64)
    const int bm = (flat & 63) * 128, bn = (flat >> 6) * 128;
    const int tid = threadIdx.x;
    const int wv = tid >> 6, lane = tid & 63;
    const int wr = (wv >> 1) * 64, wc = (wv & 1) * 64;
    const int fr = lane & 15, fg = lane >> 4;  // frag row(col), k-group

    f32x4 acc[4][4] = {};  // acc[fm][fn]

    const int kq = (tid & 7) * 4;    // uint/k offset within 32-k tile
    const int rbase = tid >> 3;      // 0..31

    for (int k0 = 0; k0 < K; k0 += 32) {
        const float* Ab = (k0 >= 512) ? A2 : A1;  // K==512 -> always A1
        const int kc = k0 & 511;
        #pragma unroll
        for (int rep = 0; rep < 4; rep++) {
            int row = rep * 32 + rbase;
            const float4 a4 = *reinterpret_cast<const float4*>(
                &Ab[(size_t)(bm + row) * 512 + kc + kq]);
            uint4 p;
            p.x = pack_split(a4.x);
            p.y = pack_split(a4.y);
            p.z = pack_split(a4.z);
            p.w = pack_split(a4.w);
            *reinterpret_cast<uint4*>(&Apk[row * GKS + kq]) = p;
        }
        #pragma unroll
        for (int rep = 0; rep < 4; rep++) {
            int n = rep * 32 + rbase;
            const uint4 b4 = *reinterpret_cast<const uint4*>(
                &WT[(size_t)(bn + n) * K + k0 + kq]);
            *reinterpret_cast<uint4*>(&Bpk[n * GKS + kq]) = b4;
        }
        __syncthreads();
        #pragma unroll
        for (int kk = 0; kk < 2; kk++) {
            short8 af[4], bf[4];
            #pragma unroll
            for (int f = 0; f < 4; f++) {
                af[f] = *reinterpret_cast<const short8*>(
                    &Apk[(wr + f * 16 + fr) * GKS + kk * 16 + fg * 4]);
                bf[f] = *reinterpret_cast<const short8*>(
                    &Bpk[(wc + f * 16 + fr) * GKS + kk * 16 + fg * 4]);
            }
            #pragma unroll
            for (int fm = 0; fm < 4; fm++)
                #pragma unroll
                for (int fn = 0; fn < 4; fn++)
                    acc[fm][fn] = __builtin_amdgcn_mfma_f32_16x16x32_bf16(
                        af[fm], bf[fn], acc[fm][fn], 0, 0, 0);
        }
        __syncthreads();
    }
    // epilogue: bias + store (C/D: col=lane&15, row=(lane>>4)*4+r)
    #pragma unroll
    for (int fn = 0; fn < 4; fn++) {
        const int col = bn + wc + fn * 16 + fr;
        const float bv = bias[col];
        #pragma unroll
        for (int fm = 0; fm < 4; fm++) {
            const int row0 = bm + wr + fm * 16 + fg * 4;
            #pragma unroll
            for (int r = 0; r < 4; r++) {
                float v = acc[fm][fn][r] + bv;
                if (PACK)
                    ((unsigned int*)Cout)[(size_t)(row0 + r) * N + col] =
                        pack_split(v);
                else
                    ((float*)Cout)[(size_t)(row0 + r) * N + col] = v;
            }
        }
    }
}

// ---------------------------------------------------------------------------
// MFMA distance-decay attention, direct-load + register-softmax variant.
// One block (512 thr, 8 waves) per (b,h, 16-row tile).
// MODE: 0 = j<=i; 1 = j<i; 2 = i-19<=j<i.
// QKu: packed-split Q/K [b,s,h*64+d] uints. VT: packed-split V^T [bh][d][j].
// XCD remap: all 64 blocks of one bh are ≡ (mod 8) -> same XCD L2.
// ---------------------------------------------------------------------------
template <int MODE, bool MAXOUT>
__global__ __launch_bounds__(512, 4) void attn_tile(
    const unsigned int* __restrict__ QKu, const unsigned int* __restrict__ VT,
    const float* __restrict__ gam, size_t g_off, float* __restrict__ O) {
    __shared__ __align__(16) unsigned int s_u[TQ * SRS];  // 65792 B
    __shared__ __align__(16) float pv[8 * 256];           // 8192 B
    __shared__ float rcoef[TQ];

    const int tid = threadIdx.x;
    const int flat = blockIdx.y * 64 + blockIdx.x;  // grid (64, 64)
    const int bh = flat & 63;
    const int i0 = (flat >> 6) * TQ;
    const int h = bh & (Hn - 1);
    const int b = bh >> 3;
    const int w = tid >> 6, lane = tid & 63;
    const int fr = lane & 15, fg = lane >> 4;

    const unsigned int* Kb = QKu + (size_t)b * Sn * Dn + h * DKn;
    const unsigned int* Vb = VT + (size_t)bh * DKn * Sn;

    const int last_j = (MODE == 0) ? (i0 + TQ - 1) : (i0 + TQ - 2);
    const int jt_hi = (last_j >> 7) + 1;
    const int jt_lo = (MODE == 2) ? (max(0, i0 - 19) >> 7) : 0;

    // ---- Q fragments in registers (each wave holds all 16 q-rows) ----
    uint4 qf[4];
    #pragma unroll
    for (int kk = 0; kk < 4; kk++)
        qf[kk] = *reinterpret_cast<const uint4*>(
            &Kb[(size_t)(i0 + fr) * Dn + kk * 16 + fg * 4]);

    // ---- phase 1: QK^T via MFMA (wave w owns j-group w*16..w*16+15) ----
    for (int jt = jt_lo; jt < jt_hi; jt++) {
        f32x4 acc = {0.f, 0.f, 0.f, 0.f};
        #pragma unroll
        for (int kk = 0; kk < 4; kk++) {
            const uint4 kf = *reinterpret_cast<const uint4*>(
                &Kb[(size_t)(jt * TJ + w * 16 + fr) * Dn + kk * 16 + fg * 4]);
            acc = __builtin_amdgcn_mfma_f32_16x16x32_bf16(
                *reinterpret_cast<const short8*>(&qf[kk]),
                *reinterpret_cast<const short8*>(&kf), acc, 0, 0, 0);
        }
        const int sj = sswz2(jt * TJ + w * 16 + fr);
        #pragma unroll
        for (int r = 0; r < 4; r++)
            s_u[(fg * 4 + r) * SRS + sj] = __float_as_uint(acc[r] * 0.125f);
    }
    __syncthreads();

    // ---- phases 2-4: register-resident softmax (1 load + 1 store pass) ----
    const int sr = tid >> 5, st = tid & 31;  // 16 rows x 32 threads
    const int i = i0 + sr;
    unsigned int* srow = &s_u[sr * SRS];
    const int c0 = st * 32;
    const int ex = (st << 1) & 31;  // even XOR for this thread's 32-col chunk
    const int lastv = (MODE == 0) ? i : i - 1;  // last valid j
    int vlo = (MODE == 2) ? min(max((i - 19) - c0, 0), 32) : 0;
    int vhi = min(max(lastv + 1 - c0, 0), 32);
    if (vhi < vlo) vhi = vlo;

    float sv[32];
    #pragma unroll
    for (int k = 0; k < 32; k += 2) {
        const uint2 u =
            *reinterpret_cast<const uint2*>(&srow[c0 + (k ^ ex)]);
        sv[k] = __uint_as_float(u.x);
        sv[k + 1] = __uint_as_float(u.y);
    }

    float lm = -3.4e38f;
    #pragma unroll
    for (int k = 0; k < 32; k++)
        lm = (k >= vlo && k < vhi) ? fmaxf(lm, sv[k]) : lm;
    #pragma unroll
    for (int off = 16; off; off >>= 1) lm = fmaxf(lm, __shfl_xor(lm, off, 64));
    const float m1 = lm;

    float csum = 0.f;
    #pragma unroll
    for (int k = 0; k < 32; k++) {
        float p = __expf(sv[k] - m1);
        csum += (k >= vlo && k < vhi) ? p : 0.f;
    }
    float scan = csum;
    #pragma unroll
    for (int off = 1; off < 32; off <<= 1) {
        float o = __shfl_up(scan, off, 32);
        if (st >= off) scan += o;
    }
    const float Z1 = __shfl(scan, 31, 32);
    const float invZ1 = 1.f / fmaxf(Z1, 1e-37f);
    const float g = -fabsf(gam[g_off + h]);
    float run = scan - csum;  // exclusive prefix at chunk start
    float lm2 = -3.4e38f;
    #pragma unroll
    for (int k = 0; k < 32; k++) {
        const bool val = (k >= vlo && k < vhi);
        float p = __expf(sv[k] - m1);
        run += val ? p : 0.f;
        float cum = run * invZ1;
        float dist = sqrtf(fmaxf((1.f - cum) * (float)(i - (c0 + k)), 0.f));
        float decay = fminf(fmaxf(__expf(g * dist), 1e-5f), 1e5f);
        float s2 = sv[k] * decay;
        sv[k] = s2;
        lm2 = val ? fmaxf(lm2, s2) : lm2;
    }
    #pragma unroll
    for (int off = 16; off; off >>= 1) lm2 = fmaxf(lm2, __shfl_xor(lm2, off, 64));

    float z2c = 0.f;
    #pragma unroll
    for (int k = 0; k < 32; k += 2) {
        const bool v0 = (k >= vlo && k < vhi);
        const bool v1 = (k + 1 >= vlo && k + 1 < vhi);
        float e0 = __expf(sv[k] - lm2);
        float e1 = __expf(sv[k + 1] - lm2);
        z2c += (v0 ? e0 : 0.f) + (v1 ? e1 : 0.f);
        uint2 u;
        u.x = v0 ? pack_split(e0) : 0u;
        u.y = v1 ? pack_split(e1) : 0u;
        *reinterpret_cast<uint2*>(&srow[c0 + (k ^ ex)]) = u;
    }
    #pragma unroll
    for (int off = 16; off; off >>= 1) z2c += __shfl_xor(z2c, off, 64);
    if (st == 0)
        rcoef[sr] = (MAXOUT ? fminf(z2c, 5.f) : 1.f) / fmaxf(z2c, 1e-37f);
    __syncthreads();

    // ---- phase 5: PV via MFMA (wave w: d-group w&3, j-half w>>2) ----
    const int dg = w & 3, jh = w >> 2;
    f32x4 accp = {0.f, 0.f, 0.f, 0.f};
    for (int jt = jt_lo; jt < jt_hi; jt++) {
        #pragma unroll
        for (int kk = 0; kk < 4; kk++) {
            const uint4 vf = *reinterpret_cast<const uint4*>(
                &Vb[(size_t)(dg * 16 + fr) * Sn + jt * TJ + jh * 64 + kk * 16 +
                    fg * 4]);
            const int jb = jt * TJ + jh * 64 + kk * 16 + fg * 4;
            const int eb = (jb >> 4) & 30;  // same for jb..jb+3
            const uint2 ua = *reinterpret_cast<const uint2*>(
                &s_u[fr * SRS + (jb ^ eb)]);
            const uint2 ub = *reinterpret_cast<const uint2*>(
                &s_u[fr * SRS + ((jb + 2) ^ eb)]);
            uint4 au;
            au.x = ua.x; au.y = ua.y; au.z = ub.x; au.w = ub.y;
            accp = __builtin_amdgcn_mfma_f32_16x16x32_bf16(
                *reinterpret_cast<const short8*>(&au),
                *reinterpret_cast<const short8*>(&vf), accp, 0, 0, 0);
        }
    }
    #pragma unroll
    for (int r = 0; r < 4; r++) pv[w * 256 + (fg * 4 + r) * 16 + fr] = accp[r];
    __syncthreads();

    // ---- combine j-halves + store ----
    #pragma unroll
    for (int rep = 0; rep < 2; rep++) {
        int idx = rep * 512 + tid;
        int r = idx >> 6, d = idx & 63;
        float v = (pv[(d >> 4) * 256 + r * 16 + (d & 15)] +
                   pv[((d >> 4) + 4) * 256 + r * 16 + (d & 15)]) *
                  rcoef[r];
        O[(size_t)(b * Sn + i0 + r) * Dn + h * DKn + d] = v;
    }
}

// ---------------------------------------------------------------------------
// out = LN(x + y) (fp32), one block per row of D=512.
// ---------------------------------------------------------------------------
__global__ __launch_bounds__(256) void add_ln(
    const float* __restrict__ X, const float* __restrict__ Y,
    const float* __restrict__ lnw, const float* __restrict__ lnb, size_t off,
    float* __restrict__ out) {
    __shared__ float red[4];
    const int row = blockIdx.x, tid = threadIdx.x;
    const size_t base = (size_t)row * Dn;
    float v0 = X[base + tid] + Y[base + tid];
    float v1 = X[base + tid + 256] + Y[base + tid + 256];
    const float mu = block_reduce_sum(v0 + v1, red) * (1.f / Dn);
    const float d0 = v0 - mu, d1 = v1 - mu;
    const float var = block_reduce_sum(d0 * d0 + d1 * d1, red) * (1.f / Dn);
    const float rs = rsqrtf(var + LN_EPS);
    out[base + tid] = d0 * rs * lnw[off + tid] + lnb[off + tid];
    out[base + tid + 256] = d1 * rs * lnw[off + tid + 256] + lnb[off + tid + 256];
}

// ---------------------------------------------------------------------------
// catA = LN2(hq + o); catB = LN2(hq + o + ow). All fp32, disjoint buffers.
// ---------------------------------------------------------------------------
__global__ __launch_bounds__(256) void cat_ln(
    const float* __restrict__ hq, const float* __restrict__ o,
    const float* __restrict__ ow, const float* __restrict__ lnw,
    const float* __restrict__ lnb, size_t off, float* __restrict__ catA,
    float* __restrict__ catB) {
    __shared__ float red[4];
    const int row = blockIdx.x, tid = threadIdx.x;
    const size_t base = (size_t)row * Dn;
    const float h0 = hq[base + tid] + o[base + tid];
    const float h1 = hq[base + tid + 256] + o[base + tid + 256];
    const float hw0 = h0 + ow[base + tid];
    const float hw1 = h1 + ow[base + tid + 256];
    const float w0 = lnw[off + tid], w1 = lnw[off + tid + 256];
    const float b0 = lnb[off + tid], b1 = lnb[off + tid + 256];

    float mu = block_reduce_sum(h0 + h1, red) * (1.f / Dn);
    float d0 = h0 - mu, d1 = h1 - mu;
    float var = block_reduce_sum(d0 * d0 + d1 * d1, red) * (1.f / Dn);
    float rs = rsqrtf(var + LN_EPS);
    catA[base + tid] = d0 * rs * w0 + b0;
    catA[base + tid + 256] = d1 * rs * w1 + b1;

    mu = block_reduce_sum(hw0 + hw1, red) * (1.f / Dn);
    d0 = hw0 - mu;
    d1 = hw1 - mu;
    var = block_reduce_sum(d0 * d0 + d1 * d1, red) * (1.f / Dn);
    rs = rsqrtf(var + LN_EPS);
    catB[base + tid] = d0 * rs * w0 + b0;
    catB[base + tid + 256] = d1 * rs * w1 + b1;
}

extern "C" void kernel_launch(void* const* d_in, const int* in_sizes, int n_in,
                              void* d_out, int out_size, void* d_ws,
                              size_t ws_size, hipStream_t stream) {
    const float* q_emb = (const float*)d_in[0];
    const float* s_emb = (const float*)d_in[1];
    const float* Wq = (const float*)d_in[2];
    const float* bq = (const float*)d_in[3];
    const float* Wqw = (const float*)d_in[4];
    const float* bqw = (const float*)d_in[5];
    const float* Wv = (const float*)d_in[6];
    const float* bv = (const float*)d_in[7];
    const float* Wo = (const float*)d_in[8];
    const float* bo = (const float*)d_in[9];
    const float* Wow = (const float*)d_in[10];
    const float* bow = (const float*)d_in[11];
    const float* gammas = (const float*)d_in[12];
    const float* ln_w = (const float*)d_in[13];
    const float* ln_b = (const float*)d_in[14];
    const float* Wc = (const float*)d_in[15];
    const float* bc = (const float*)d_in[16];
    // d_in[17] = lens: unused in the forward pass.

    const size_t BSD = (size_t)Bn * Sn * Dn;
    float* ws = (float*)d_ws;
    float* W0 = ws;
    float* W1 = ws + BSD;
    float* W2 = ws + 2 * BSD;
    unsigned int* VTp = (unsigned int*)(ws + 3 * BSD);   // 16 MB packed V^T
    unsigned int* Wpk = (unsigned int*)(ws + 4 * BSD);   // 2 MB packed weights
    unsigned int* W0u = (unsigned int*)W0;

    float* out_main = (float*)d_out;     // out [B,S,D]
    float* out_hq = out_main + BSD;      // hq
    float* out_hs = out_main + 2 * BSD;  // hs

    const int rows = Bn * Sn;  // 8192
    const dim3 tpb(256), tpA(512);
    const dim3 ggemm(Dn / 128, rows / 128);  // (4, 64)
    const dim3 gattn(Sn / TQ, Bn * Hn);      // (64, 64)
    const dim3 gvt(Sn / 64, Bn * Hn);        // (16, 64)
    const dim3 grow(rows);
    const size_t DD = (size_t)Dn * Dn;

    #define PK(Wp, Kk) pack_wt<<<(Kk) * 2, tpb, 0, stream>>>((Wp), Wpk, (Kk))
    #define GM(A, Bi, Cc) \
        gemm_mfma<false><<<ggemm, tpb, 0, stream>>>((A), (A), Wpk, (Bi), (Cc), rows, Dn, Dn)
    #define GMP(A, Bi, Cc) \
        gemm_mfma<true><<<ggemm, tpb, 0, stream>>>((A), (A), Wpk, (Bi), (Cc), rows, Dn, Dn)

    // ---- Block 1: hq = LN0(q_emb + attn0(q_emb)) -> out_hq ----
    PK(Wq, Dn);               GMP(q_emb, bq, W0u);
    PK(Wv, Dn);               GM(q_emb, bv, W1);
    pack_vt<<<gvt, tpb, 0, stream>>>(W1, VTp);
    attn_tile<0, false><<<gattn, tpA, 0, stream>>>(W0u, VTp, gammas, 0, W2);
    PK(Wo, Dn);               GM(W2, bo, W0);
    add_ln<<<grow, tpb, 0, stream>>>(q_emb, W0, ln_w, ln_b, 0, out_hq);

    // ---- Block 2: hs = LN1(s_emb + attn1(s_emb)) -> out_hs ----
    PK(Wq + DD, Dn);          GMP(s_emb, bq + Dn, W0u);
    PK(Wv + DD, Dn);          GM(s_emb, bv + Dn, W1);
    pack_vt<<<gvt, tpb, 0, stream>>>(W1, VTp);
    attn_tile<0, false><<<gattn, tpA, 0, stream>>>(W0u, VTp, gammas, Hn, W2);
    PK(Wo + DD, Dn);          GM(W2, bo + Dn, W0);
    add_ln<<<grow, tpb, 0, stream>>>(s_emb, W0, ln_w, ln_b, Dn, out_hs);

    // ---- Block 3: xq=xk=hq, xv=hs ----
    PK(Wq + 2 * DD, Dn);      GMP(out_hq, bq + 2 * Dn, W0u);
    PK(Wv + 2 * DD, Dn);      GM(out_hs, bv + 2 * Dn, W1);
    pack_vt<<<gvt, tpb, 0, stream>>>(W1, VTp);
    attn_tile<1, true><<<gattn, tpA, 0, stream>>>(W0u, VTp, gammas, 2 * Hn, W2);
    PK(Wo + 2 * DD, Dn);      GM(W2, bo + 2 * Dn, out_main);
    PK(Wqw + 2 * DD, Dn);     GMP(out_hq, bqw + 2 * Dn, W0u);
    attn_tile<2, false><<<gattn, tpA, 0, stream>>>(W0u, VTp, gammas, 2 * Hn, W2);
    PK(Wow, Dn);              GM(W2, bow, W0);
    // catA = LN2(hq + o) -> W1 ; catB = LN2(hq + o + ow) -> W2
    cat_ln<<<grow, tpb, 0, stream>>>(out_hq, out_main, W0, ln_w, ln_b, 2 * Dn, W1, W2);
    // out = [catA | catB] @ Wc + bc  (K=1024)
    PK(Wc, 2 * Dn);
    gemm_mfma<false><<<ggemm, tpb, 0, stream>>>(W1, W2, Wpk, bc, out_main,
                                                rows, Dn, 2 * Dn);
    #undef PK
    #undef GM
    #undef GMP
}

// Round 10
// 886.421 us; speedup vs baseline: 4.9444x; 1.3251x over previous
//
#include <hip/hip_runtime.h>
#include <hip/hip_bf16.h>

// AKT_27917287424232 — 3-block distance-decay attention transformer.
// B=8, S=1024, D=512, H=8, dk=64. Inputs fp32, outputs fp32 (out,hq,hs).
// R13: split-bf16 MFMA attention. ->2001 us.
// R14: direct global->register K/V/Q frags, no in-loop barriers. ->1485 us.
// R15: register-resident softmax + pair swizzle. ->1354 us.
// R16: XCD-locality block remap (FETCH 131->20MB). ->1175 us.
// R17: pure RNE-bf16 everywhere. The R12 "split" scheme misses the hi/lo
// cross terms, so its error == plain bf16's leading error: halve K', MFMA,
// staging, and K/V/P bytes for free. GEMM: K-chunk 64, granule-XOR LDS
// swizzle (kills the (fr+fg)%8 8-way ds_read_b128 conflict). attn: QK^T and
// PV 2 MFMA/tile, P pair-packed bf16 in-place (wave-lockstep), swizzles
// dropped (one-shot softmax passes make conflicts negligible).

typedef __hip_bfloat16 bf16;
typedef __attribute__((ext_vector_type(8))) short short8;
typedef __attribute__((ext_vector_type(4))) float f32x4;

constexpr int Bn = 8, Sn = 1024, Dn = 512, Hn = 8, DKn = 64;
constexpr float LN_EPS = 1e-5f;
constexpr int TQ = 16;    // query rows per block
constexpr int TJ = 128;   // K/V tile rows (j per tile)
constexpr int SRS = 1028; // s_u row stride (uints; scores fp32, P packed)
constexpr int GUS = 72;   // gemm LDS ushort stride (9 x 16B granules)

__device__ inline float wave_reduce_sum(float v) {
    #pragma unroll
    for (int off = 32; off; off >>= 1) v += __shfl_xor(v, off, 64);
    return v;
}
// Block of exactly 256 threads (4 waves). smem >= 4 floats.
__device__ inline float block_reduce_sum(float v, float* smem) {
    int lane = threadIdx.x & 63, wave = threadIdx.x >> 6;
    v = wave_reduce_sum(v);
    __syncthreads();
    if (lane == 0) smem[wave] = v;
    __syncthreads();
    return smem[0] + smem[1] + smem[2] + smem[3];
}

// RNE float -> bf16 (as ushort bits).
__device__ inline unsigned short bf16r(float x) {
    unsigned int b = __float_as_uint(x);
    return (unsigned short)((b + 0x7FFFu + ((b >> 16) & 1u)) >> 16);
}
// Two floats -> packed pair of bf16 (low = a).
__device__ inline unsigned int pack2_bf16(float a, float b) {
    return (unsigned int)bf16r(a) | ((unsigned int)bf16r(b) << 16);
}

// ---------------------------------------------------------------------------
// Pack W [K][512] fp32 -> WT [512][K] bf16 ushorts (transposed).
// ---------------------------------------------------------------------------
__global__ __launch_bounds__(256) void pack_wt(
    const float* __restrict__ W, unsigned short* __restrict__ WT, int K) {
    int idx = blockIdx.x * 256 + threadIdx.x;  // over K*512
    int k = idx >> 9, n = idx & 511;
    WT[(size_t)n * K + k] = bf16r(W[idx]);
}

// ---------------------------------------------------------------------------
// Pack V [B,S,D] fp32 -> VT [bh][d][j] bf16 (per-head transpose).
// Grid (16 j-tiles, 64 bh), 256 threads, LDS 64x64 ushort tile.
// ---------------------------------------------------------------------------
__global__ __launch_bounds__(256) void pack_vt(
    const float* __restrict__ V, unsigned short* __restrict__ VT) {
    __shared__ unsigned short tl[64 * 66];
    const int tid = threadIdx.x;
    const int j0 = blockIdx.x * 64;
    const int bh = blockIdx.y;
    const int b = bh >> 3, h = bh & 7;
    #pragma unroll
    for (int rep = 0; rep < 16; rep++) {
        int idx = rep * 256 + tid;
        int jj = idx >> 6, d = idx & 63;
        tl[d * 66 + jj] =
            bf16r(V[(size_t)(b * Sn + j0 + jj) * Dn + h * DKn + d]);
    }
    __syncthreads();
    // store as uints (2 jj per thread) for 4B-coalesced writes
    unsigned int* VTu = (unsigned int*)VT;
    #pragma unroll
    for (int rep = 0; rep < 8; rep++) {
        int idx = rep * 256 + tid;
        int d = idx >> 5, jj2 = (idx & 31) * 2;
        unsigned int v = (unsigned int)tl[d * 66 + jj2] |
                         ((unsigned int)tl[d * 66 + jj2 + 1] << 16);
        VTu[((size_t)(bh * DKn + d) * Sn + j0 + jj2) >> 1] = v;
    }
}

// ---------------------------------------------------------------------------
// C[M,512] = A[M,K] @ W[K,512] + bias via bf16 MFMA (RNE-rounded inputs).
// PACK: write bf16 ushort result (for attn Q/K). 128x128 tile, 4 waves,
// K-chunk 64. LDS granule-XOR swizzle: 16B granule g of row r stored at
// g ^ (r&7) -> ds_read_b128 2-way (free) instead of 8-way.
// XCD remap: same-A-panel blocks land on one XCD.
// ---------------------------------------------------------------------------
template <bool PACK>
__global__ __launch_bounds__(256) void gemm_mfma(
    const float* __restrict__ A1, const float* __restrict__ A2,
    const unsigned short* __restrict__ WT, const float* __restrict__ bias,
    void* __restrict__ Cout, int M, int N, int K) {
    __shared__ __align__(16) unsigned short Apk[128 * GUS];  // 18432 B
    __shared__ __align__(16) unsigned short Bpk[128 * GUS];  // 18432 B
    const int flat = blockIdx.y * 4 + blockIdx.x;  // grid (4, 64)
    const int bm = (flat & 63) * 128, bn = (flat >> 6) * 128;
    const int tid = threadIdx.x;
    const int wv = tid >> 6, lane = tid & 63;
    const int wr = (wv >> 1) * 64, wc = (wv & 1) * 64;
    const int fr = lane & 15, fg = lane >> 4;  // frag row(col), k-group

    f32x4 acc[4][4] = {};  // acc[fm][fn]

    const int g0 = tid & 7;       // ushort granule (8 k) within 64-k chunk
    const int rbase = tid >> 3;   // 0..31

    for (int k0 = 0; k0 < K; k0 += 64) {
        const float* Ab = (k0 >= 512) ? A2 : A1;  // K==512 -> always A1
        const int kc = k0 & 511;
        #pragma unroll
        for (int rep = 0; rep < 4; rep++) {
            int row = rep * 32 + rbase;
            const float4 a0 = *reinterpret_cast<const float4*>(
                &Ab[(size_t)(bm + row) * 512 + kc + g0 * 8]);
            const float4 a1 = *reinterpret_cast<const float4*>(
                &Ab[(size_t)(bm + row) * 512 + kc + g0 * 8 + 4]);
            uint4 p;
            p.x = pack2_bf16(a0.x, a0.y);
            p.y = pack2_bf16(a0.z, a0.w);
            p.z = pack2_bf16(a1.x, a1.y);
            p.w = pack2_bf16(a1.z, a1.w);
            *reinterpret_cast<uint4*>(
                &Apk[row * GUS + ((g0 ^ (row & 7)) << 3)]) = p;
        }
        #pragma unroll
        for (int rep = 0; rep < 4; rep++) {
            int n = rep * 32 + rbase;
            const uint4 b4 = *reinterpret_cast<const uint4*>(
                &WT[(size_t)(bn + n) * K + k0 + g0 * 8]);
            *reinterpret_cast<uint4*>(
                &Bpk[n * GUS + ((g0 ^ (n & 7)) << 3)]) = b4;
        }
        __syncthreads();
        #pragma unroll
        for (int kk = 0; kk < 2; kk++) {
            short8 af[4], bf[4];
            #pragma unroll
            for (int f = 0; f < 4; f++) {
                const int ra = wr + f * 16 + fr;
                const int rb = wc + f * 16 + fr;
                af[f] = *reinterpret_cast<const short8*>(
                    &Apk[ra * GUS + (((kk * 4 + fg) ^ (ra & 7)) << 3)]);
                bf[f] = *reinterpret_cast<const short8*>(
                    &Bpk[rb * GUS + (((kk * 4 + fg) ^ (rb & 7)) << 3)]);
            }
            #pragma unroll
            for (int fm = 0; fm < 4; fm++)
                #pragma unroll
                for (int fn = 0; fn < 4; fn++)
                    acc[fm][fn] = __builtin_amdgcn_mfma_f32_16x16x32_bf16(
                        af[fm], bf[fn], acc[fm][fn], 0, 0, 0);
        }
        __syncthreads();
    }
    // epilogue: bias + store (C/D: col=lane&15, row=(lane>>4)*4+r)
    #pragma unroll
    for (int fn = 0; fn < 4; fn++) {
        const int col = bn + wc + fn * 16 + fr;
        const float bv = bias[col];
        #pragma unroll
        for (int fm = 0; fm < 4; fm++) {
            const int row0 = bm + wr + fm * 16 + fg * 4;
            #pragma unroll
            for (int r = 0; r < 4; r++) {
                float v = acc[fm][fn][r] + bv;
                if (PACK)
                    ((unsigned short*)Cout)[(size_t)(row0 + r) * N + col] =
                        bf16r(v);
                else
                    ((float*)Cout)[(size_t)(row0 + r) * N + col] = v;
            }
        }
    }
}

// ---------------------------------------------------------------------------
// MFMA distance-decay attention, pure-bf16 direct-load variant.
// One block (512 thr, 8 waves) per (b,h, 16-row tile).
// MODE: 0 = j<=i; 1 = j<i; 2 = i-19<=j<i.
// QKu: bf16 Q/K [b,s,h*64+d]. VT: bf16 V^T [bh][d][j]. Scores fp32 in s_u;
// softmax writes P pair-packed bf16 in place (wave-lockstep safe).
// XCD remap: all 64 blocks of one bh are ≡ (mod 8) -> same XCD L2.
// ---------------------------------------------------------------------------
template <int MODE, bool MAXOUT>
__global__ __launch_bounds__(512, 4) void attn_tile(
    const unsigned short* __restrict__ QKu,
    const unsigned short* __restrict__ VT, const float* __restrict__ gam,
    size_t g_off, float* __restrict__ O) {
    __shared__ __align__(16) unsigned int s_u[TQ * SRS];  // 65792 B
    __shared__ __align__(16) float pv[8 * 256];           // 8192 B
    __shared__ float rcoef[TQ];

    const int tid = threadIdx.x;
    const int flat = blockIdx.y * 64 + blockIdx.x;  // grid (64, 64)
    const int bh = flat & 63;
    const int i0 = (flat >> 6) * TQ;
    const int h = bh & (Hn - 1);
    const int b = bh >> 3;
    const int w = tid >> 6, lane = tid & 63;
    const int fr = lane & 15, fg = lane >> 4;

    const unsigned short* Kb = QKu + (size_t)b * Sn * Dn + h * DKn;
    const unsigned short* Vb = VT + (size_t)bh * DKn * Sn;

    const int last_j = (MODE == 0) ? (i0 + TQ - 1) : (i0 + TQ - 2);
    const int jt_hi = (last_j >> 7) + 1;
    const int jt_lo = (MODE == 2) ? (max(0, i0 - 19) >> 7) : 0;

    // ---- Q fragments in registers ----
    uint4 qf[2];
    #pragma unroll
    for (int kk = 0; kk < 2; kk++)
        qf[kk] = *reinterpret_cast<const uint4*>(
            &Kb[(size_t)(i0 + fr) * Dn + kk * 32 + fg * 8]);

    // ---- phase 1: QK^T via MFMA (wave w owns j-group w*16..w*16+15) ----
    for (int jt = jt_lo; jt < jt_hi; jt++) {
        f32x4 acc = {0.f, 0.f, 0.f, 0.f};
        #pragma unroll
        for (int kk = 0; kk < 2; kk++) {
            const uint4 kf = *reinterpret_cast<const uint4*>(
                &Kb[(size_t)(jt * TJ + w * 16 + fr) * Dn + kk * 32 + fg * 8]);
            acc = __builtin_amdgcn_mfma_f32_16x16x32_bf16(
                *reinterpret_cast<const short8*>(&qf[kk]),
                *reinterpret_cast<const short8*>(&kf), acc, 0, 0, 0);
        }
        const int sj = jt * TJ + w * 16 + fr;
        #pragma unroll
        for (int r = 0; r < 4; r++)
            s_u[(fg * 4 + r) * SRS + sj] = __float_as_uint(acc[r] * 0.125f);
    }
    __syncthreads();

    // ---- phases 2-4: register-resident softmax ----
    const int sr = tid >> 5, st = tid & 31;  // 16 rows x 32 threads
    const int i = i0 + sr;
    unsigned int* srow = &s_u[sr * SRS];
    const int c0 = st * 32;
    const int lastv = (MODE == 0) ? i : i - 1;  // last valid j
    int vlo = (MODE == 2) ? min(max((i - 19) - c0, 0), 32) : 0;
    int vhi = min(max(lastv + 1 - c0, 0), 32);
    if (vhi < vlo) vhi = vlo;

    float sv[32];
    #pragma unroll
    for (int k = 0; k < 32; k += 2) {
        const uint2 u = *reinterpret_cast<const uint2*>(&srow[c0 + k]);
        sv[k] = __uint_as_float(u.x);
        sv[k + 1] = __uint_as_float(u.y);
    }

    float lm = -3.4e38f;
    #pragma unroll
    for (int k = 0; k < 32; k++)
        lm = (k >= vlo && k < vhi) ? fmaxf(lm, sv[k]) : lm;
    #pragma unroll
    for (int off = 16; off; off >>= 1) lm = fmaxf(lm, __shfl_xor(lm, off, 64));
    const float m1 = lm;

    float csum = 0.f;
    #pragma unroll
    for (int k = 0; k < 32; k++) {
        float p = __expf(sv[k] - m1);
        csum += (k >= vlo && k < vhi) ? p : 0.f;
    }
    float scan = csum;
    #pragma unroll
    for (int off = 1; off < 32; off <<= 1) {
        float o = __shfl_up(scan, off, 32);
        if (st >= off) scan += o;
    }
    const float Z1 = __shfl(scan, 31, 32);
    const float invZ1 = 1.f / fmaxf(Z1, 1e-37f);
    const float g = -fabsf(gam[g_off + h]);
    float run = scan - csum;  // exclusive prefix at chunk start
    float lm2 = -3.4e38f;
    #pragma unroll
    for (int k = 0; k < 32; k++) {
        const bool val = (k >= vlo && k < vhi);
        float p = __expf(sv[k] - m1);
        run += val ? p : 0.f;
        float cum = run * invZ1;
        float dist = sqrtf(fmaxf((1.f - cum) * (float)(i - (c0 + k)), 0.f));
        float decay = fminf(fmaxf(__expf(g * dist), 1e-5f), 1e5f);
        float s2 = sv[k] * decay;
        sv[k] = s2;
        lm2 = val ? fmaxf(lm2, s2) : lm2;
    }
    #pragma unroll
    for (int off = 16; off; off >>= 1) lm2 = fmaxf(lm2, __shfl_xor(lm2, off, 64));

    // final pass: e -> bf16 pair-packed P at uint slot j/2, IN PLACE.
    // Safe: all score loads above happened (wave lockstep) before stores.
    float z2c = 0.f;
    #pragma unroll
    for (int k = 0; k < 32; k += 2) {
        const bool v0 = (k >= vlo && k < vhi);
        const bool v1 = (k + 1 >= vlo && k + 1 < vhi);
        float e0 = __expf(sv[k] - lm2);
        float e1 = __expf(sv[k + 1] - lm2);
        z2c += (v0 ? e0 : 0.f) + (v1 ? e1 : 0.f);
        unsigned int u = pack2_bf16(v0 ? e0 : 0.f, v1 ? e1 : 0.f);
        srow[16 * st + (k >> 1)] = u;
    }
    #pragma unroll
    for (int off = 16; off; off >>= 1) z2c += __shfl_xor(z2c, off, 64);
    if (st == 0)
        rcoef[sr] = (MAXOUT ? fminf(z2c, 5.f) : 1.f) / fmaxf(z2c, 1e-37f);
    __syncthreads();

    // ---- phase 5: PV via MFMA (wave w: d-group w&3, j-half w>>2) ----
    const int dg = w & 3, jh = w >> 2;
    f32x4 accp = {0.f, 0.f, 0.f, 0.f};
    for (int jt = jt_lo; jt < jt_hi; jt++) {
        #pragma unroll
        for (int kk = 0; kk < 2; kk++) {
            const uint4 vf = *reinterpret_cast<const uint4*>(
                &Vb[(size_t)(dg * 16 + fr) * Sn + jt * TJ + jh * 64 + kk * 32 +
                    fg * 8]);
            const uint4 au = *reinterpret_cast<const uint4*>(
                &s_u[fr * SRS + jt * 64 + jh * 32 + kk * 16 + fg * 4]);
            accp = __builtin_amdgcn_mfma_f32_16x16x32_bf16(
                *reinterpret_cast<const short8*>(&au),
                *reinterpret_cast<const short8*>(&vf), accp, 0, 0, 0);
        }
    }
    #pragma unroll
    for (int r = 0; r < 4; r++) pv[w * 256 + (fg * 4 + r) * 16 + fr] = accp[r];
    __syncthreads();

    // ---- combine j-halves + store ----
    #pragma unroll
    for (int rep = 0; rep < 2; rep++) {
        int idx = rep * 512 + tid;
        int r = idx >> 6, d = idx & 63;
        float v = (pv[(d >> 4) * 256 + r * 16 + (d & 15)] +
                   pv[((d >> 4) + 4) * 256 + r * 16 + (d & 15)]) *
                  rcoef[r];
        O[(size_t)(b * Sn + i0 + r) * Dn + h * DKn + d] = v;
    }
}

// ---------------------------------------------------------------------------
// out = LN(x + y) (fp32), one block per row of D=512.
// ---------------------------------------------------------------------------
__global__ __launch_bounds__(256) void add_ln(
    const float* __restrict__ X, const float* __restrict__ Y,
    const float* __restrict__ lnw, const float* __restrict__ lnb, size_t off,
    float* __restrict__ out) {
    __shared__ float red[4];
    const int row = blockIdx.x, tid = threadIdx.x;
    const size_t base = (size_t)row * Dn;
    float v0 = X[base + tid] + Y[base + tid];
    float v1 = X[base + tid + 256] + Y[base + tid + 256];
    const float mu = block_reduce_sum(v0 + v1, red) * (1.f / Dn);
    const float d0 = v0 - mu, d1 = v1 - mu;
    const float var = block_reduce_sum(d0 * d0 + d1 * d1, red) * (1.f / Dn);
    const float rs = rsqrtf(var + LN_EPS);
    out[base + tid] = d0 * rs * lnw[off + tid] + lnb[off + tid];
    out[base + tid + 256] = d1 * rs * lnw[off + tid + 256] + lnb[off + tid + 256];
}

// ---------------------------------------------------------------------------
// catA = LN2(hq + o); catB = LN2(hq + o + ow). All fp32, disjoint buffers.
// ---------------------------------------------------------------------------
__global__ __launch_bounds__(256) void cat_ln(
    const float* __restrict__ hq, const float* __restrict__ o,
    const float* __restrict__ ow, const float* __restrict__ lnw,
    const float* __restrict__ lnb, size_t off, float* __restrict__ catA,
    float* __restrict__ catB) {
    __shared__ float red[4];
    const int row = blockIdx.x, tid = threadIdx.x;
    const size_t base = (size_t)row * Dn;
    const float h0 = hq[base + tid] + o[base + tid];
    const float h1 = hq[base + tid + 256] + o[base + tid + 256];
    const float hw0 = h0 + ow[base + tid];
    const float hw1 = h1 + ow[base + tid + 256];
    const float w0 = lnw[off + tid], w1 = lnw[off + tid + 256];
    const float b0 = lnb[off + tid], b1 = lnb[off + tid + 256];

    float mu = block_reduce_sum(h0 + h1, red) * (1.f / Dn);
    float d0 = h0 - mu, d1 = h1 - mu;
    float var = block_reduce_sum(d0 * d0 + d1 * d1, red) * (1.f / Dn);
    float rs = rsqrtf(var + LN_EPS);
    catA[base + tid] = d0 * rs * w0 + b0;
    catA[base + tid + 256] = d1 * rs * w1 + b1;

    mu = block_reduce_sum(hw0 + hw1, red) * (1.f / Dn);
    d0 = hw0 - mu;
    d1 = hw1 - mu;
    var = block_reduce_sum(d0 * d0 + d1 * d1, red) * (1.f / Dn);
    rs = rsqrtf(var + LN_EPS);
    catB[base + tid] = d0 * rs * w0 + b0;
    catB[base + tid + 256] = d1 * rs * w1 + b1;
}

extern "C" void kernel_launch(void* const* d_in, const int* in_sizes, int n_in,
                              void* d_out, int out_size, void* d_ws,
                              size_t ws_size, hipStream_t stream) {
    const float* q_emb = (const float*)d_in[0];
    const float* s_emb = (const float*)d_in[1];
    const float* Wq = (const float*)d_in[2];
    const float* bq = (const float*)d_in[3];
    const float* Wqw = (const float*)d_in[4];
    const float* bqw = (const float*)d_in[5];
    const float* Wv = (const float*)d_in[6];
    const float* bv = (const float*)d_in[7];
    const float* Wo = (const float*)d_in[8];
    const float* bo = (const float*)d_in[9];
    const float* Wow = (const float*)d_in[10];
    const float* bow = (const float*)d_in[11];
    const float* gammas = (const float*)d_in[12];
    const float* ln_w = (const float*)d_in[13];
    const float* ln_b = (const float*)d_in[14];
    const float* Wc = (const float*)d_in[15];
    const float* bc = (const float*)d_in[16];
    // d_in[17] = lens: unused in the forward pass.

    const size_t BSD = (size_t)Bn * Sn * Dn;
    float* ws = (float*)d_ws;
    float* W0 = ws;
    float* W1 = ws + BSD;
    float* W2 = ws + 2 * BSD;
    unsigned short* VTp = (unsigned short*)(ws + 3 * BSD);  // 8 MB bf16 V^T
    unsigned short* Wpk = (unsigned short*)(ws + 4 * BSD);  // 1 MB bf16 W^T
    unsigned short* W0u = (unsigned short*)W0;

    float* out_main = (float*)d_out;     // out [B,S,D]
    float* out_hq = out_main + BSD;      // hq
    float* out_hs = out_main + 2 * BSD;  // hs

    const int rows = Bn * Sn;  // 8192
    const dim3 tpb(256), tpA(512);
    const dim3 ggemm(Dn / 128, rows / 128);  // (4, 64)
    const dim3 gattn(Sn / TQ, Bn * Hn);      // (64, 64)
    const dim3 gvt(Sn / 64, Bn * Hn);        // (16, 64)
    const dim3 grow(rows);
    const size_t DD = (size_t)Dn * Dn;

    #define PK(Wp, Kk) pack_wt<<<(Kk) * 2, tpb, 0, stream>>>((Wp), Wpk, (Kk))
    #define GM(A, Bi, Cc) \
        gemm_mfma<false><<<ggemm, tpb, 0, stream>>>((A), (A), Wpk, (Bi), (Cc), rows, Dn, Dn)
    #define GMP(A, Bi, Cc) \
        gemm_mfma<true><<<ggemm, tpb, 0, stream>>>((A), (A), Wpk, (Bi), (Cc), rows, Dn, Dn)

    // ---- Block 1: hq = LN0(q_emb + attn0(q_emb)) -> out_hq ----
    PK(Wq, Dn);               GMP(q_emb, bq, W0u);
    PK(Wv, Dn);               GM(q_emb, bv, W1);
    pack_vt<<<gvt, tpb, 0, stream>>>(W1, VTp);
    attn_tile<0, false><<<gattn, tpA, 0, stream>>>(W0u, VTp, gammas, 0, W2);
    PK(Wo, Dn);               GM(W2, bo, W0);
    add_ln<<<grow, tpb, 0, stream>>>(q_emb, W0, ln_w, ln_b, 0, out_hq);

    // ---- Block 2: hs = LN1(s_emb + attn1(s_emb)) -> out_hs ----
    PK(Wq + DD, Dn);          GMP(s_emb, bq + Dn, W0u);
    PK(Wv + DD, Dn);          GM(s_emb, bv + Dn, W1);
    pack_vt<<<gvt, tpb, 0, stream>>>(W1, VTp);
    attn_tile<0, false><<<gattn, tpA, 0, stream>>>(W0u, VTp, gammas, Hn, W2);
    PK(Wo + DD, Dn);          GM(W2, bo + Dn, W0);
    add_ln<<<grow, tpb, 0, stream>>>(s_emb, W0, ln_w, ln_b, Dn, out_hs);

    // ---- Block 3: xq=xk=hq, xv=hs ----
    PK(Wq + 2 * DD, Dn);      GMP(out_hq, bq + 2 * Dn, W0u);
    PK(Wv + 2 * DD, Dn);      GM(out_hs, bv + 2 * Dn, W1);
    pack_vt<<<gvt, tpb, 0, stream>>>(W1, VTp);
    attn_tile<1, true><<<gattn, tpA, 0, stream>>>(W0u, VTp, gammas, 2 * Hn, W2);
    PK(Wo + 2 * DD, Dn);      GM(W2, bo + 2 * Dn, out_main);
    PK(Wqw + 2 * DD, Dn);     GMP(out_hq, bqw + 2 * Dn, W0u);
    attn_tile<2, false><<<gattn, tpA, 0, stream>>>(W0u, VTp, gammas, 2 * Hn, W2);
    PK(Wow, Dn);              GM(W2, bow, W0);
    // catA = LN2(hq + o) -> W1 ; catB = LN2(hq + o + ow) -> W2
    cat_ln<<<grow, tpb, 0, stream>>>(out_hq, out_main, W0, ln_w, ln_b, 2 * Dn, W1, W2);
    // out = [catA | catB] @ Wc + bc  (K=1024)
    PK(Wc, 2 * Dn);
    gemm_mfma<false><<<ggemm, tpb, 0, stream>>>(W1, W2, Wpk, bc, out_main,
                                                rows, Dn, 2 * Dn);
    #undef PK
    #undef GM
    #undef GMP
}